// Round 2
// baseline (34606.433 us; speedup 1.0000x reference)
//
#include <hip/hip_runtime.h>
#include <math.h>

#define LNUM 6
#define HNUM 8
#define DMODEL 512
#define DHEAD 64
#define MFEAT 256
#define BATCH 8
#define SEQ 2048
#define TOK (BATCH*SEQ)      // 16384
#define BHN (BATCH*HNUM)     // 64
#define DFF 2048
#define EPSF 1e-4f
#define LN_EPS 1e-5f
#define DNRM 0.35355339059327373f   /* 64^-0.25 */
#define SMF 0.0625f                  /* 256^-0.5 */

typedef unsigned short u16;

__device__ __forceinline__ u16 f2bf(float f){
  unsigned int u = __float_as_uint(f);
  u = (u + 0x7fffu + ((u >> 16) & 1u)) >> 16;
  return (u16)u;
}
__device__ __forceinline__ float bf2f(u16 s){
  return __uint_as_float(((unsigned int)s) << 16);
}
__device__ __forceinline__ void atomicMaxF(float* addr, float val){
  if(val >= 0.f) atomicMax((int*)addr, __float_as_int(val));
  else           atomicMin((unsigned int*)addr, __float_as_uint(val));
}

// ---------------- x = x + sinusoidal PE ----------------
__global__ void k_addpe(const float* __restrict__ x, float* __restrict__ xo){
  int idx = blockIdx.x*256 + threadIdx.x;
  int d = idx & (DMODEL-1);
  int n = (idx >> 9) & (SEQ-1);
  int j = d >> 1;
  float freq = expf((float)(2*j) * (-9.210340371976184f / (float)DMODEL));
  float ang = (float)n * freq;
  float pe = (d & 1) ? cosf(ang) : sinf(ang);
  xo[idx] = x[idx] + pe;
}

// ---------------- LayerNorm over last dim 512, 1 block per token ----------------
template<typename OT>
__global__ void k_ln(const float* __restrict__ x, const float* __restrict__ g,
                     const float* __restrict__ bv, OT* __restrict__ out){
  __shared__ float sred[8];
  int t = blockIdx.x, tid = threadIdx.x;
  const float2 v = ((const float2*)(x + (size_t)t*DMODEL))[tid];
  float s = v.x + v.y;
  #pragma unroll
  for(int o=32;o;o>>=1) s += __shfl_down(s,o);
  if((tid&63)==0) sred[tid>>6] = s;
  __syncthreads();
  if(tid==0) sred[4] = (sred[0]+sred[1]+sred[2]+sred[3]) * (1.0f/DMODEL);
  __syncthreads();
  float mu = sred[4];
  float dx = v.x - mu, dy = v.y - mu;
  float s2 = dx*dx + dy*dy;
  #pragma unroll
  for(int o=32;o;o>>=1) s2 += __shfl_down(s2,o);
  if((tid&63)==0) sred[tid>>6] = s2;
  __syncthreads();
  if(tid==0) sred[5] = rsqrtf((sred[0]+sred[1]+sred[2]+sred[3])*(1.0f/DMODEL) + LN_EPS);
  __syncthreads();
  float rs = sred[5];
  const float2 gg = ((const float2*)g)[tid];
  const float2 bb = ((const float2*)bv)[tid];
  float o0 = dx*rs*gg.x + bb.x;
  float o1 = dy*rs*gg.y + bb.y;
  if constexpr (sizeof(OT)==2){
    ushort2 o2; o2.x = f2bf(o0); o2.y = f2bf(o1);
    ((ushort2*)(out + (size_t)t*DMODEL))[tid] = o2;
  } else {
    ((float2*)(out + (size_t)t*DMODEL))[tid] = make_float2(o0, o1);
  }
}

// ---------------- generic GEMM: C[M,N] = A[M,K] @ B[K,N], epilogues ----------------
// MODE 1: split-head bf16 write [b,h,n,dh]   2: C(f32) += acc + bias   3: C(bf16) = gelu(acc+bias)
template<typename AT, int MODE>
__global__ void k_gemm(const AT* __restrict__ A, const float* __restrict__ Bw,
                       const float* __restrict__ bias, void* __restrict__ Cv,
                       int Nc, int K){
  __shared__ float As[16][64];
  __shared__ float Bs[16][64];
  int tid = threadIdx.x;
  int tx = tid & 15, ty = tid >> 4;
  float acc[4][4];
  #pragma unroll
  for(int i=0;i<4;i++)
    #pragma unroll
    for(int j=0;j<4;j++) acc[i][j]=0.f;
  int ar = tid >> 2, ac = (tid & 3) << 2;
  int br = tid >> 4, bc = (tid & 15) << 2;
  const AT* Ap = A + (size_t)(blockIdx.y*64 + ar)*K + ac;
  const float* Bp = Bw + (size_t)br*Nc + blockIdx.x*64 + bc;
  for(int k0=0;k0<K;k0+=16){
    float a0,a1,a2,a3;
    if constexpr (sizeof(AT)==2){
      ushort4 t4 = *(const ushort4*)(Ap + k0);
      a0=bf2f(t4.x); a1=bf2f(t4.y); a2=bf2f(t4.z); a3=bf2f(t4.w);
    } else {
      float4 t4 = *(const float4*)(Ap + k0);
      a0=t4.x; a1=t4.y; a2=t4.z; a3=t4.w;
    }
    float4 b4 = *(const float4*)(Bp + (size_t)k0*Nc);
    As[ac+0][ar]=a0; As[ac+1][ar]=a1; As[ac+2][ar]=a2; As[ac+3][ar]=a3;
    *(float4*)&Bs[br][bc] = b4;
    __syncthreads();
    #pragma unroll
    for(int kk=0;kk<16;kk++){
      float av[4], bb[4];
      #pragma unroll
      for(int i=0;i<4;i++) av[i]=As[kk][(ty<<2)+i];
      #pragma unroll
      for(int j=0;j<4;j++) bb[j]=Bs[kk][(tx<<2)+j];
      #pragma unroll
      for(int i=0;i<4;i++)
        #pragma unroll
        for(int j=0;j<4;j++) acc[i][j] += av[i]*bb[j];
    }
    __syncthreads();
  }
  int row0 = blockIdx.y*64 + (ty<<2);
  int col0 = blockIdx.x*64 + (tx<<2);
  #pragma unroll
  for(int i=0;i<4;i++){
    int row = row0 + i;
    #pragma unroll
    for(int j=0;j<4;j++){
      int col = col0 + j;
      if constexpr (MODE==1){
        int b = row >> 11, n = row & (SEQ-1);
        int h = col >> 6, dh = col & 63;
        ((u16*)Cv)[(((size_t)b*HNUM + h)*SEQ + n)*DHEAD + dh] = f2bf(acc[i][j]);
      } else if constexpr (MODE==2){
        size_t idx = (size_t)row*Nc + col;
        ((float*)Cv)[idx] += acc[i][j] + bias[col];
      } else {
        size_t idx = (size_t)row*Nc + col;
        float z = acc[i][j] + bias[col];
        ((u16*)Cv)[idx] = f2bf(0.5f*z*(1.0f + erff(z*0.70710678118654752f)));
      }
    }
  }
}

// ---------------- FAVOR+ features: u = (x*dn) @ proj^T for 32 rows per block ----------------
// PHASE 0: K max pass (atomic global max per bh).  PHASE 1: K exp pass (write kp bf16).
// PHASE 2: Q pass (row max stab, write qp bf16).
template<int PHASE>
__global__ void k_feat(const u16* __restrict__ xin, const float* __restrict__ proj,
                       u16* __restrict__ outp, float* __restrict__ kmax){
  __shared__ u16 pj[MFEAT][68];
  __shared__ float xs[32][68];
  __shared__ float dg[32];
  __shared__ float red[4][32];
  __shared__ float smax[32];
  int tid = threadIdx.x;
  int r0 = blockIdx.x * 32;            // global row (bh*SEQ + n), SEQ%32==0
  #pragma unroll
  for(int j=0;j<16;j++){
    int v4 = j*256 + tid;              // 4096 float4 = 256*64 floats of proj
    float4 p4 = ((const float4*)proj)[v4];
    int m = v4 >> 4, d = (v4 & 15) << 2;
    pj[m][d]=f2bf(p4.x); pj[m][d+1]=f2bf(p4.y); pj[m][d+2]=f2bf(p4.z); pj[m][d+3]=f2bf(p4.w);
  }
  #pragma unroll
  for(int j=0;j<2;j++){
    int v4 = j*256 + tid;              // 512 ushort4 = 32 rows * 64
    ushort4 x4 = ((const ushort4*)(xin + (size_t)r0*DHEAD))[v4];
    int n = v4 >> 4, d = (v4 & 15) << 2;
    xs[n][d]   = bf2f(x4.x)*DNRM;
    xs[n][d+1] = bf2f(x4.y)*DNRM;
    xs[n][d+2] = bf2f(x4.z)*DNRM;
    xs[n][d+3] = bf2f(x4.w)*DNRM;
  }
  __syncthreads();
  if constexpr (PHASE != 0){
    if(tid < 32){
      float s = 0.f;
      #pragma unroll
      for(int d=0;d<DHEAD;d++){ float t = xs[tid][d]; s += t*t; }
      dg[tid] = 0.5f*s;
    }
    __syncthreads();
  }
  float um[32];
  #pragma unroll
  for(int n=0;n<32;n++) um[n]=0.f;
  #pragma unroll
  for(int d4=0;d4<16;d4++){
    ushort4 p4 = *(const ushort4*)&pj[tid][d4<<2];
    float p0=bf2f(p4.x), p1=bf2f(p4.y), p2=bf2f(p4.z), p3=bf2f(p4.w);
    #pragma unroll
    for(int n=0;n<32;n++){
      float4 xv = *(const float4*)&xs[n][d4<<2];
      um[n] += xv.x*p0 + xv.y*p1 + xv.z*p2 + xv.w*p3;
    }
  }
  int lane = tid & 63, wid = tid >> 6;
  if constexpr (PHASE == 0){
    float mx = um[0];
    #pragma unroll
    for(int n=1;n<32;n++) mx = fmaxf(mx, um[n]);
    #pragma unroll
    for(int o=32;o;o>>=1) mx = fmaxf(mx, __shfl_xor(mx,o));
    if(lane==0) red[wid][0] = mx;
    __syncthreads();
    if(tid==0){
      float m2 = fmaxf(fmaxf(red[0][0],red[1][0]), fmaxf(red[2][0],red[3][0]));
      atomicMaxF(&kmax[blockIdx.x >> 6], m2);   // 64 blocks per bh
    }
  } else if constexpr (PHASE == 1){
    float km = kmax[blockIdx.x >> 6];
    #pragma unroll
    for(int n=0;n<32;n++){
      float val = SMF*(expf(um[n] - dg[n] - km) + EPSF);
      outp[(size_t)(r0+n)*MFEAT + tid] = f2bf(val);
    }
  } else {
    #pragma unroll
    for(int n=0;n<32;n++){
      float v = um[n];
      #pragma unroll
      for(int o=32;o;o>>=1) v = fmaxf(v, __shfl_xor(v,o));
      if(lane==0) red[wid][n] = v;
    }
    __syncthreads();
    if(tid<32) smax[tid] = fmaxf(fmaxf(red[0][tid],red[1][tid]), fmaxf(red[2][tid],red[3][tid]));
    __syncthreads();
    #pragma unroll
    for(int n=0;n<32;n++){
      float val = SMF*(expf(um[n] - dg[n] - smax[n]) + EPSF);
      outp[(size_t)(r0+n)*MFEAT + tid] = f2bf(val);
    }
  }
}

// ---------------- ksum[bh,m] = sum_n kp (no atomics, one block per bh) ----------------
__global__ void k_ksum(const u16* __restrict__ kp, float* __restrict__ ksum){
  int bh = blockIdx.x, m = threadIdx.x;
  const u16* p = kp + (size_t)bh*SEQ*MFEAT + m;
  float s = 0.f;
  #pragma unroll 8
  for(int n=0;n<SEQ;n++) s += bf2f(p[(size_t)n*MFEAT]);
  ksum[bh*MFEAT + m] = s;
}

// ---------------- ctx[bh,m,dh] = sum_n kp[bh,n,m] * v[bh,n,dh] ----------------
__global__ void k_ctx(const u16* __restrict__ kp, const u16* __restrict__ v,
                      float* __restrict__ ctx){
  __shared__ float As[32][64];   // [n_local][m_local]
  __shared__ float Bs[32][64];   // [n_local][dh]
  int tid = threadIdx.x;
  int tx = tid & 15, ty = tid >> 4;
  int bh = blockIdx.y, m0 = blockIdx.x*64;
  float acc[4][4];
  #pragma unroll
  for(int i=0;i<4;i++)
    #pragma unroll
    for(int j=0;j<4;j++) acc[i][j]=0.f;
  for(int n0=0;n0<SEQ;n0+=32){
    #pragma unroll
    for(int j=0;j<2;j++){
      int vv = j*256 + tid;
      int nl = vv >> 4, mg = (vv & 15) << 2;
      ushort4 u4 = *(const ushort4*)(kp + ((size_t)bh*SEQ + n0 + nl)*MFEAT + m0 + mg);
      As[nl][mg]=bf2f(u4.x); As[nl][mg+1]=bf2f(u4.y); As[nl][mg+2]=bf2f(u4.z); As[nl][mg+3]=bf2f(u4.w);
      ushort4 f4 = *(const ushort4*)(v + ((size_t)bh*SEQ + n0 + nl)*DHEAD + mg);
      Bs[nl][mg]=bf2f(f4.x); Bs[nl][mg+1]=bf2f(f4.y); Bs[nl][mg+2]=bf2f(f4.z); Bs[nl][mg+3]=bf2f(f4.w);
    }
    __syncthreads();
    #pragma unroll
    for(int kk=0;kk<32;kk++){
      float av[4], bb[4];
      #pragma unroll
      for(int i=0;i<4;i++) av[i]=As[kk][(ty<<2)+i];
      #pragma unroll
      for(int j=0;j<4;j++) bb[j]=Bs[kk][(tx<<2)+j];
      #pragma unroll
      for(int i=0;i<4;i++)
        #pragma unroll
        for(int j=0;j<4;j++) acc[i][j] += av[i]*bb[j];
    }
    __syncthreads();
  }
  #pragma unroll
  for(int i=0;i<4;i++)
    #pragma unroll
    for(int j=0;j<4;j++)
      ctx[((size_t)bh*MFEAT + m0 + (ty<<2)+i)*DHEAD + (tx<<2)+j] = acc[i][j];
}

// ---------------- o = (qp @ ctx) * 1/(qp . ksum), merged-head f32 write ----------------
__global__ void k_o(const u16* __restrict__ qp, const float* __restrict__ ctx,
                    const float* __restrict__ ksum, float* __restrict__ o){
  __shared__ float As[64][36];   // [n_local][m_local] padded
  __shared__ float Bs[32][64];   // [m_local][dh]
  __shared__ float Ks[32];
  int tid = threadIdx.x;
  int tx = tid & 15, ty = tid >> 4;
  int bh = blockIdx.y, n0 = blockIdx.x*64;
  int b = bh >> 3, h = bh & 7;
  float acc[4][4];
  float den[4] = {0.f,0.f,0.f,0.f};
  #pragma unroll
  for(int i=0;i<4;i++)
    #pragma unroll
    for(int j=0;j<4;j++) acc[i][j]=0.f;
  for(int k0=0;k0<MFEAT;k0+=32){
    #pragma unroll
    for(int j=0;j<2;j++){
      int vv = j*256 + tid;
      int nl = vv >> 3, mg = (vv & 7) << 2;
      ushort4 u4 = *(const ushort4*)(qp + ((size_t)bh*SEQ + n0 + nl)*MFEAT + k0 + mg);
      As[nl][mg]=bf2f(u4.x); As[nl][mg+1]=bf2f(u4.y); As[nl][mg+2]=bf2f(u4.z); As[nl][mg+3]=bf2f(u4.w);
      int kl = vv >> 4, dg = (vv & 15) << 2;
      float4 f4 = *(const float4*)(ctx + ((size_t)bh*MFEAT + k0 + kl)*DHEAD + dg);
      *(float4*)&Bs[kl][dg] = f4;
    }
    if(tid < 32) Ks[tid] = ksum[bh*MFEAT + k0 + tid];
    __syncthreads();
    #pragma unroll
    for(int kk=0;kk<32;kk++){
      float bb[4];
      #pragma unroll
      for(int j=0;j<4;j++) bb[j]=Bs[kk][(tx<<2)+j];
      float kv = Ks[kk];
      #pragma unroll
      for(int i=0;i<4;i++){
        float a = As[(ty<<2)+i][kk];
        den[i] += a*kv;
        #pragma unroll
        for(int j=0;j<4;j++) acc[i][j] += a*bb[j];
      }
    }
    __syncthreads();
  }
  #pragma unroll
  for(int i=0;i<4;i++){
    float di = 1.0f/den[i];
    int n = n0 + (ty<<2) + i;
    #pragma unroll
    for(int j=0;j<4;j++)
      o[((size_t)b*SEQ + n)*DMODEL + h*DHEAD + (tx<<2)+j] = acc[i][j]*di;
  }
}

__global__ void k_init(float* kmax){
  int i = threadIdx.x;
  if(i < BHN) kmax[i] = -INFINITY;
}

extern "C" void kernel_launch(void* const* d_in, const int* in_sizes, int n_in,
                              void* d_out, int out_size, void* d_ws, size_t ws_size,
                              hipStream_t stream){
  (void)in_sizes; (void)n_in; (void)out_size; (void)ws_size;
  const float* x    = (const float*)d_in[0];
  const float* proj = (const float*)d_in[1];
  const float* ln1g = (const float*)d_in[2];
  const float* ln1b = (const float*)d_in[3];
  const float* wq   = (const float*)d_in[4];
  const float* wk   = (const float*)d_in[5];
  const float* wv   = (const float*)d_in[6];
  const float* wo   = (const float*)d_in[7];
  const float* bo   = (const float*)d_in[8];
  const float* ln2g = (const float*)d_in[9];
  const float* ln2b = (const float*)d_in[10];
  const float* w1   = (const float*)d_in[11];
  const float* b1   = (const float*)d_in[12];
  const float* w2   = (const float*)d_in[13];
  const float* b2   = (const float*)d_in[14];
  float* xo = (float*)d_out;

  // workspace layout — total ~121.8 MB
  char* ws = (char*)d_ws;
  float* bufH  = (float*)ws;  ws += (size_t)TOK*DMODEL*4;      // 33.55 MB  h / o (f32)
  u16*   bufA  = (u16*)ws;    ws += (size_t)TOK*DMODEL*2;      // 16.78 MB  k/q/v/h2 (bf16)
  u16*   featb = (u16*)ws;    ws += (size_t)BHN*SEQ*MFEAT*2;   // 67.11 MB  kp -> qp -> ffn1 (bf16)
  float* ctx   = (float*)ws;  ws += (size_t)BHN*MFEAT*DHEAD*4; //  4.19 MB
  float* ksum  = (float*)ws;  ws += (size_t)BHN*MFEAT*4;       // 64 KB
  float* kmax  = (float*)ws;  ws += 256;

  k_addpe<<<(TOK*DMODEL)/256, 256, 0, stream>>>(x, xo);

  for(int l=0; l<LNUM; l++){
    const float* proj_l = proj + (size_t)l*MFEAT*DHEAD;
    const float* wq_l = wq + (size_t)l*DMODEL*DMODEL;
    const float* wk_l = wk + (size_t)l*DMODEL*DMODEL;
    const float* wv_l = wv + (size_t)l*DMODEL*DMODEL;
    const float* wo_l = wo + (size_t)l*DMODEL*DMODEL;
    const float* w1_l = w1 + (size_t)l*DMODEL*DFF;
    const float* w2_l = w2 + (size_t)l*DFF*DMODEL;

    k_init<<<1, 64, 0, stream>>>(kmax);
    k_ln<float><<<TOK, 256, 0, stream>>>(xo, ln1g + l*DMODEL, ln1b + l*DMODEL, bufH);
    // K path: k -> (max pass, exp pass) -> kp in featb
    k_gemm<float,1><<<dim3(8,256), 256, 0, stream>>>(bufH, wk_l, nullptr, bufA, DMODEL, DMODEL);
    k_feat<0><<<(BHN*SEQ)/32, 256, 0, stream>>>(bufA, proj_l, nullptr, kmax);
    k_feat<1><<<(BHN*SEQ)/32, 256, 0, stream>>>(bufA, proj_l, featb, kmax);
    k_ksum<<<BHN, 256, 0, stream>>>(featb, ksum);
    // V path (overwrites k in bufA — k is done)
    k_gemm<float,1><<<dim3(8,256), 256, 0, stream>>>(bufH, wv_l, nullptr, bufA, DMODEL, DMODEL);
    k_ctx<<<dim3(4,64), 256, 0, stream>>>(featb, bufA, ctx);
    // Q path (overwrites v — v is done; qp overwrites kp — kp is done)
    k_gemm<float,1><<<dim3(8,256), 256, 0, stream>>>(bufH, wq_l, nullptr, bufA, DMODEL, DMODEL);
    k_feat<2><<<(BHN*SEQ)/32, 256, 0, stream>>>(bufA, proj_l, featb, nullptr);
    k_o<<<dim3(32,64), 256, 0, stream>>>(featb, ctx, ksum, bufH);
    k_gemm<float,2><<<dim3(8,256), 256, 0, stream>>>(bufH, wo_l, bo + l*DMODEL, xo, DMODEL, DMODEL);
    // FFN (h2 bf16 in bufA; gelu hidden bf16 in featb)
    k_ln<u16><<<TOK, 256, 0, stream>>>(xo, ln2g + l*DMODEL, ln2b + l*DMODEL, bufA);
    k_gemm<u16,3><<<dim3(32,256), 256, 0, stream>>>(bufA, w1_l, b1 + l*DFF, featb, DFF, DMODEL);
    k_gemm<u16,2><<<dim3(8,256), 256, 0, stream>>>(featb, w2_l, b2 + l*DMODEL, xo, DMODEL, DFF);
  }
}

// Round 5
// 2791.748 us; speedup vs baseline: 12.3960x; 12.3960x over previous
//
#include <hip/hip_runtime.h>
#include <math.h>

#define LNUM 6
#define HNUM 8
#define DMODEL 512
#define DHEAD 64
#define MFEAT 256
#define BATCH 8
#define SEQ 2048
#define TOK (BATCH*SEQ)
#define BHN (BATCH*HNUM)
#define DFF 2048
#define EPSF 1e-4f
#define LN_EPS 1e-5f
#define DNRM 0.35355339059327373f
#define SMF 0.0625f

typedef unsigned short u16;
typedef __attribute__((ext_vector_type(8))) short bf16x8;
typedef __attribute__((ext_vector_type(4))) float f32x4;
#define MFMA16(a,b,c) __builtin_amdgcn_mfma_f32_16x16x32_bf16(a,b,c,0,0,0)

__device__ __forceinline__ u16 f2bf(float f){
  unsigned int u = __float_as_uint(f);
  u = (u + 0x7fffu + ((u >> 16) & 1u)) >> 16;
  return (u16)u;
}
__device__ __forceinline__ float bf2f(u16 s){
  return __uint_as_float(((unsigned int)s) << 16);
}
__device__ __forceinline__ void atomicMaxF(float* addr, float val){
  if(val >= 0.f) atomicMax((int*)addr, __float_as_int(val));
  else           atomicMin((unsigned int*)addr, __float_as_uint(val));
}

// ---------------- x = x + sinusoidal PE ----------------
__global__ void k_addpe(const float* __restrict__ x, float* __restrict__ xo){
  int idx = blockIdx.x*256 + threadIdx.x;
  int d = idx & (DMODEL-1);
  int n = (idx >> 9) & (SEQ-1);
  int j = d >> 1;
  float freq = expf((float)(2*j) * (-9.210340371976184f / (float)DMODEL));
  float ang = (float)n * freq;
  float pe = (d & 1) ? cosf(ang) : sinf(ang);
  xo[idx] = x[idx] + pe;
}

// ---------------- LayerNorm (512) -> bf16 ----------------
__global__ void k_ln(const float* __restrict__ x, const float* __restrict__ g,
                     const float* __restrict__ bv, u16* __restrict__ out){
  __shared__ float sred[8];
  int t = blockIdx.x, tid = threadIdx.x;
  const float2 v = ((const float2*)(x + (size_t)t*DMODEL))[tid];
  float s = v.x + v.y;
  #pragma unroll
  for(int o=32;o;o>>=1) s += __shfl_down(s,o);
  if((tid&63)==0) sred[tid>>6] = s;
  __syncthreads();
  if(tid==0) sred[4] = (sred[0]+sred[1]+sred[2]+sred[3]) * (1.0f/DMODEL);
  __syncthreads();
  float mu = sred[4];
  float dx = v.x - mu, dy = v.y - mu;
  float s2 = dx*dx + dy*dy;
  #pragma unroll
  for(int o=32;o;o>>=1) s2 += __shfl_down(s2,o);
  if((tid&63)==0) sred[tid>>6] = s2;
  __syncthreads();
  if(tid==0) sred[5] = rsqrtf((sred[0]+sred[1]+sred[2]+sred[3])*(1.0f/DMODEL) + LN_EPS);
  __syncthreads();
  float rs = sred[5];
  const float2 gg = ((const float2*)g)[tid];
  const float2 bb = ((const float2*)bv)[tid];
  ushort2 o2; o2.x = f2bf(dx*rs*gg.x + bb.x); o2.y = f2bf(dy*rs*gg.y + bb.y);
  ((ushort2*)(out + (size_t)t*DMODEL))[tid] = o2;
}

// ---------------- w[K][N] f32 -> wt[N][K] bf16 ----------------
__global__ void k_wcvt(const float* __restrict__ w, u16* __restrict__ wt, int K, int N){
  __shared__ float sm[64][65];
  int kt = blockIdx.y*64, nt = blockIdx.x*64;
  int t = threadIdx.x;
  int c = t & 63, r4 = t >> 6;
  #pragma unroll
  for(int i=0;i<16;i++){
    int kl = i*4 + r4;
    sm[kl][c] = w[(size_t)(kt+kl)*N + nt + c];
  }
  __syncthreads();
  #pragma unroll
  for(int i=0;i<16;i++){
    int nl = i*4 + r4;
    wt[(size_t)(nt+nl)*K + kt + c] = f2bf(sm[c][nl]);
  }
}

__global__ void k_pcvt(const float* __restrict__ p, u16* __restrict__ pb){
  int i = blockIdx.x*256 + threadIdx.x;
  pb[i] = f2bf(p[i]);
}

// ---------------- MFMA GEMM: C[M,Nc] = A[M,K](bf16) @ Bt[Nc,K]^T ----------------
// EPI 1: split-head bf16 [bh][n][dh]   2: f32 C += acc+bias
// EPI 3: bf16 C = gelu(acc+bias)       4: v_t bf16 [bh][dh][n]
template<int EPI>
__global__ __launch_bounds__(256)
void k_mm(const u16* __restrict__ A, const u16* __restrict__ Bt,
          const float* __restrict__ bias, void* __restrict__ Cv,
          int Nc, int K){
  __shared__ u16 As[128*64];
  __shared__ u16 Bs[128*64];
  int tid = threadIdx.x;
  int w = tid >> 6, lane = tid & 63;
  int wr = w >> 1, wc = w & 1;
  int hi = lane >> 4, li = lane & 15;
  int row0 = blockIdx.y*128, col0 = blockIdx.x*128;
  f32x4 acc[4][4] = {};
  for(int k0=0;k0<K;k0+=64){
    #pragma unroll
    for(int i=0;i<4;i++){
      int idx = i*256 + tid;
      int r = idx >> 3, c = idx & 7;
      bf16x8 va = *(const bf16x8*)(A  + (size_t)(row0+r)*K + k0 + c*8);
      *(bf16x8*)&As[r*64 + ((c ^ (r&7))<<3)] = va;
      bf16x8 vb = *(const bf16x8*)(Bt + (size_t)(col0+r)*K + k0 + c*8);
      *(bf16x8*)&Bs[r*64 + ((c ^ (r&7))<<3)] = vb;
    }
    __syncthreads();
    #pragma unroll
    for(int ks=0;ks<2;ks++){
      bf16x8 af[4], bfr[4];
      int kc = ks*4 + hi;
      #pragma unroll
      for(int t=0;t<4;t++){
        int ar = wr*64 + t*16 + li;
        af[t] = *(const bf16x8*)&As[ar*64 + ((kc ^ (ar&7))<<3)];
        int bc = wc*64 + t*16 + li;
        bfr[t] = *(const bf16x8*)&Bs[bc*64 + ((kc ^ (bc&7))<<3)];
      }
      #pragma unroll
      for(int i2=0;i2<4;i2++)
        #pragma unroll
        for(int j2=0;j2<4;j2++)
          acc[i2][j2] = MFMA16(af[i2], bfr[j2], acc[i2][j2]);
    }
    __syncthreads();
  }
  #pragma unroll
  for(int i2=0;i2<4;i2++){
    #pragma unroll
    for(int j2=0;j2<4;j2++){
      int col = col0 + wc*64 + j2*16 + li;
      float bcol = (EPI==2 || EPI==3) ? bias[col] : 0.f;
      if constexpr (EPI==4){
        int nb = row0 + wr*64 + i2*16 + hi*4;
        int b = nb >> 11, n = nb & (SEQ-1);
        int h = col >> 6, dh = col & 63;
        ushort4 pk;
        pk.x = f2bf(acc[i2][j2][0]); pk.y = f2bf(acc[i2][j2][1]);
        pk.z = f2bf(acc[i2][j2][2]); pk.w = f2bf(acc[i2][j2][3]);
        *(ushort4*)((u16*)Cv + (((size_t)(b*HNUM+h)*DHEAD + dh)*SEQ + n)) = pk;
      } else {
        #pragma unroll
        for(int r=0;r<4;r++){
          int row = row0 + wr*64 + i2*16 + hi*4 + r;
          float v = acc[i2][j2][r];
          if constexpr (EPI==1){
            int b = row >> 11, n = row & (SEQ-1);
            int h = col >> 6, dh = col & 63;
            ((u16*)Cv)[((size_t)(b*HNUM+h)*SEQ + n)*DHEAD + dh] = f2bf(v);
          } else if constexpr (EPI==2){
            ((float*)Cv)[(size_t)row*Nc + col] += v + bcol;
          } else {
            float z = v + bcol;
            ((u16*)Cv)[(size_t)row*Nc + col] = f2bf(0.5f*z*(1.0f + erff(z*0.70710678118654752f)));
          }
        }
      }
    }
  }
}

// ---------------- FAVOR+ features via MFMA; 32 rows x 256 feats per block ----------------
// PHASE 0: global max per bh (atomic).  PHASE 1: kp_t[bh][m][n] bf16.
// PHASE 2: qp[row][m] bf16 + den = qp.ksum.
template<int PHASE>
__global__ __launch_bounds__(256)
void k_feat(const u16* __restrict__ xg, const u16* __restrict__ pjb,
            u16* __restrict__ outp, float* __restrict__ kmax,
            const float* __restrict__ ksum, float* __restrict__ den){
  __shared__ u16 pj[256*64];
  __shared__ u16 xs[32*64];
  __shared__ float dgs[32];
  __shared__ float wred[4][32];
  __shared__ float wden[4][32];
  __shared__ float ksl[256];
  int tid = threadIdx.x, w = tid >> 6, lane = tid & 63;
  int hi = lane >> 4, li = lane & 15;
  int r0 = blockIdx.x * 32;        // global feature row = bh*SEQ + n0
  int bh = r0 >> 11;
  #pragma unroll
  for(int i=0;i<8;i++){
    int idx = i*256 + tid;
    int m = idx >> 3, c = idx & 7;
    bf16x8 v = *(const bf16x8*)(pjb + m*64 + c*8);
    *(bf16x8*)&pj[m*64 + ((c ^ (m&7))<<3)] = v;
  }
  {
    int m = tid >> 3, c = tid & 7;
    bf16x8 v = *(const bf16x8*)(xg + (size_t)(r0+m)*64 + c*8);
    *(bf16x8*)&xs[m*64 + ((c ^ (m&7))<<3)] = v;
  }
  if constexpr (PHASE==2){ ksl[tid] = ksum[bh*MFEAT + tid]; }
  __syncthreads();
  if constexpr (PHASE!=0){
    if(tid < 32){
      // sum of squares is invariant under the chunk swizzle (in-row permutation)
      float s = 0.f;
      #pragma unroll
      for(int d=0;d<64;d++){ float t = bf2f(xs[tid*64 + d]); s += t*t; }
      dgs[tid] = 0.5f*DNRM*DNRM*s;
    }
  }
  f32x4 acc[2][4] = {};
  #pragma unroll
  for(int ks=0;ks<2;ks++){
    bf16x8 af[2], bfr[4];
    int kc = ks*4 + hi;
    #pragma unroll
    for(int t=0;t<2;t++){
      int ar = t*16 + li;
      af[t] = *(const bf16x8*)&xs[ar*64 + ((kc ^ (ar&7))<<3)];
    }
    #pragma unroll
    for(int t=0;t<4;t++){
      int bc = w*64 + t*16 + li;
      bfr[t] = *(const bf16x8*)&pj[bc*64 + ((kc ^ (bc&7))<<3)];
    }
    #pragma unroll
    for(int i2=0;i2<2;i2++)
      #pragma unroll
      for(int j2=0;j2<4;j2++)
        acc[i2][j2] = MFMA16(af[i2], bfr[j2], acc[i2][j2]);
  }
  __syncthreads();   // dgs ready, MFMA results in regs
  if constexpr (PHASE==0){
    float mx = -1e30f;
    #pragma unroll
    for(int i2=0;i2<2;i2++)
      #pragma unroll
      for(int j2=0;j2<4;j2++)
        #pragma unroll
        for(int r=0;r<4;r++) mx = fmaxf(mx, acc[i2][j2][r]);
    #pragma unroll
    for(int o=32;o;o>>=1) mx = fmaxf(mx, __shfl_xor(mx,o));
    if(lane==0) wred[w][0] = mx;
    __syncthreads();
    if(tid==0){
      float m2 = fmaxf(fmaxf(wred[0][0],wred[1][0]), fmaxf(wred[2][0],wred[3][0]));
      atomicMaxF(&kmax[bh], m2*DNRM);
    }
  } else if constexpr (PHASE==1){
    float km = kmax[bh];
    #pragma unroll
    for(int i2=0;i2<2;i2++){
      #pragma unroll
      for(int j2=0;j2<4;j2++){
        int col = w*64 + j2*16 + li;
        ushort4 pk;
        #pragma unroll
        for(int r=0;r<4;r++){
          int rl = i2*16 + hi*4 + r;
          float u = acc[i2][j2][r]*DNRM;
          ((u16*)&pk)[r] = f2bf(SMF*(expf(u - dgs[rl] - km) + EPSF));
        }
        *(ushort4*)(outp + ((size_t)(bh*MFEAT + col)*SEQ + (r0 & (SEQ-1)) + i2*16 + hi*4)) = pk;
      }
    }
  } else {
    #pragma unroll
    for(int i2=0;i2<2;i2++){
      #pragma unroll
      for(int r=0;r<4;r++){
        float v = fmaxf(fmaxf(acc[i2][0][r],acc[i2][1][r]), fmaxf(acc[i2][2][r],acc[i2][3][r]));
        v = fmaxf(v, __shfl_xor(v,1)); v = fmaxf(v, __shfl_xor(v,2));
        v = fmaxf(v, __shfl_xor(v,4)); v = fmaxf(v, __shfl_xor(v,8));
        if(li==0) wred[w][i2*16 + hi*4 + r] = v;
      }
    }
    __syncthreads();
    #pragma unroll
    for(int i2=0;i2<2;i2++){
      #pragma unroll
      for(int r=0;r<4;r++){
        int rl = i2*16 + hi*4 + r;
        float rm = fmaxf(fmaxf(wred[0][rl],wred[1][rl]), fmaxf(wred[2][rl],wred[3][rl]));
        float dsum = 0.f;
        #pragma unroll
        for(int j2=0;j2<4;j2++){
          int col = w*64 + j2*16 + li;
          float u = acc[i2][j2][r]*DNRM;
          u16 eb = f2bf(SMF*(expf(u - dgs[rl] - rm) + EPSF));
          outp[((size_t)r0 + rl)*MFEAT + col] = eb;
          dsum += bf2f(eb)*ksl[col];
        }
        dsum += __shfl_xor(dsum,1); dsum += __shfl_xor(dsum,2);
        dsum += __shfl_xor(dsum,4); dsum += __shfl_xor(dsum,8);
        if(li==0) wden[w][rl] = dsum;
      }
    }
    __syncthreads();
    if(tid < 32) den[(size_t)r0 + tid] = wden[0][tid]+wden[1][tid]+wden[2][tid]+wden[3][tid];
  }
}

// ---------------- ksum[bh*256+m] = sum_n kp_t[m][n] ----------------
__global__ __launch_bounds__(256)
void k_ksum(const u16* __restrict__ kpt, float* __restrict__ ksum){
  int row = blockIdx.x*4 + (threadIdx.x>>6);
  int lane = threadIdx.x & 63;
  const u16* p = kpt + (size_t)row*SEQ;
  float s = 0.f;
  #pragma unroll
  for(int i=0;i<4;i++){
    bf16x8 v = *(const bf16x8*)(p + i*512 + lane*8);
    #pragma unroll
    for(int j=0;j<8;j++) s += bf2f((u16)v[j]);
  }
  #pragma unroll
  for(int o=32;o;o>>=1) s += __shfl_down(s,o);
  if(lane==0) ksum[row] = s;
}

// ---------------- ctx_t[bh][dh][m] = sum_n v_t[dh][n]*kp_t[m][n] ----------------
__global__ __launch_bounds__(256)
void k_ctx(const u16* __restrict__ vt, const u16* __restrict__ kpt,
           u16* __restrict__ ctxt){
  __shared__ u16 As[64*64];
  __shared__ u16 Bs[64*64];
  int tid = threadIdx.x, w = tid >> 6, lane = tid & 63;
  int wr = w >> 1, wc = w & 1;
  int hi = lane >> 4, li = lane & 15;
  int bh = blockIdx.y, mb = blockIdx.x*64;
  const u16* Ab = vt  + (size_t)bh*DHEAD*SEQ;
  const u16* Bb = kpt + ((size_t)bh*MFEAT + mb)*SEQ;
  f32x4 acc[2][2] = {};
  for(int k0=0;k0<SEQ;k0+=64){
    #pragma unroll
    for(int i=0;i<2;i++){
      int idx = i*256 + tid;
      int r = idx >> 3, c = idx & 7;
      bf16x8 va = *(const bf16x8*)(Ab + (size_t)r*SEQ + k0 + c*8);
      *(bf16x8*)&As[r*64 + ((c ^ (r&7))<<3)] = va;
      bf16x8 vb = *(const bf16x8*)(Bb + (size_t)r*SEQ + k0 + c*8);
      *(bf16x8*)&Bs[r*64 + ((c ^ (r&7))<<3)] = vb;
    }
    __syncthreads();
    #pragma unroll
    for(int ks=0;ks<2;ks++){
      bf16x8 af[2], bfr[2];
      int kc = ks*4 + hi;
      #pragma unroll
      for(int t=0;t<2;t++){
        int ar = wr*32 + t*16 + li;
        af[t] = *(const bf16x8*)&As[ar*64 + ((kc ^ (ar&7))<<3)];
        int bc = wc*32 + t*16 + li;
        bfr[t] = *(const bf16x8*)&Bs[bc*64 + ((kc ^ (bc&7))<<3)];
      }
      #pragma unroll
      for(int i2=0;i2<2;i2++)
        #pragma unroll
        for(int j2=0;j2<2;j2++)
          acc[i2][j2] = MFMA16(af[i2], bfr[j2], acc[i2][j2]);
    }
    __syncthreads();
  }
  #pragma unroll
  for(int i2=0;i2<2;i2++)
    #pragma unroll
    for(int j2=0;j2<2;j2++){
      int m = mb + wc*32 + j2*16 + li;
      #pragma unroll
      for(int r=0;r<4;r++){
        int dh = wr*32 + i2*16 + hi*4 + r;
        ctxt[((size_t)bh*DHEAD + dh)*MFEAT + m] = f2bf(acc[i2][j2][r]);
      }
    }
}

// ---------------- o[b][n][h*64+dh] = (qp @ ctx_t^T)/den, bf16 ----------------
__global__ __launch_bounds__(256)
void k_o(const u16* __restrict__ qp, const u16* __restrict__ ctxt,
         const float* __restrict__ den, u16* __restrict__ o){
  __shared__ u16 As[128*64];
  __shared__ u16 Bs[64*64];
  int tid = threadIdx.x, w = tid >> 6, lane = tid & 63;
  int wr = w >> 1, wc = w & 1;
  int hi = lane >> 4, li = lane & 15;
  int bh = blockIdx.y, nb = blockIdx.x*128;
  int b = bh >> 3, h = bh & 7;
  const u16* Ab = qp   + ((size_t)bh*SEQ + nb)*MFEAT;
  const u16* Bb = ctxt + (size_t)bh*DHEAD*MFEAT;
  f32x4 acc[4][2] = {};
  for(int k0=0;k0<MFEAT;k0+=64){
    #pragma unroll
    for(int i=0;i<4;i++){
      int idx = i*256 + tid;
      int r = idx >> 3, c = idx & 7;
      bf16x8 va = *(const bf16x8*)(Ab + (size_t)r*MFEAT + k0 + c*8);
      *(bf16x8*)&As[r*64 + ((c ^ (r&7))<<3)] = va;
      if(i < 2){
        bf16x8 vb = *(const bf16x8*)(Bb + (size_t)r*MFEAT + k0 + c*8);
        *(bf16x8*)&Bs[r*64 + ((c ^ (r&7))<<3)] = vb;
      }
    }
    __syncthreads();
    #pragma unroll
    for(int ks=0;ks<2;ks++){
      bf16x8 af[4], bfr[2];
      int kc = ks*4 + hi;
      #pragma unroll
      for(int t=0;t<4;t++){
        int ar = wr*64 + t*16 + li;
        af[t] = *(const bf16x8*)&As[ar*64 + ((kc ^ (ar&7))<<3)];
      }
      #pragma unroll
      for(int t=0;t<2;t++){
        int bc = wc*32 + t*16 + li;
        bfr[t] = *(const bf16x8*)&Bs[bc*64 + ((kc ^ (bc&7))<<3)];
      }
      #pragma unroll
      for(int i2=0;i2<4;i2++)
        #pragma unroll
        for(int j2=0;j2<2;j2++)
          acc[i2][j2] = MFMA16(af[i2], bfr[j2], acc[i2][j2]);
    }
    __syncthreads();
  }
  #pragma unroll
  for(int i2=0;i2<4;i2++){
    #pragma unroll
    for(int r=0;r<4;r++){
      int n = nb + wr*64 + i2*16 + hi*4 + r;
      float di = 1.0f/den[(size_t)bh*SEQ + n];
      #pragma unroll
      for(int j2=0;j2<2;j2++){
        int dh = wc*32 + j2*16 + li;
        o[((size_t)b*SEQ + n)*DMODEL + h*DHEAD + dh] = f2bf(acc[i2][j2][r]*di);
      }
    }
  }
}

__global__ void k_init(float* kmax){
  int i = threadIdx.x;
  if(i < BHN) kmax[i] = -INFINITY;
}

extern "C" void kernel_launch(void* const* d_in, const int* in_sizes, int n_in,
                              void* d_out, int out_size, void* d_ws, size_t ws_size,
                              hipStream_t stream){
  (void)in_sizes; (void)n_in; (void)out_size; (void)ws_size;
  const float* x    = (const float*)d_in[0];
  const float* proj = (const float*)d_in[1];
  const float* ln1g = (const float*)d_in[2];
  const float* ln1b = (const float*)d_in[3];
  const float* wq   = (const float*)d_in[4];
  const float* wk   = (const float*)d_in[5];
  const float* wv   = (const float*)d_in[6];
  const float* wo   = (const float*)d_in[7];
  const float* bo   = (const float*)d_in[8];
  const float* ln2g = (const float*)d_in[9];
  const float* ln2b = (const float*)d_in[10];
  const float* w1   = (const float*)d_in[11];
  const float* b1   = (const float*)d_in[12];
  const float* w2   = (const float*)d_in[13];
  const float* b2   = (const float*)d_in[14];
  float* xo = (float*)d_out;

  // workspace ~110 MB
  char* ws = (char*)d_ws;
  u16* bufH  = (u16*)ws;  ws += (size_t)TOK*DMODEL*2;       // 16.78 MB  h / o (bf16)
  u16* bufA  = (u16*)ws;  ws += (size_t)TOK*DMODEL*2;       // 16.78 MB  k / v_t / q / h2 (bf16)
  u16* featb = (u16*)ws;  ws += (size_t)BHN*SEQ*MFEAT*2;    // 67.11 MB  kp_t / qp / ffn1 (bf16)
  u16* ctxt  = (u16*)ws;  ws += (size_t)BHN*DHEAD*MFEAT*2;  //  2.10 MB
  u16* wT    = (u16*)ws;  ws += (size_t)3*1048576*2;        //  6.29 MB  per-layer bf16 W^T
  u16* pjb   = (u16*)ws;  ws += (size_t)LNUM*MFEAT*DHEAD*2; //  0.19 MB
  float* ksum= (float*)ws; ws += (size_t)BHN*MFEAT*4;       // 64 KB
  float* den = (float*)ws; ws += (size_t)BHN*SEQ*4;         // 512 KB
  float* kmax= (float*)ws; ws += 256;

  u16* wqT = wT;                 // [512][512]
  u16* wkT = wT +  262144;
  u16* wvT = wT +  524288;
  u16* woT = wT +  786432;
  u16* w1T = wT + 1048576;       // [2048][512]
  u16* w2T = wT + 2097152;       // [512][2048]

  k_addpe<<<(TOK*DMODEL)/256, 256, 0, stream>>>(x, xo);
  k_pcvt<<<(LNUM*MFEAT*DHEAD)/256, 256, 0, stream>>>(proj, pjb);

  for(int l=0; l<LNUM; l++){
    const u16* pj_l = pjb + (size_t)l*MFEAT*DHEAD;
    k_wcvt<<<dim3(8,8),  256, 0, stream>>>(wq + (size_t)l*262144,  wqT, DMODEL, DMODEL);
    k_wcvt<<<dim3(8,8),  256, 0, stream>>>(wk + (size_t)l*262144,  wkT, DMODEL, DMODEL);
    k_wcvt<<<dim3(8,8),  256, 0, stream>>>(wv + (size_t)l*262144,  wvT, DMODEL, DMODEL);
    k_wcvt<<<dim3(8,8),  256, 0, stream>>>(wo + (size_t)l*262144,  woT, DMODEL, DMODEL);
    k_wcvt<<<dim3(32,8), 256, 0, stream>>>(w1 + (size_t)l*1048576, w1T, DMODEL, DFF);
    k_wcvt<<<dim3(8,32), 256, 0, stream>>>(w2 + (size_t)l*1048576, w2T, DFF, DMODEL);

    k_init<<<1, 64, 0, stream>>>(kmax);
    k_ln<<<TOK, 256, 0, stream>>>(xo, ln1g + l*DMODEL, ln1b + l*DMODEL, bufH);
    // K path: k -> kmax -> kp_t -> ksum
    k_mm<1><<<dim3(4,128), 256, 0, stream>>>(bufH, wkT, nullptr, bufA, DMODEL, DMODEL);
    k_feat<0><<<(BHN*SEQ)/32, 256, 0, stream>>>(bufA, pj_l, nullptr, kmax, nullptr, nullptr);
    k_feat<1><<<(BHN*SEQ)/32, 256, 0, stream>>>(bufA, pj_l, featb, kmax, nullptr, nullptr);
    k_ksum<<<(BHN*MFEAT)/4, 256, 0, stream>>>(featb, ksum);
    // V path: v_t -> ctx_t
    k_mm<4><<<dim3(4,128), 256, 0, stream>>>(bufH, wvT, nullptr, bufA, DMODEL, DMODEL);
    k_ctx<<<dim3(4,BHN), 256, 0, stream>>>(bufA, featb, ctxt);
    // Q path: q -> qp + den -> o -> wo-GEMM (residual add)
    k_mm<1><<<dim3(4,128), 256, 0, stream>>>(bufH, wqT, nullptr, bufA, DMODEL, DMODEL);
    k_feat<2><<<(BHN*SEQ)/32, 256, 0, stream>>>(bufA, pj_l, featb, nullptr, ksum, den);
    k_o<<<dim3(SEQ/128,BHN), 256, 0, stream>>>(featb, ctxt, den, bufH);
    k_mm<2><<<dim3(4,128), 256, 0, stream>>>(bufH, woT, bo + l*DMODEL, xo, DMODEL, DMODEL);
    // FFN
    k_ln<<<TOK, 256, 0, stream>>>(xo, ln2g + l*DMODEL, ln2b + l*DMODEL, bufA);
    k_mm<3><<<dim3(16,128), 256, 0, stream>>>(bufA, w1T, b1 + l*DFF, featb, DFF, DMODEL);
    k_mm<2><<<dim3(4,128), 256, 0, stream>>>(featb, w2T, b2 + l*DMODEL, xo, DMODEL, DFF);
  }
}

// Round 6
// 2730.671 us; speedup vs baseline: 12.6732x; 1.0224x over previous
//
#include <hip/hip_runtime.h>
#include <math.h>

#define LNUM 6
#define HNUM 8
#define DMODEL 512
#define DHEAD 64
#define MFEAT 256
#define BATCH 8
#define SEQ 2048
#define TOK (BATCH*SEQ)
#define BHN (BATCH*HNUM)
#define DFF 2048
#define EPSF 1e-4f
#define LN_EPS 1e-5f
#define DNRM 0.35355339059327373f
#define SMF 0.0625f

typedef unsigned short u16;
typedef __attribute__((ext_vector_type(8))) short bf16x8;
typedef __attribute__((ext_vector_type(4))) float f32x4;
#define MFMA16(a,b,c) __builtin_amdgcn_mfma_f32_16x16x32_bf16(a,b,c,0,0,0)

// async global->LDS, 16B per lane; LDS dest = wave-uniform base + lane*16
#define GLOAD16(g,l) __builtin_amdgcn_global_load_lds( \
    (const __attribute__((address_space(1))) void*)(g), \
    (__attribute__((address_space(3))) void*)(l), 16, 0, 0)

__device__ __forceinline__ u16 f2bf(float f){
  unsigned int u = __float_as_uint(f);
  u = (u + 0x7fffu + ((u >> 16) & 1u)) >> 16;
  return (u16)u;
}
__device__ __forceinline__ float bf2f(u16 s){
  return __uint_as_float(((unsigned int)s) << 16);
}
__device__ __forceinline__ void atomicMaxF(float* addr, float val){
  if(val >= 0.f) atomicMax((int*)addr, __float_as_int(val));
  else           atomicMin((unsigned int*)addr, __float_as_uint(val));
}

// ---------------- x = x + sinusoidal PE ----------------
__global__ void k_addpe(const float* __restrict__ x, float* __restrict__ xo){
  int idx = blockIdx.x*256 + threadIdx.x;
  int d = idx & (DMODEL-1);
  int n = (idx >> 9) & (SEQ-1);
  int j = d >> 1;
  float freq = expf((float)(2*j) * (-9.210340371976184f / (float)DMODEL));
  float ang = (float)n * freq;
  float pe = (d & 1) ? cosf(ang) : sinf(ang);
  xo[idx] = x[idx] + pe;
}

// ---------------- LayerNorm (512) -> bf16 ----------------
__global__ void k_ln(const float* __restrict__ x, const float* __restrict__ g,
                     const float* __restrict__ bv, u16* __restrict__ out){
  __shared__ float sred[8];
  int t = blockIdx.x, tid = threadIdx.x;
  const float2 v = ((const float2*)(x + (size_t)t*DMODEL))[tid];
  float s = v.x + v.y;
  #pragma unroll
  for(int o=32;o;o>>=1) s += __shfl_down(s,o);
  if((tid&63)==0) sred[tid>>6] = s;
  __syncthreads();
  if(tid==0) sred[4] = (sred[0]+sred[1]+sred[2]+sred[3]) * (1.0f/DMODEL);
  __syncthreads();
  float mu = sred[4];
  float dx = v.x - mu, dy = v.y - mu;
  float s2 = dx*dx + dy*dy;
  #pragma unroll
  for(int o=32;o;o>>=1) s2 += __shfl_down(s2,o);
  if((tid&63)==0) sred[tid>>6] = s2;
  __syncthreads();
  if(tid==0) sred[5] = rsqrtf((sred[0]+sred[1]+sred[2]+sred[3])*(1.0f/DMODEL) + LN_EPS);
  __syncthreads();
  float rs = sred[5];
  const float2 gg = ((const float2*)g)[tid];
  const float2 bb = ((const float2*)bv)[tid];
  ushort2 o2; o2.x = f2bf(dx*rs*gg.x + bb.x); o2.y = f2bf(dy*rs*gg.y + bb.y);
  ((ushort2*)(out + (size_t)t*DMODEL))[tid] = o2;
}

// ---------------- w[K][N] f32 -> wt[N][K] bf16 ----------------
__global__ void k_wcvt(const float* __restrict__ w, u16* __restrict__ wt, int K, int N){
  __shared__ float sm[64][65];
  int kt = blockIdx.y*64, nt = blockIdx.x*64;
  int t = threadIdx.x;
  int c = t & 63, r4 = t >> 6;
  #pragma unroll
  for(int i=0;i<16;i++){
    int kl = i*4 + r4;
    sm[kl][c] = w[(size_t)(kt+kl)*N + nt + c];
  }
  __syncthreads();
  #pragma unroll
  for(int i=0;i<16;i++){
    int nl = i*4 + r4;
    wt[(size_t)(nt+nl)*K + kt + c] = f2bf(sm[c][nl]);
  }
}

__global__ void k_pcvt(const float* __restrict__ p, u16* __restrict__ pb){
  int i = blockIdx.x*256 + threadIdx.x;
  pb[i] = f2bf(p[i]);
}

// ---------------- MFMA GEMM: C[M,Nc] = A[M,K](bf16) @ Bt[Nc,K]^T ----------------
// Staging: global_load_lds with pre-swizzled source. Linear LDS chunk (r,cs)
// holds global chunk cs^(r&7); per-lane source chunk (l&7)^(l>>3) is constant.
// EPI 1: split-head bf16 [bh][n][dh]   2: f32 C += acc+bias
// EPI 3: bf16 C = gelu(acc+bias)       4: v_t bf16 [bh][dh][n]
template<int EPI>
__global__ __launch_bounds__(256)
void k_mm(const u16* __restrict__ A, const u16* __restrict__ Bt,
          const float* __restrict__ bias, void* __restrict__ Cv,
          int Nc, int K){
  __shared__ u16 As[128*64];
  __shared__ u16 Bs[128*64];
  int tid = threadIdx.x;
  int w = tid >> 6, lane = tid & 63;
  int wr = w >> 1, wc = w & 1;
  int hi = lane >> 4, li = lane & 15;
  int row0 = blockIdx.y*128, col0 = blockIdx.x*128;
  int lr = lane >> 3;
  int lc = (lane & 7) ^ lr;
  const u16* gA = A  + (size_t)(row0 + w*8 + lr)*K + lc*8;
  const u16* gB = Bt + (size_t)(col0 + w*8 + lr)*K + lc*8;
  f32x4 acc[4][4] = {};
  for(int k0=0;k0<K;k0+=64){
    #pragma unroll
    for(int t=0;t<4;t++){
      GLOAD16(gA + (size_t)(t*32)*K + k0, &As[(t*4+w)*512]);
      GLOAD16(gB + (size_t)(t*32)*K + k0, &Bs[(t*4+w)*512]);
    }
    __syncthreads();
    #pragma unroll
    for(int ks=0;ks<2;ks++){
      bf16x8 af[4], bfr[4];
      int kc = ks*4 + hi;
      #pragma unroll
      for(int t=0;t<4;t++){
        int ar = wr*64 + t*16 + li;
        af[t] = *(const bf16x8*)&As[ar*64 + ((kc ^ (ar&7))<<3)];
        int bc = wc*64 + t*16 + li;
        bfr[t] = *(const bf16x8*)&Bs[bc*64 + ((kc ^ (bc&7))<<3)];
      }
      #pragma unroll
      for(int i2=0;i2<4;i2++)
        #pragma unroll
        for(int j2=0;j2<4;j2++)
          acc[i2][j2] = MFMA16(af[i2], bfr[j2], acc[i2][j2]);
    }
    __syncthreads();
  }
  #pragma unroll
  for(int i2=0;i2<4;i2++){
    #pragma unroll
    for(int j2=0;j2<4;j2++){
      int col = col0 + wc*64 + j2*16 + li;
      float bcol = (EPI==2 || EPI==3) ? bias[col] : 0.f;
      if constexpr (EPI==4){
        int nb = row0 + wr*64 + i2*16 + hi*4;
        int b = nb >> 11, n = nb & (SEQ-1);
        int h = col >> 6, dh = col & 63;
        ushort4 pk;
        pk.x = f2bf(acc[i2][j2][0]); pk.y = f2bf(acc[i2][j2][1]);
        pk.z = f2bf(acc[i2][j2][2]); pk.w = f2bf(acc[i2][j2][3]);
        *(ushort4*)((u16*)Cv + (((size_t)(b*HNUM+h)*DHEAD + dh)*SEQ + n)) = pk;
      } else {
        #pragma unroll
        for(int r=0;r<4;r++){
          int row = row0 + wr*64 + i2*16 + hi*4 + r;
          float v = acc[i2][j2][r];
          if constexpr (EPI==1){
            int b = row >> 11, n = row & (SEQ-1);
            int h = col >> 6, dh = col & 63;
            ((u16*)Cv)[((size_t)(b*HNUM+h)*SEQ + n)*DHEAD + dh] = f2bf(v);
          } else if constexpr (EPI==2){
            ((float*)Cv)[(size_t)row*Nc + col] += v + bcol;
          } else {
            float z = v + bcol;
            ((u16*)Cv)[(size_t)row*Nc + col] = f2bf(0.5f*z*(1.0f + erff(z*0.70710678118654752f)));
          }
        }
      }
    }
  }
}

// ---------------- FAVOR+ features via MFMA; 32 rows x 256 feats per block ----------------
// PHASE 0: global max per bh (atomic).  PHASE 1: kp_t[bh][m][n] bf16.
// PHASE 2: qp[row][m] bf16 + den = qp.ksum.
template<int PHASE>
__global__ __launch_bounds__(256)
void k_feat(const u16* __restrict__ xg, const u16* __restrict__ pjb,
            u16* __restrict__ outp, float* __restrict__ kmax,
            const float* __restrict__ ksum, float* __restrict__ den){
  __shared__ u16 pj[256*64];
  __shared__ u16 xs[32*64];
  __shared__ float dgs[32];
  __shared__ float wred[4][32];
  __shared__ float wden[4][32];
  __shared__ float ksl[256];
  int tid = threadIdx.x, w = tid >> 6, lane = tid & 63;
  int hi = lane >> 4, li = lane & 15;
  int r0 = blockIdx.x * 32;        // global feature row = bh*SEQ + n0
  int bh = r0 >> 11;
  #pragma unroll
  for(int i=0;i<8;i++){
    int idx = i*256 + tid;
    int m = idx >> 3, c = idx & 7;
    bf16x8 v = *(const bf16x8*)(pjb + m*64 + c*8);
    *(bf16x8*)&pj[m*64 + ((c ^ (m&7))<<3)] = v;
  }
  {
    int m = tid >> 3, c = tid & 7;
    bf16x8 v = *(const bf16x8*)(xg + (size_t)(r0+m)*64 + c*8);
    *(bf16x8*)&xs[m*64 + ((c ^ (m&7))<<3)] = v;
  }
  if constexpr (PHASE==2){ ksl[tid] = ksum[bh*MFEAT + tid]; }
  __syncthreads();
  if constexpr (PHASE!=0){
    if(tid < 32){
      float s = 0.f;
      #pragma unroll
      for(int d=0;d<64;d++){ float t = bf2f(xs[tid*64 + d]); s += t*t; }
      dgs[tid] = 0.5f*DNRM*DNRM*s;
    }
  }
  f32x4 acc[2][4] = {};
  #pragma unroll
  for(int ks=0;ks<2;ks++){
    bf16x8 af[2], bfr[4];
    int kc = ks*4 + hi;
    #pragma unroll
    for(int t=0;t<2;t++){
      int ar = t*16 + li;
      af[t] = *(const bf16x8*)&xs[ar*64 + ((kc ^ (ar&7))<<3)];
    }
    #pragma unroll
    for(int t=0;t<4;t++){
      int bc = w*64 + t*16 + li;
      bfr[t] = *(const bf16x8*)&pj[bc*64 + ((kc ^ (bc&7))<<3)];
    }
    #pragma unroll
    for(int i2=0;i2<2;i2++)
      #pragma unroll
      for(int j2=0;j2<4;j2++)
        acc[i2][j2] = MFMA16(af[i2], bfr[j2], acc[i2][j2]);
  }
  __syncthreads();
  if constexpr (PHASE==0){
    float mx = -1e30f;
    #pragma unroll
    for(int i2=0;i2<2;i2++)
      #pragma unroll
      for(int j2=0;j2<4;j2++)
        #pragma unroll
        for(int r=0;r<4;r++) mx = fmaxf(mx, acc[i2][j2][r]);
    #pragma unroll
    for(int o=32;o;o>>=1) mx = fmaxf(mx, __shfl_xor(mx,o));
    if(lane==0) wred[w][0] = mx;
    __syncthreads();
    if(tid==0){
      float m2 = fmaxf(fmaxf(wred[0][0],wred[1][0]), fmaxf(wred[2][0],wred[3][0]));
      atomicMaxF(&kmax[bh], m2*DNRM);
    }
  } else if constexpr (PHASE==1){
    float km = kmax[bh];
    #pragma unroll
    for(int i2=0;i2<2;i2++){
      #pragma unroll
      for(int j2=0;j2<4;j2++){
        int col = w*64 + j2*16 + li;
        ushort4 pk;
        #pragma unroll
        for(int r=0;r<4;r++){
          int rl = i2*16 + hi*4 + r;
          float u = acc[i2][j2][r]*DNRM;
          ((u16*)&pk)[r] = f2bf(SMF*(expf(u - dgs[rl] - km) + EPSF));
        }
        *(ushort4*)(outp + ((size_t)(bh*MFEAT + col)*SEQ + (r0 & (SEQ-1)) + i2*16 + hi*4)) = pk;
      }
    }
  } else {
    #pragma unroll
    for(int i2=0;i2<2;i2++){
      #pragma unroll
      for(int r=0;r<4;r++){
        float v = fmaxf(fmaxf(acc[i2][0][r],acc[i2][1][r]), fmaxf(acc[i2][2][r],acc[i2][3][r]));
        v = fmaxf(v, __shfl_xor(v,1)); v = fmaxf(v, __shfl_xor(v,2));
        v = fmaxf(v, __shfl_xor(v,4)); v = fmaxf(v, __shfl_xor(v,8));
        if(li==0) wred[w][i2*16 + hi*4 + r] = v;
      }
    }
    __syncthreads();
    #pragma unroll
    for(int i2=0;i2<2;i2++){
      #pragma unroll
      for(int r=0;r<4;r++){
        int rl = i2*16 + hi*4 + r;
        float rm = fmaxf(fmaxf(wred[0][rl],wred[1][rl]), fmaxf(wred[2][rl],wred[3][rl]));
        float dsum = 0.f;
        #pragma unroll
        for(int j2=0;j2<4;j2++){
          int col = w*64 + j2*16 + li;
          float u = acc[i2][j2][r]*DNRM;
          u16 eb = f2bf(SMF*(expf(u - dgs[rl] - rm) + EPSF));
          outp[((size_t)r0 + rl)*MFEAT + col] = eb;
          dsum += bf2f(eb)*ksl[col];
        }
        dsum += __shfl_xor(dsum,1); dsum += __shfl_xor(dsum,2);
        dsum += __shfl_xor(dsum,4); dsum += __shfl_xor(dsum,8);
        if(li==0) wden[w][rl] = dsum;
      }
    }
    __syncthreads();
    if(tid < 32) den[(size_t)r0 + tid] = wden[0][tid]+wden[1][tid]+wden[2][tid]+wden[3][tid];
  }
}

// ---------------- ksum[bh*256+m] = sum_n kp_t[m][n] ----------------
__global__ __launch_bounds__(256)
void k_ksum(const u16* __restrict__ kpt, float* __restrict__ ksum){
  int row = blockIdx.x*4 + (threadIdx.x>>6);
  int lane = threadIdx.x & 63;
  const u16* p = kpt + (size_t)row*SEQ;
  float s = 0.f;
  #pragma unroll
  for(int i=0;i<4;i++){
    bf16x8 v = *(const bf16x8*)(p + i*512 + lane*8);
    #pragma unroll
    for(int j=0;j<8;j++) s += bf2f((u16)v[j]);
  }
  #pragma unroll
  for(int o=32;o;o>>=1) s += __shfl_down(s,o);
  if(lane==0) ksum[row] = s;
}

// ---------------- ctx_t[bh][dh][m] = sum_n v_t[dh][n]*kp_t[m][n] ----------------
__global__ __launch_bounds__(256)
void k_ctx(const u16* __restrict__ vt, const u16* __restrict__ kpt,
           u16* __restrict__ ctxt){
  __shared__ u16 As[64*64];
  __shared__ u16 Bs[64*64];
  int tid = threadIdx.x, w = tid >> 6, lane = tid & 63;
  int wr = w >> 1, wc = w & 1;
  int hi = lane >> 4, li = lane & 15;
  int bh = blockIdx.y, mb = blockIdx.x*64;
  int lr = lane >> 3;
  int lc = (lane & 7) ^ lr;
  const u16* gA = vt  + (size_t)bh*DHEAD*SEQ + (size_t)(w*8 + lr)*SEQ + lc*8;
  const u16* gB = kpt + ((size_t)bh*MFEAT + mb + w*8 + lr)*SEQ + lc*8;
  f32x4 acc[2][2] = {};
  for(int k0=0;k0<SEQ;k0+=64){
    #pragma unroll
    for(int t=0;t<2;t++){
      GLOAD16(gA + (size_t)(t*32)*SEQ + k0, &As[(t*4+w)*512]);
      GLOAD16(gB + (size_t)(t*32)*SEQ + k0, &Bs[(t*4+w)*512]);
    }
    __syncthreads();
    #pragma unroll
    for(int ks=0;ks<2;ks++){
      bf16x8 af[2], bfr[2];
      int kc = ks*4 + hi;
      #pragma unroll
      for(int t=0;t<2;t++){
        int ar = wr*32 + t*16 + li;
        af[t] = *(const bf16x8*)&As[ar*64 + ((kc ^ (ar&7))<<3)];
        int bc = wc*32 + t*16 + li;
        bfr[t] = *(const bf16x8*)&Bs[bc*64 + ((kc ^ (bc&7))<<3)];
      }
      #pragma unroll
      for(int i2=0;i2<2;i2++)
        #pragma unroll
        for(int j2=0;j2<2;j2++)
          acc[i2][j2] = MFMA16(af[i2], bfr[j2], acc[i2][j2]);
    }
    __syncthreads();
  }
  #pragma unroll
  for(int i2=0;i2<2;i2++)
    #pragma unroll
    for(int j2=0;j2<2;j2++){
      int m = mb + wc*32 + j2*16 + li;
      #pragma unroll
      for(int r=0;r<4;r++){
        int dh = wr*32 + i2*16 + hi*4 + r;
        ctxt[((size_t)bh*DHEAD + dh)*MFEAT + m] = f2bf(acc[i2][j2][r]);
      }
    }
}

// ---------------- o[b][n][h*64+dh] = (qp @ ctx_t^T)/den, bf16 ----------------
__global__ __launch_bounds__(256)
void k_o(const u16* __restrict__ qp, const u16* __restrict__ ctxt,
         const float* __restrict__ den, u16* __restrict__ o){
  __shared__ u16 As[128*64];
  __shared__ u16 Bs[64*64];
  int tid = threadIdx.x, w = tid >> 6, lane = tid & 63;
  int wr = w >> 1, wc = w & 1;
  int hi = lane >> 4, li = lane & 15;
  int bh = blockIdx.y, nb = blockIdx.x*128;
  int b = bh >> 3, h = bh & 7;
  int lr = lane >> 3;
  int lc = (lane & 7) ^ lr;
  const u16* gA = qp   + ((size_t)bh*SEQ + nb + w*8 + lr)*MFEAT + lc*8;
  const u16* gB = ctxt + (size_t)bh*DHEAD*MFEAT + (size_t)(w*8 + lr)*MFEAT + lc*8;
  f32x4 acc[4][2] = {};
  for(int k0=0;k0<MFEAT;k0+=64){
    #pragma unroll
    for(int t=0;t<4;t++){
      GLOAD16(gA + (size_t)(t*32)*MFEAT + k0, &As[(t*4+w)*512]);
      if(t < 2) GLOAD16(gB + (size_t)(t*32)*MFEAT + k0, &Bs[(t*4+w)*512]);
    }
    __syncthreads();
    #pragma unroll
    for(int ks=0;ks<2;ks++){
      bf16x8 af[4], bfr[2];
      int kc = ks*4 + hi;
      #pragma unroll
      for(int t=0;t<4;t++){
        int ar = wr*64 + t*16 + li;
        af[t] = *(const bf16x8*)&As[ar*64 + ((kc ^ (ar&7))<<3)];
      }
      #pragma unroll
      for(int t=0;t<2;t++){
        int bc = wc*32 + t*16 + li;
        bfr[t] = *(const bf16x8*)&Bs[bc*64 + ((kc ^ (bc&7))<<3)];
      }
      #pragma unroll
      for(int i2=0;i2<4;i2++)
        #pragma unroll
        for(int j2=0;j2<2;j2++)
          acc[i2][j2] = MFMA16(af[i2], bfr[j2], acc[i2][j2]);
    }
    __syncthreads();
  }
  #pragma unroll
  for(int i2=0;i2<4;i2++){
    #pragma unroll
    for(int r=0;r<4;r++){
      int n = nb + wr*64 + i2*16 + hi*4 + r;
      float di = 1.0f/den[(size_t)bh*SEQ + n];
      #pragma unroll
      for(int j2=0;j2<2;j2++){
        int dh = wc*32 + j2*16 + li;
        o[((size_t)b*SEQ + n)*DMODEL + h*DHEAD + dh] = f2bf(acc[i2][j2][r]*di);
      }
    }
  }
}

__global__ void k_init(float* kmax){
  int i = threadIdx.x;
  if(i < BHN) kmax[i] = -INFINITY;
}

extern "C" void kernel_launch(void* const* d_in, const int* in_sizes, int n_in,
                              void* d_out, int out_size, void* d_ws, size_t ws_size,
                              hipStream_t stream){
  (void)in_sizes; (void)n_in; (void)out_size; (void)ws_size;
  const float* x    = (const float*)d_in[0];
  const float* proj = (const float*)d_in[1];
  const float* ln1g = (const float*)d_in[2];
  const float* ln1b = (const float*)d_in[3];
  const float* wq   = (const float*)d_in[4];
  const float* wk   = (const float*)d_in[5];
  const float* wv   = (const float*)d_in[6];
  const float* wo   = (const float*)d_in[7];
  const float* bo   = (const float*)d_in[8];
  const float* ln2g = (const float*)d_in[9];
  const float* ln2b = (const float*)d_in[10];
  const float* w1   = (const float*)d_in[11];
  const float* b1   = (const float*)d_in[12];
  const float* w2   = (const float*)d_in[13];
  const float* b2   = (const float*)d_in[14];
  float* xo = (float*)d_out;

  // workspace ~110 MB
  char* ws = (char*)d_ws;
  u16* bufH  = (u16*)ws;  ws += (size_t)TOK*DMODEL*2;       // 16.78 MB  h / o (bf16)
  u16* bufA  = (u16*)ws;  ws += (size_t)TOK*DMODEL*2;       // 16.78 MB  k / v_t / q / h2 (bf16)
  u16* featb = (u16*)ws;  ws += (size_t)BHN*SEQ*MFEAT*2;    // 67.11 MB  kp_t / qp / ffn1 (bf16)
  u16* ctxt  = (u16*)ws;  ws += (size_t)BHN*DHEAD*MFEAT*2;  //  2.10 MB
  u16* wT    = (u16*)ws;  ws += (size_t)3*1048576*2;        //  6.29 MB  per-layer bf16 W^T
  u16* pjb   = (u16*)ws;  ws += (size_t)LNUM*MFEAT*DHEAD*2; //  0.19 MB
  float* ksum= (float*)ws; ws += (size_t)BHN*MFEAT*4;       // 64 KB
  float* den = (float*)ws; ws += (size_t)BHN*SEQ*4;         // 512 KB
  float* kmax= (float*)ws; ws += 256;

  u16* wqT = wT;                 // [512][512]
  u16* wkT = wT +  262144;
  u16* wvT = wT +  524288;
  u16* woT = wT +  786432;
  u16* w1T = wT + 1048576;       // [2048][512]
  u16* w2T = wT + 2097152;       // [512][2048]

  k_addpe<<<(TOK*DMODEL)/256, 256, 0, stream>>>(x, xo);
  k_pcvt<<<(LNUM*MFEAT*DHEAD)/256, 256, 0, stream>>>(proj, pjb);

  for(int l=0; l<LNUM; l++){
    const u16* pj_l = pjb + (size_t)l*MFEAT*DHEAD;
    k_wcvt<<<dim3(8,8),  256, 0, stream>>>(wq + (size_t)l*262144,  wqT, DMODEL, DMODEL);
    k_wcvt<<<dim3(8,8),  256, 0, stream>>>(wk + (size_t)l*262144,  wkT, DMODEL, DMODEL);
    k_wcvt<<<dim3(8,8),  256, 0, stream>>>(wv + (size_t)l*262144,  wvT, DMODEL, DMODEL);
    k_wcvt<<<dim3(8,8),  256, 0, stream>>>(wo + (size_t)l*262144,  woT, DMODEL, DMODEL);
    k_wcvt<<<dim3(32,8), 256, 0, stream>>>(w1 + (size_t)l*1048576, w1T, DMODEL, DFF);
    k_wcvt<<<dim3(8,32), 256, 0, stream>>>(w2 + (size_t)l*1048576, w2T, DFF, DMODEL);

    k_init<<<1, 64, 0, stream>>>(kmax);
    k_ln<<<TOK, 256, 0, stream>>>(xo, ln1g + l*DMODEL, ln1b + l*DMODEL, bufH);
    // K path: k -> kmax -> kp_t -> ksum
    k_mm<1><<<dim3(4,128), 256, 0, stream>>>(bufH, wkT, nullptr, bufA, DMODEL, DMODEL);
    k_feat<0><<<(BHN*SEQ)/32, 256, 0, stream>>>(bufA, pj_l, nullptr, kmax, nullptr, nullptr);
    k_feat<1><<<(BHN*SEQ)/32, 256, 0, stream>>>(bufA, pj_l, featb, kmax, nullptr, nullptr);
    k_ksum<<<(BHN*MFEAT)/4, 256, 0, stream>>>(featb, ksum);
    // V path: v_t -> ctx_t
    k_mm<4><<<dim3(4,128), 256, 0, stream>>>(bufH, wvT, nullptr, bufA, DMODEL, DMODEL);
    k_ctx<<<dim3(4,BHN), 256, 0, stream>>>(bufA, featb, ctxt);
    // Q path: q -> qp + den -> o -> wo-GEMM (residual add)
    k_mm<1><<<dim3(4,128), 256, 0, stream>>>(bufH, wqT, nullptr, bufA, DMODEL, DMODEL);
    k_feat<2><<<(BHN*SEQ)/32, 256, 0, stream>>>(bufA, pj_l, featb, nullptr, ksum, den);
    k_o<<<dim3(SEQ/128,BHN), 256, 0, stream>>>(featb, ctxt, den, bufH);
    k_mm<2><<<dim3(4,128), 256, 0, stream>>>(bufH, woT, bo + l*DMODEL, xo, DMODEL, DMODEL);
    // FFN
    k_ln<<<TOK, 256, 0, stream>>>(xo, ln2g + l*DMODEL, ln2b + l*DMODEL, bufA);
    k_mm<3><<<dim3(16,128), 256, 0, stream>>>(bufA, w1T, b1 + l*DFF, featb, DFF, DMODEL);
    k_mm<2><<<dim3(4,128), 256, 0, stream>>>(featb, w2T, b2 + l*DMODEL, xo, DMODEL, DFF);
  }
}

// Round 7
// 2550.647 us; speedup vs baseline: 13.5677x; 1.0706x over previous
//
#include <hip/hip_runtime.h>
#include <math.h>

#define LNUM 6
#define HNUM 8
#define DMODEL 512
#define DHEAD 64
#define MFEAT 256
#define BATCH 8
#define SEQ 2048
#define TOK (BATCH*SEQ)
#define BHN (BATCH*HNUM)
#define DFF 2048
#define EPSF 1e-4f
#define LN_EPS 1e-5f
#define DNRM 0.35355339059327373f
#define SMF 0.0625f

typedef unsigned short u16;
typedef __attribute__((ext_vector_type(8))) short bf16x8;
typedef __attribute__((ext_vector_type(4))) float f32x4;
#define MFMA16(a,b,c) __builtin_amdgcn_mfma_f32_16x16x32_bf16(a,b,c,0,0,0)

// async global->LDS, 16B per lane; LDS dest = wave-uniform base + lane*16
#define GLOAD16(g,l) __builtin_amdgcn_global_load_lds( \
    (const __attribute__((address_space(1))) void*)(g), \
    (__attribute__((address_space(3))) void*)(l), 16, 0, 0)

__device__ __forceinline__ u16 f2bf(float f){
  unsigned int u = __float_as_uint(f);
  u = (u + 0x7fffu + ((u >> 16) & 1u)) >> 16;
  return (u16)u;
}
__device__ __forceinline__ float bf2f(u16 s){
  return __uint_as_float(((unsigned int)s) << 16);
}
__device__ __forceinline__ void atomicMaxF(float* addr, float val){
  if(val >= 0.f) atomicMax((int*)addr, __float_as_int(val));
  else           atomicMin((unsigned int*)addr, __float_as_uint(val));
}
// gelu tanh-approx: 0.5 z (1+tanh(c1 z + c2 z^3)) = z * sigmoid(2*(c1 z + c2 z^3))
__device__ __forceinline__ float fast_gelu(float z){
  float g2 = z*(1.5957691216f + 0.07135481628f*z*z);
  return z / (1.0f + __expf(-g2));
}

// ---------------- x = x + sinusoidal PE ----------------
__global__ void k_addpe(const float* __restrict__ x, float* __restrict__ xo){
  int idx = blockIdx.x*256 + threadIdx.x;
  int d = idx & (DMODEL-1);
  int n = (idx >> 9) & (SEQ-1);
  int j = d >> 1;
  float freq = expf((float)(2*j) * (-9.210340371976184f / (float)DMODEL));
  float ang = (float)n * freq;
  float pe = (d & 1) ? cosf(ang) : sinf(ang);
  xo[idx] = x[idx] + pe;
}

// ---------------- LayerNorm (512) -> bf16 ----------------
__global__ void k_ln(const float* __restrict__ x, const float* __restrict__ g,
                     const float* __restrict__ bv, u16* __restrict__ out){
  __shared__ float sred[8];
  int t = blockIdx.x, tid = threadIdx.x;
  const float2 v = ((const float2*)(x + (size_t)t*DMODEL))[tid];
  float s = v.x + v.y;
  #pragma unroll
  for(int o=32;o;o>>=1) s += __shfl_down(s,o);
  if((tid&63)==0) sred[tid>>6] = s;
  __syncthreads();
  if(tid==0) sred[4] = (sred[0]+sred[1]+sred[2]+sred[3]) * (1.0f/DMODEL);
  __syncthreads();
  float mu = sred[4];
  float dx = v.x - mu, dy = v.y - mu;
  float s2 = dx*dx + dy*dy;
  #pragma unroll
  for(int o=32;o;o>>=1) s2 += __shfl_down(s2,o);
  if((tid&63)==0) sred[tid>>6] = s2;
  __syncthreads();
  if(tid==0) sred[5] = rsqrtf((sred[0]+sred[1]+sred[2]+sred[3])*(1.0f/DMODEL) + LN_EPS);
  __syncthreads();
  float rs = sred[5];
  const float2 gg = ((const float2*)g)[tid];
  const float2 bb = ((const float2*)bv)[tid];
  ushort2 o2; o2.x = f2bf(dx*rs*gg.x + bb.x); o2.y = f2bf(dy*rs*gg.y + bb.y);
  ((ushort2*)(out + (size_t)t*DMODEL))[tid] = o2;
}

// ---------------- w[K][N] f32 -> wt[N][K] bf16 ----------------
__global__ void k_wcvt(const float* __restrict__ w, u16* __restrict__ wt, int K, int N){
  __shared__ float sm[64][65];
  int kt = blockIdx.y*64, nt = blockIdx.x*64;
  int t = threadIdx.x;
  int c = t & 63, r4 = t >> 6;
  #pragma unroll
  for(int i=0;i<16;i++){
    int kl = i*4 + r4;
    sm[kl][c] = w[(size_t)(kt+kl)*N + nt + c];
  }
  __syncthreads();
  #pragma unroll
  for(int i=0;i<16;i++){
    int nl = i*4 + r4;
    wt[(size_t)(nt+nl)*K + kt + c] = f2bf(sm[c][nl]);
  }
}

__global__ void k_pcvt(const float* __restrict__ p, u16* __restrict__ pb){
  int i = blockIdx.x*256 + threadIdx.x;
  pb[i] = f2bf(p[i]);
}

// ---------------- MFMA GEMM, BK=32, double-buffered 2-phase pipeline ----------------
// LDS[buf][r][c] (c = 8-u16 chunk 0..3) holds global chunk c ^ ((r>>1)&3).
// Staging source pre-swizzled (lane-constant chunk (l&3)^((l>>3)&3)); GLOAD dest linear.
// EPI 1: split-head bf16 [bh][n][dh]   2: f32 C += acc+bias
// EPI 3: bf16 C = gelu(acc+bias)       4: v_t bf16 [bh][dh][n]
template<int EPI>
__global__ __launch_bounds__(256)
void k_mm(const u16* __restrict__ A, const u16* __restrict__ Bt,
          const float* __restrict__ bias, void* __restrict__ Cv,
          int Nc, int K){
  __shared__ u16 As[2][128*32];
  __shared__ u16 Bs[2][128*32];
  int tid = threadIdx.x;
  int w = tid >> 6, lane = tid & 63;
  int wr = w >> 1, wc = w & 1;
  int hi = lane >> 4, li = lane & 15;
  int row0 = blockIdx.y*128, col0 = blockIdx.x*128;
  // staging: thread covers LDS row w*16+(lane>>2) (+64 for second issue), slot lane&3
  int lr = lane >> 2;
  int cs = (lane & 3) ^ ((lane >> 3) & 3);
  const u16* gA = A  + (size_t)(row0 + w*16 + lr)*K + cs*8;
  const u16* gB = Bt + (size_t)(col0 + w*16 + lr)*K + cs*8;
  f32x4 acc[4][4] = {};

#define STAGE_MM(b,k0) { \
    GLOAD16(gA + (k0),                    &As[b][(w*16)*32]);      \
    GLOAD16(gA + (size_t)64*K + (k0),     &As[b][(64+w*16)*32]);   \
    GLOAD16(gB + (k0),                    &Bs[b][(w*16)*32]);      \
    GLOAD16(gB + (size_t)64*K + (k0),     &Bs[b][(64+w*16)*32]); }

  int nk = K >> 5;
  STAGE_MM(0, 0)
  __builtin_amdgcn_sched_barrier(0);
  asm volatile("s_waitcnt vmcnt(0)");
  __builtin_amdgcn_s_barrier();
  __builtin_amdgcn_sched_barrier(0);
  int cur = 0;
  for(int t=0; t<nk; ++t){
    if(t+1 < nk){ STAGE_MM(cur^1, (size_t)(t+1)*32) }
    bf16x8 af[4], bfr[4];
    #pragma unroll
    for(int q=0;q<4;q++){
      int ar = wr*64 + q*16 + li;
      af[q]  = *(const bf16x8*)&As[cur][ar*32 + ((hi ^ ((ar>>1)&3))<<3)];
      int bc = wc*64 + q*16 + li;
      bfr[q] = *(const bf16x8*)&Bs[cur][bc*32 + ((hi ^ ((bc>>1)&3))<<3)];
    }
    #pragma unroll
    for(int i2=0;i2<4;i2++)
      #pragma unroll
      for(int j2=0;j2<4;j2++)
        acc[i2][j2] = MFMA16(af[i2], bfr[j2], acc[i2][j2]);
    __builtin_amdgcn_sched_barrier(0);
    asm volatile("s_waitcnt vmcnt(0)");
    __builtin_amdgcn_s_barrier();
    __builtin_amdgcn_sched_barrier(0);
    cur ^= 1;
  }
#undef STAGE_MM

  #pragma unroll
  for(int i2=0;i2<4;i2++){
    #pragma unroll
    for(int j2=0;j2<4;j2++){
      int col = col0 + wc*64 + j2*16 + li;
      float bcol = (EPI==2 || EPI==3) ? bias[col] : 0.f;
      if constexpr (EPI==4){
        int nb = row0 + wr*64 + i2*16 + hi*4;
        int b = nb >> 11, n = nb & (SEQ-1);
        int h = col >> 6, dh = col & 63;
        ushort4 pk;
        pk.x = f2bf(acc[i2][j2][0]); pk.y = f2bf(acc[i2][j2][1]);
        pk.z = f2bf(acc[i2][j2][2]); pk.w = f2bf(acc[i2][j2][3]);
        *(ushort4*)((u16*)Cv + (((size_t)(b*HNUM+h)*DHEAD + dh)*SEQ + n)) = pk;
      } else {
        #pragma unroll
        for(int r=0;r<4;r++){
          int row = row0 + wr*64 + i2*16 + hi*4 + r;
          float v = acc[i2][j2][r];
          if constexpr (EPI==1){
            int b = row >> 11, n = row & (SEQ-1);
            int h = col >> 6, dh = col & 63;
            ((u16*)Cv)[((size_t)(b*HNUM+h)*SEQ + n)*DHEAD + dh] = f2bf(v);
          } else if constexpr (EPI==2){
            ((float*)Cv)[(size_t)row*Nc + col] += v + bcol;
          } else {
            ((u16*)Cv)[(size_t)row*Nc + col] = f2bf(fast_gelu(v + bcol));
          }
        }
      }
    }
  }
}

// ---------------- FAVOR+ features via MFMA; 32 rows x 256 feats per block ----------------
// PHASE 0: global max per bh (atomic).  PHASE 1: kp_t[bh][m][n] bf16.
// PHASE 2: qp[row][m] bf16 + den = qp.ksum.
template<int PHASE>
__global__ __launch_bounds__(256)
void k_feat(const u16* __restrict__ xg, const u16* __restrict__ pjb,
            u16* __restrict__ outp, float* __restrict__ kmax,
            const float* __restrict__ ksum, float* __restrict__ den){
  __shared__ u16 pj[256*64];
  __shared__ u16 xs[32*64];
  __shared__ float dgs[32];
  __shared__ float wred[4][32];
  __shared__ float wden[4][32];
  __shared__ float ksl[256];
  int tid = threadIdx.x, w = tid >> 6, lane = tid & 63;
  int hi = lane >> 4, li = lane & 15;
  int r0 = blockIdx.x * 32;        // global feature row = bh*SEQ + n0
  int bh = r0 >> 11;
  #pragma unroll
  for(int i=0;i<8;i++){
    int idx = i*256 + tid;
    int m = idx >> 3, c = idx & 7;
    bf16x8 v = *(const bf16x8*)(pjb + m*64 + c*8);
    *(bf16x8*)&pj[m*64 + ((c ^ (m&7))<<3)] = v;
  }
  {
    int m = tid >> 3, c = tid & 7;
    bf16x8 v = *(const bf16x8*)(xg + (size_t)(r0+m)*64 + c*8);
    *(bf16x8*)&xs[m*64 + ((c ^ (m&7))<<3)] = v;
  }
  if constexpr (PHASE==2){ ksl[tid] = ksum[bh*MFEAT + tid]; }
  __syncthreads();
  if constexpr (PHASE!=0){
    if(tid < 32){
      float s = 0.f;
      #pragma unroll
      for(int d=0;d<64;d++){ float t = bf2f(xs[tid*64 + d]); s += t*t; }
      dgs[tid] = 0.5f*DNRM*DNRM*s;
    }
  }
  f32x4 acc[2][4] = {};
  #pragma unroll
  for(int ks=0;ks<2;ks++){
    bf16x8 af[2], bfr[4];
    int kc = ks*4 + hi;
    #pragma unroll
    for(int t=0;t<2;t++){
      int ar = t*16 + li;
      af[t] = *(const bf16x8*)&xs[ar*64 + ((kc ^ (ar&7))<<3)];
    }
    #pragma unroll
    for(int t=0;t<4;t++){
      int bc = w*64 + t*16 + li;
      bfr[t] = *(const bf16x8*)&pj[bc*64 + ((kc ^ (bc&7))<<3)];
    }
    #pragma unroll
    for(int i2=0;i2<2;i2++)
      #pragma unroll
      for(int j2=0;j2<4;j2++)
        acc[i2][j2] = MFMA16(af[i2], bfr[j2], acc[i2][j2]);
  }
  __syncthreads();
  if constexpr (PHASE==0){
    float mx = -1e30f;
    #pragma unroll
    for(int i2=0;i2<2;i2++)
      #pragma unroll
      for(int j2=0;j2<4;j2++)
        #pragma unroll
        for(int r=0;r<4;r++) mx = fmaxf(mx, acc[i2][j2][r]);
    #pragma unroll
    for(int o=32;o;o>>=1) mx = fmaxf(mx, __shfl_xor(mx,o));
    if(lane==0) wred[w][0] = mx;
    __syncthreads();
    if(tid==0){
      float m2 = fmaxf(fmaxf(wred[0][0],wred[1][0]), fmaxf(wred[2][0],wred[3][0]));
      atomicMaxF(&kmax[bh], m2*DNRM);
    }
  } else if constexpr (PHASE==1){
    float km = kmax[bh];
    #pragma unroll
    for(int i2=0;i2<2;i2++){
      #pragma unroll
      for(int j2=0;j2<4;j2++){
        int col = w*64 + j2*16 + li;
        ushort4 pk;
        #pragma unroll
        for(int r=0;r<4;r++){
          int rl = i2*16 + hi*4 + r;
          float u = acc[i2][j2][r]*DNRM;
          ((u16*)&pk)[r] = f2bf(SMF*(expf(u - dgs[rl] - km) + EPSF));
        }
        *(ushort4*)(outp + ((size_t)(bh*MFEAT + col)*SEQ + (r0 & (SEQ-1)) + i2*16 + hi*4)) = pk;
      }
    }
  } else {
    #pragma unroll
    for(int i2=0;i2<2;i2++){
      #pragma unroll
      for(int r=0;r<4;r++){
        float v = fmaxf(fmaxf(acc[i2][0][r],acc[i2][1][r]), fmaxf(acc[i2][2][r],acc[i2][3][r]));
        v = fmaxf(v, __shfl_xor(v,1)); v = fmaxf(v, __shfl_xor(v,2));
        v = fmaxf(v, __shfl_xor(v,4)); v = fmaxf(v, __shfl_xor(v,8));
        if(li==0) wred[w][i2*16 + hi*4 + r] = v;
      }
    }
    __syncthreads();
    #pragma unroll
    for(int i2=0;i2<2;i2++){
      #pragma unroll
      for(int r=0;r<4;r++){
        int rl = i2*16 + hi*4 + r;
        float rm = fmaxf(fmaxf(wred[0][rl],wred[1][rl]), fmaxf(wred[2][rl],wred[3][rl]));
        float dsum = 0.f;
        #pragma unroll
        for(int j2=0;j2<4;j2++){
          int col = w*64 + j2*16 + li;
          float u = acc[i2][j2][r]*DNRM;
          u16 eb = f2bf(SMF*(expf(u - dgs[rl] - rm) + EPSF));
          outp[((size_t)r0 + rl)*MFEAT + col] = eb;
          dsum += bf2f(eb)*ksl[col];
        }
        dsum += __shfl_xor(dsum,1); dsum += __shfl_xor(dsum,2);
        dsum += __shfl_xor(dsum,4); dsum += __shfl_xor(dsum,8);
        if(li==0) wden[w][rl] = dsum;
      }
    }
    __syncthreads();
    if(tid < 32) den[(size_t)r0 + tid] = wden[0][tid]+wden[1][tid]+wden[2][tid]+wden[3][tid];
  }
}

// ---------------- ksum[bh*256+m] = sum_n kp_t[m][n] ----------------
__global__ __launch_bounds__(256)
void k_ksum(const u16* __restrict__ kpt, float* __restrict__ ksum){
  int row = blockIdx.x*4 + (threadIdx.x>>6);
  int lane = threadIdx.x & 63;
  const u16* p = kpt + (size_t)row*SEQ;
  float s = 0.f;
  #pragma unroll
  for(int i=0;i<4;i++){
    bf16x8 v = *(const bf16x8*)(p + i*512 + lane*8);
    #pragma unroll
    for(int j=0;j<8;j++) s += bf2f((u16)v[j]);
  }
  #pragma unroll
  for(int o=32;o;o>>=1) s += __shfl_down(s,o);
  if(lane==0) ksum[row] = s;
}

// ---------------- ctx_t[bh][dh][m] = sum_n v_t[dh][n]*kp_t[m][n] ----------------
__global__ __launch_bounds__(256)
void k_ctx(const u16* __restrict__ vt, const u16* __restrict__ kpt,
           u16* __restrict__ ctxt){
  __shared__ u16 As[64*64];
  __shared__ u16 Bs[64*64];
  int tid = threadIdx.x, w = tid >> 6, lane = tid & 63;
  int wr = w >> 1, wc = w & 1;
  int hi = lane >> 4, li = lane & 15;
  int bh = blockIdx.y, mb = blockIdx.x*64;
  int lr = lane >> 3;
  int lc = (lane & 7) ^ lr;
  const u16* gA = vt  + (size_t)bh*DHEAD*SEQ + (size_t)(w*8 + lr)*SEQ + lc*8;
  const u16* gB = kpt + ((size_t)bh*MFEAT + mb + w*8 + lr)*SEQ + lc*8;
  f32x4 acc[2][2] = {};
  for(int k0=0;k0<SEQ;k0+=64){
    #pragma unroll
    for(int t=0;t<2;t++){
      GLOAD16(gA + (size_t)(t*32)*SEQ + k0, &As[(t*4+w)*512]);
      GLOAD16(gB + (size_t)(t*32)*SEQ + k0, &Bs[(t*4+w)*512]);
    }
    __syncthreads();
    #pragma unroll
    for(int ks=0;ks<2;ks++){
      bf16x8 af[2], bfr[2];
      int kc = ks*4 + hi;
      #pragma unroll
      for(int t=0;t<2;t++){
        int ar = wr*32 + t*16 + li;
        af[t] = *(const bf16x8*)&As[ar*64 + ((kc ^ (ar&7))<<3)];
        int bc = wc*32 + t*16 + li;
        bfr[t] = *(const bf16x8*)&Bs[bc*64 + ((kc ^ (bc&7))<<3)];
      }
      #pragma unroll
      for(int i2=0;i2<2;i2++)
        #pragma unroll
        for(int j2=0;j2<2;j2++)
          acc[i2][j2] = MFMA16(af[i2], bfr[j2], acc[i2][j2]);
    }
    __syncthreads();
  }
  #pragma unroll
  for(int i2=0;i2<2;i2++)
    #pragma unroll
    for(int j2=0;j2<2;j2++){
      int m = mb + wc*32 + j2*16 + li;
      #pragma unroll
      for(int r=0;r<4;r++){
        int dh = wr*32 + i2*16 + hi*4 + r;
        ctxt[((size_t)bh*DHEAD + dh)*MFEAT + m] = f2bf(acc[i2][j2][r]);
      }
    }
}

// ---------------- o[b][n][h*64+dh] = (qp @ ctx_t^T)/den, bf16 ----------------
__global__ __launch_bounds__(256)
void k_o(const u16* __restrict__ qp, const u16* __restrict__ ctxt,
         const float* __restrict__ den, u16* __restrict__ o){
  __shared__ u16 As[128*64];
  __shared__ u16 Bs[64*64];
  int tid = threadIdx.x, w = tid >> 6, lane = tid & 63;
  int wr = w >> 1, wc = w & 1;
  int hi = lane >> 4, li = lane & 15;
  int bh = blockIdx.y, nb = blockIdx.x*128;
  int b = bh >> 3, h = bh & 7;
  int lr = lane >> 3;
  int lc = (lane & 7) ^ lr;
  const u16* gA = qp   + ((size_t)bh*SEQ + nb + w*8 + lr)*MFEAT + lc*8;
  const u16* gB = ctxt + (size_t)bh*DHEAD*MFEAT + (size_t)(w*8 + lr)*MFEAT + lc*8;
  f32x4 acc[4][2] = {};
  for(int k0=0;k0<MFEAT;k0+=64){
    #pragma unroll
    for(int t=0;t<4;t++){
      GLOAD16(gA + (size_t)(t*32)*MFEAT + k0, &As[(t*4+w)*512]);
      if(t < 2) GLOAD16(gB + (size_t)(t*32)*MFEAT + k0, &Bs[(t*4+w)*512]);
    }
    __syncthreads();
    #pragma unroll
    for(int ks=0;ks<2;ks++){
      bf16x8 af[4], bfr[2];
      int kc = ks*4 + hi;
      #pragma unroll
      for(int t=0;t<4;t++){
        int ar = wr*64 + t*16 + li;
        af[t] = *(const bf16x8*)&As[ar*64 + ((kc ^ (ar&7))<<3)];
      }
      #pragma unroll
      for(int t=0;t<2;t++){
        int bc = wc*32 + t*16 + li;
        bfr[t] = *(const bf16x8*)&Bs[bc*64 + ((kc ^ (bc&7))<<3)];
      }
      #pragma unroll
      for(int i2=0;i2<4;i2++)
        #pragma unroll
        for(int j2=0;j2<2;j2++)
          acc[i2][j2] = MFMA16(af[i2], bfr[j2], acc[i2][j2]);
    }
    __syncthreads();
  }
  #pragma unroll
  for(int i2=0;i2<4;i2++){
    #pragma unroll
    for(int r=0;r<4;r++){
      int n = nb + wr*64 + i2*16 + hi*4 + r;
      float di = 1.0f/den[(size_t)bh*SEQ + n];
      #pragma unroll
      for(int j2=0;j2<2;j2++){
        int dh = wc*32 + j2*16 + li;
        o[((size_t)b*SEQ + n)*DMODEL + h*DHEAD + dh] = f2bf(acc[i2][j2][r]*di);
      }
    }
  }
}

__global__ void k_init(float* kmax){
  int i = threadIdx.x;
  if(i < BHN) kmax[i] = -INFINITY;
}

extern "C" void kernel_launch(void* const* d_in, const int* in_sizes, int n_in,
                              void* d_out, int out_size, void* d_ws, size_t ws_size,
                              hipStream_t stream){
  (void)in_sizes; (void)n_in; (void)out_size; (void)ws_size;
  const float* x    = (const float*)d_in[0];
  const float* proj = (const float*)d_in[1];
  const float* ln1g = (const float*)d_in[2];
  const float* ln1b = (const float*)d_in[3];
  const float* wq   = (const float*)d_in[4];
  const float* wk   = (const float*)d_in[5];
  const float* wv   = (const float*)d_in[6];
  const float* wo   = (const float*)d_in[7];
  const float* bo   = (const float*)d_in[8];
  const float* ln2g = (const float*)d_in[9];
  const float* ln2b = (const float*)d_in[10];
  const float* w1   = (const float*)d_in[11];
  const float* b1   = (const float*)d_in[12];
  const float* w2   = (const float*)d_in[13];
  const float* b2   = (const float*)d_in[14];
  float* xo = (float*)d_out;

  // workspace ~110 MB
  char* ws = (char*)d_ws;
  u16* bufH  = (u16*)ws;  ws += (size_t)TOK*DMODEL*2;       // 16.78 MB  h / o (bf16)
  u16* bufA  = (u16*)ws;  ws += (size_t)TOK*DMODEL*2;       // 16.78 MB  k / v_t / q / h2 (bf16)
  u16* featb = (u16*)ws;  ws += (size_t)BHN*SEQ*MFEAT*2;    // 67.11 MB  kp_t / qp / ffn1 (bf16)
  u16* ctxt  = (u16*)ws;  ws += (size_t)BHN*DHEAD*MFEAT*2;  //  2.10 MB
  u16* wT    = (u16*)ws;  ws += (size_t)3*1048576*2;        //  6.29 MB  per-layer bf16 W^T
  u16* pjb   = (u16*)ws;  ws += (size_t)LNUM*MFEAT*DHEAD*2; //  0.19 MB
  float* ksum= (float*)ws; ws += (size_t)BHN*MFEAT*4;       // 64 KB
  float* den = (float*)ws; ws += (size_t)BHN*SEQ*4;         // 512 KB
  float* kmax= (float*)ws; ws += 256;

  u16* wqT = wT;                 // [512][512]
  u16* wkT = wT +  262144;
  u16* wvT = wT +  524288;
  u16* woT = wT +  786432;
  u16* w1T = wT + 1048576;       // [2048][512]
  u16* w2T = wT + 2097152;       // [512][2048]

  k_addpe<<<(TOK*DMODEL)/256, 256, 0, stream>>>(x, xo);
  k_pcvt<<<(LNUM*MFEAT*DHEAD)/256, 256, 0, stream>>>(proj, pjb);

  for(int l=0; l<LNUM; l++){
    const u16* pj_l = pjb + (size_t)l*MFEAT*DHEAD;
    k_wcvt<<<dim3(8,8),  256, 0, stream>>>(wq + (size_t)l*262144,  wqT, DMODEL, DMODEL);
    k_wcvt<<<dim3(8,8),  256, 0, stream>>>(wk + (size_t)l*262144,  wkT, DMODEL, DMODEL);
    k_wcvt<<<dim3(8,8),  256, 0, stream>>>(wv + (size_t)l*262144,  wvT, DMODEL, DMODEL);
    k_wcvt<<<dim3(8,8),  256, 0, stream>>>(wo + (size_t)l*262144,  woT, DMODEL, DMODEL);
    k_wcvt<<<dim3(32,8), 256, 0, stream>>>(w1 + (size_t)l*1048576, w1T, DMODEL, DFF);
    k_wcvt<<<dim3(8,32), 256, 0, stream>>>(w2 + (size_t)l*1048576, w2T, DFF, DMODEL);

    k_init<<<1, 64, 0, stream>>>(kmax);
    k_ln<<<TOK, 256, 0, stream>>>(xo, ln1g + l*DMODEL, ln1b + l*DMODEL, bufH);
    // K path: k -> kmax -> kp_t -> ksum
    k_mm<1><<<dim3(4,128), 256, 0, stream>>>(bufH, wkT, nullptr, bufA, DMODEL, DMODEL);
    k_feat<0><<<(BHN*SEQ)/32, 256, 0, stream>>>(bufA, pj_l, nullptr, kmax, nullptr, nullptr);
    k_feat<1><<<(BHN*SEQ)/32, 256, 0, stream>>>(bufA, pj_l, featb, kmax, nullptr, nullptr);
    k_ksum<<<(BHN*MFEAT)/4, 256, 0, stream>>>(featb, ksum);
    // V path: v_t -> ctx_t
    k_mm<4><<<dim3(4,128), 256, 0, stream>>>(bufH, wvT, nullptr, bufA, DMODEL, DMODEL);
    k_ctx<<<dim3(4,BHN), 256, 0, stream>>>(bufA, featb, ctxt);
    // Q path: q -> qp + den -> o -> wo-GEMM (residual add)
    k_mm<1><<<dim3(4,128), 256, 0, stream>>>(bufH, wqT, nullptr, bufA, DMODEL, DMODEL);
    k_feat<2><<<(BHN*SEQ)/32, 256, 0, stream>>>(bufA, pj_l, featb, nullptr, ksum, den);
    k_o<<<dim3(SEQ/128,BHN), 256, 0, stream>>>(featb, ctxt, den, bufH);
    k_mm<2><<<dim3(4,128), 256, 0, stream>>>(bufH, woT, bo + l*DMODEL, xo, DMODEL, DMODEL);
    // FFN
    k_ln<<<TOK, 256, 0, stream>>>(xo, ln2g + l*DMODEL, ln2b + l*DMODEL, bufA);
    k_mm<3><<<dim3(16,128), 256, 0, stream>>>(bufA, w1T, b1 + l*DFF, featb, DFF, DMODEL);
    k_mm<2><<<dim3(4,128), 256, 0, stream>>>(featb, w2T, b2 + l*DMODEL, xo, DMODEL, DFF);
  }
}

// Round 8
// 2478.250 us; speedup vs baseline: 13.9641x; 1.0292x over previous
//
#include <hip/hip_runtime.h>
#include <math.h>

#define LNUM 6
#define HNUM 8
#define DMODEL 512
#define DHEAD 64
#define MFEAT 256
#define BATCH 8
#define SEQ 2048
#define TOK (BATCH*SEQ)
#define BHN (BATCH*HNUM)
#define DFF 2048
#define EPSF 1e-4f
#define LN_EPS 1e-5f
#define DNRM 0.35355339059327373f
#define SMF 0.0625f

typedef unsigned short u16;
typedef __attribute__((ext_vector_type(8))) short bf16x8;
typedef __attribute__((ext_vector_type(4))) float f32x4;
#define MFMA16(a,b,c) __builtin_amdgcn_mfma_f32_16x16x32_bf16(a,b,c,0,0,0)

// async global->LDS, 16B per lane; LDS dest = wave-uniform base + lane*16
#define GLOAD16(g,l) __builtin_amdgcn_global_load_lds( \
    (const __attribute__((address_space(1))) void*)(g), \
    (__attribute__((address_space(3))) void*)(l), 16, 0, 0)

__device__ __forceinline__ u16 f2bf(float f){
  unsigned int u = __float_as_uint(f);
  u = (u + 0x7fffu + ((u >> 16) & 1u)) >> 16;
  return (u16)u;
}
__device__ __forceinline__ float bf2f(u16 s){
  return __uint_as_float(((unsigned int)s) << 16);
}
__device__ __forceinline__ void atomicMaxF(float* addr, float val){
  if(val >= 0.f) atomicMax((int*)addr, __float_as_int(val));
  else           atomicMin((unsigned int*)addr, __float_as_uint(val));
}
// gelu tanh-approx: 0.5 z (1+tanh(c1 z + c2 z^3)) = z * sigmoid(2*(c1 z + c2 z^3))
__device__ __forceinline__ float fast_gelu(float z){
  float g2 = z*(1.5957691216f + 0.07135481628f*z*z);
  return z / (1.0f + __expf(-g2));
}

// ---------------- x = x + sinusoidal PE ----------------
__global__ void k_addpe(const float* __restrict__ x, float* __restrict__ xo){
  int idx = blockIdx.x*256 + threadIdx.x;
  int d = idx & (DMODEL-1);
  int n = (idx >> 9) & (SEQ-1);
  int j = d >> 1;
  float freq = expf((float)(2*j) * (-9.210340371976184f / (float)DMODEL));
  float ang = (float)n * freq;
  float pe = (d & 1) ? cosf(ang) : sinf(ang);
  xo[idx] = x[idx] + pe;
}

// ---------------- LayerNorm (512) -> bf16 ----------------
__global__ void k_ln(const float* __restrict__ x, const float* __restrict__ g,
                     const float* __restrict__ bv, u16* __restrict__ out){
  __shared__ float sred[8];
  int t = blockIdx.x, tid = threadIdx.x;
  const float2 v = ((const float2*)(x + (size_t)t*DMODEL))[tid];
  float s = v.x + v.y;
  #pragma unroll
  for(int o=32;o;o>>=1) s += __shfl_down(s,o);
  if((tid&63)==0) sred[tid>>6] = s;
  __syncthreads();
  if(tid==0) sred[4] = (sred[0]+sred[1]+sred[2]+sred[3]) * (1.0f/DMODEL);
  __syncthreads();
  float mu = sred[4];
  float dx = v.x - mu, dy = v.y - mu;
  float s2 = dx*dx + dy*dy;
  #pragma unroll
  for(int o=32;o;o>>=1) s2 += __shfl_down(s2,o);
  if((tid&63)==0) sred[tid>>6] = s2;
  __syncthreads();
  if(tid==0) sred[5] = rsqrtf((sred[0]+sred[1]+sred[2]+sred[3])*(1.0f/DMODEL) + LN_EPS);
  __syncthreads();
  float rs = sred[5];
  const float2 gg = ((const float2*)g)[tid];
  const float2 bb = ((const float2*)bv)[tid];
  ushort2 o2; o2.x = f2bf(dx*rs*gg.x + bb.x); o2.y = f2bf(dy*rs*gg.y + bb.y);
  ((ushort2*)(out + (size_t)t*DMODEL))[tid] = o2;
}

// ---------------- w[K][N] f32 -> wt[N][K] bf16 ----------------
__global__ void k_wcvt(const float* __restrict__ w, u16* __restrict__ wt, int K, int N){
  __shared__ float sm[64][65];
  int kt = blockIdx.y*64, nt = blockIdx.x*64;
  int t = threadIdx.x;
  int c = t & 63, r4 = t >> 6;
  #pragma unroll
  for(int i=0;i<16;i++){
    int kl = i*4 + r4;
    sm[kl][c] = w[(size_t)(kt+kl)*N + nt + c];
  }
  __syncthreads();
  #pragma unroll
  for(int i=0;i<16;i++){
    int nl = i*4 + r4;
    wt[(size_t)(nt+nl)*K + kt + c] = f2bf(sm[c][nl]);
  }
}

__global__ void k_pcvt(const float* __restrict__ p, u16* __restrict__ pb){
  int i = blockIdx.x*256 + threadIdx.x;
  pb[i] = f2bf(p[i]);
}

// ---------------- MFMA GEMM, BK=32, depth-4 circular pipeline (counted vmcnt) ----------------
// LDS[buf][r][c] (c = 8-u16 chunk 0..3) holds global chunk c ^ ((r>>1)&3).
// Staging source pre-swizzled (lane-constant chunk (l&3)^((l>>3)&3)); GLOAD dest linear.
// Loads issued 3 iterations ahead; main loop waits vmcnt(8) (oldest batch only).
// EPI 1: split-head bf16 [bh][n][dh]   2: f32 C += acc+bias
// EPI 3: bf16 C = gelu(acc+bias)       4: v_t bf16 [bh][dh][n]
template<int EPI>
__global__ __launch_bounds__(256)
void k_mm(const u16* __restrict__ A, const u16* __restrict__ Bt,
          const float* __restrict__ bias, void* __restrict__ Cv,
          int Nc, int K){
  __shared__ u16 As[4][128*32];
  __shared__ u16 Bs[4][128*32];
  int tid = threadIdx.x;
  int w = tid >> 6, lane = tid & 63;
  int wr = w >> 1, wc = w & 1;
  int hi = lane >> 4, li = lane & 15;
  int row0 = blockIdx.y*128, col0 = blockIdx.x*128;
  // staging: thread covers LDS row w*16+(lane>>2) (+64 for second issue), slot lane&3
  int lr = lane >> 2;
  int cs = (lane & 3) ^ ((lane >> 3) & 3);
  const u16* gA = A  + (size_t)(row0 + w*16 + lr)*K + cs*8;
  const u16* gB = Bt + (size_t)(col0 + w*16 + lr)*K + cs*8;
  f32x4 acc[4][4] = {};

#define STAGE_MM(b,k0) { \
    GLOAD16(gA + (k0),                    &As[b][(w*16)*32]);      \
    GLOAD16(gA + (size_t)64*K + (k0),     &As[b][(64+w*16)*32]);   \
    GLOAD16(gB + (k0),                    &Bs[b][(w*16)*32]);      \
    GLOAD16(gB + (size_t)64*K + (k0),     &Bs[b][(64+w*16)*32]); }

  int nk = K >> 5;           // K/32 >= 16 for all our shapes
  STAGE_MM(0, 0)
  STAGE_MM(1, 32)
  STAGE_MM(2, 64)
  for(int t=0; t<nk; ++t){
    int cur = t & 3;
    int rem = nk - 1 - t;
    __builtin_amdgcn_sched_barrier(0);
    if(rem >= 2)      { asm volatile("s_waitcnt vmcnt(8)"); }
    else if(rem == 1) { asm volatile("s_waitcnt vmcnt(4)"); }
    else              { asm volatile("s_waitcnt vmcnt(0)"); }
    __builtin_amdgcn_s_barrier();
    __builtin_amdgcn_sched_barrier(0);
    bf16x8 af[4], bfr[4];
    #pragma unroll
    for(int q=0;q<4;q++){
      int ar = wr*64 + q*16 + li;
      af[q]  = *(const bf16x8*)&As[cur][ar*32 + ((hi ^ ((ar>>1)&3))<<3)];
      int bc = wc*64 + q*16 + li;
      bfr[q] = *(const bf16x8*)&Bs[cur][bc*32 + ((hi ^ ((bc>>1)&3))<<3)];
    }
    #pragma unroll
    for(int i2=0;i2<4;i2++)
      #pragma unroll
      for(int j2=0;j2<4;j2++)
        acc[i2][j2] = MFMA16(af[i2], bfr[j2], acc[i2][j2]);
    if(t+3 < nk){
      STAGE_MM((t+3)&3, (size_t)(t+3)*32)
    }
  }
#undef STAGE_MM

  #pragma unroll
  for(int i2=0;i2<4;i2++){
    #pragma unroll
    for(int j2=0;j2<4;j2++){
      int col = col0 + wc*64 + j2*16 + li;
      float bcol = (EPI==2 || EPI==3) ? bias[col] : 0.f;
      if constexpr (EPI==4){
        int nb = row0 + wr*64 + i2*16 + hi*4;
        int b = nb >> 11, n = nb & (SEQ-1);
        int h = col >> 6, dh = col & 63;
        ushort4 pk;
        pk.x = f2bf(acc[i2][j2][0]); pk.y = f2bf(acc[i2][j2][1]);
        pk.z = f2bf(acc[i2][j2][2]); pk.w = f2bf(acc[i2][j2][3]);
        *(ushort4*)((u16*)Cv + (((size_t)(b*HNUM+h)*DHEAD + dh)*SEQ + n)) = pk;
      } else {
        #pragma unroll
        for(int r=0;r<4;r++){
          int row = row0 + wr*64 + i2*16 + hi*4 + r;
          float v = acc[i2][j2][r];
          if constexpr (EPI==1){
            int b = row >> 11, n = row & (SEQ-1);
            int h = col >> 6, dh = col & 63;
            ((u16*)Cv)[((size_t)(b*HNUM+h)*SEQ + n)*DHEAD + dh] = f2bf(v);
          } else if constexpr (EPI==2){
            ((float*)Cv)[(size_t)row*Nc + col] += v + bcol;
          } else {
            ((u16*)Cv)[(size_t)row*Nc + col] = f2bf(fast_gelu(v + bcol));
          }
        }
      }
    }
  }
}

// ---------------- FAVOR+ features via MFMA; 32 rows x 256 feats per block ----------------
// PHASE 0: global max per bh (atomic).  PHASE 1: kp_t[bh][m][n] bf16.
// PHASE 2: qp[row][m] bf16 + den = qp.ksum.
template<int PHASE>
__global__ __launch_bounds__(256)
void k_feat(const u16* __restrict__ xg, const u16* __restrict__ pjb,
            u16* __restrict__ outp, float* __restrict__ kmax,
            const float* __restrict__ ksum, float* __restrict__ den){
  __shared__ u16 pj[256*64];
  __shared__ u16 xs[32*64];
  __shared__ float dgs[32];
  __shared__ float wred[4][32];
  __shared__ float wden[4][32];
  __shared__ float ksl[256];
  int tid = threadIdx.x, w = tid >> 6, lane = tid & 63;
  int hi = lane >> 4, li = lane & 15;
  int r0 = blockIdx.x * 32;        // global feature row = bh*SEQ + n0
  int bh = r0 >> 11;
  #pragma unroll
  for(int i=0;i<8;i++){
    int idx = i*256 + tid;
    int m = idx >> 3, c = idx & 7;
    bf16x8 v = *(const bf16x8*)(pjb + m*64 + c*8);
    *(bf16x8*)&pj[m*64 + ((c ^ (m&7))<<3)] = v;
  }
  {
    int m = tid >> 3, c = tid & 7;
    bf16x8 v = *(const bf16x8*)(xg + (size_t)(r0+m)*64 + c*8);
    *(bf16x8*)&xs[m*64 + ((c ^ (m&7))<<3)] = v;
  }
  if constexpr (PHASE==2){ ksl[tid] = ksum[bh*MFEAT + tid]; }
  __syncthreads();
  if constexpr (PHASE!=0){
    if(tid < 32){
      float s = 0.f;
      #pragma unroll
      for(int d=0;d<64;d++){ float t = bf2f(xs[tid*64 + d]); s += t*t; }
      dgs[tid] = 0.5f*DNRM*DNRM*s;
    }
  }
  f32x4 acc[2][4] = {};
  #pragma unroll
  for(int ks=0;ks<2;ks++){
    bf16x8 af[2], bfr[4];
    int kc = ks*4 + hi;
    #pragma unroll
    for(int t=0;t<2;t++){
      int ar = t*16 + li;
      af[t] = *(const bf16x8*)&xs[ar*64 + ((kc ^ (ar&7))<<3)];
    }
    #pragma unroll
    for(int t=0;t<4;t++){
      int bc = w*64 + t*16 + li;
      bfr[t] = *(const bf16x8*)&pj[bc*64 + ((kc ^ (bc&7))<<3)];
    }
    #pragma unroll
    for(int i2=0;i2<2;i2++)
      #pragma unroll
      for(int j2=0;j2<4;j2++)
        acc[i2][j2] = MFMA16(af[i2], bfr[j2], acc[i2][j2]);
  }
  __syncthreads();
  if constexpr (PHASE==0){
    float mx = -1e30f;
    #pragma unroll
    for(int i2=0;i2<2;i2++)
      #pragma unroll
      for(int j2=0;j2<4;j2++)
        #pragma unroll
        for(int r=0;r<4;r++) mx = fmaxf(mx, acc[i2][j2][r]);
    #pragma unroll
    for(int o=32;o;o>>=1) mx = fmaxf(mx, __shfl_xor(mx,o));
    if(lane==0) wred[w][0] = mx;
    __syncthreads();
    if(tid==0){
      float m2 = fmaxf(fmaxf(wred[0][0],wred[1][0]), fmaxf(wred[2][0],wred[3][0]));
      atomicMaxF(&kmax[bh], m2*DNRM);
    }
  } else if constexpr (PHASE==1){
    float km = kmax[bh];
    #pragma unroll
    for(int i2=0;i2<2;i2++){
      #pragma unroll
      for(int j2=0;j2<4;j2++){
        int col = w*64 + j2*16 + li;
        ushort4 pk;
        #pragma unroll
        for(int r=0;r<4;r++){
          int rl = i2*16 + hi*4 + r;
          float u = acc[i2][j2][r]*DNRM;
          ((u16*)&pk)[r] = f2bf(SMF*(expf(u - dgs[rl] - km) + EPSF));
        }
        *(ushort4*)(outp + ((size_t)(bh*MFEAT + col)*SEQ + (r0 & (SEQ-1)) + i2*16 + hi*4)) = pk;
      }
    }
  } else {
    #pragma unroll
    for(int i2=0;i2<2;i2++){
      #pragma unroll
      for(int r=0;r<4;r++){
        float v = fmaxf(fmaxf(acc[i2][0][r],acc[i2][1][r]), fmaxf(acc[i2][2][r],acc[i2][3][r]));
        v = fmaxf(v, __shfl_xor(v,1)); v = fmaxf(v, __shfl_xor(v,2));
        v = fmaxf(v, __shfl_xor(v,4)); v = fmaxf(v, __shfl_xor(v,8));
        if(li==0) wred[w][i2*16 + hi*4 + r] = v;
      }
    }
    __syncthreads();
    #pragma unroll
    for(int i2=0;i2<2;i2++){
      #pragma unroll
      for(int r=0;r<4;r++){
        int rl = i2*16 + hi*4 + r;
        float rm = fmaxf(fmaxf(wred[0][rl],wred[1][rl]), fmaxf(wred[2][rl],wred[3][rl]));
        float dsum = 0.f;
        #pragma unroll
        for(int j2=0;j2<4;j2++){
          int col = w*64 + j2*16 + li;
          float u = acc[i2][j2][r]*DNRM;
          u16 eb = f2bf(SMF*(expf(u - dgs[rl] - rm) + EPSF));
          outp[((size_t)r0 + rl)*MFEAT + col] = eb;
          dsum += bf2f(eb)*ksl[col];
        }
        dsum += __shfl_xor(dsum,1); dsum += __shfl_xor(dsum,2);
        dsum += __shfl_xor(dsum,4); dsum += __shfl_xor(dsum,8);
        if(li==0) wden[w][rl] = dsum;
      }
    }
    __syncthreads();
    if(tid < 32) den[(size_t)r0 + tid] = wden[0][tid]+wden[1][tid]+wden[2][tid]+wden[3][tid];
  }
}

// ---------------- ksum[bh*256+m] = sum_n kp_t[m][n] ----------------
__global__ __launch_bounds__(256)
void k_ksum(const u16* __restrict__ kpt, float* __restrict__ ksum){
  int row = blockIdx.x*4 + (threadIdx.x>>6);
  int lane = threadIdx.x & 63;
  const u16* p = kpt + (size_t)row*SEQ;
  float s = 0.f;
  #pragma unroll
  for(int i=0;i<4;i++){
    bf16x8 v = *(const bf16x8*)(p + i*512 + lane*8);
    #pragma unroll
    for(int j=0;j<8;j++) s += bf2f((u16)v[j]);
  }
  #pragma unroll
  for(int o=32;o;o>>=1) s += __shfl_down(s,o);
  if(lane==0) ksum[row] = s;
}

// ---------------- ctx_t[bh][dh][m] = sum_n v_t[dh][n]*kp_t[m][n] ----------------
__global__ __launch_bounds__(256)
void k_ctx(const u16* __restrict__ vt, const u16* __restrict__ kpt,
           u16* __restrict__ ctxt){
  __shared__ u16 As[64*64];
  __shared__ u16 Bs[64*64];
  int tid = threadIdx.x, w = tid >> 6, lane = tid & 63;
  int wr = w >> 1, wc = w & 1;
  int hi = lane >> 4, li = lane & 15;
  int bh = blockIdx.y, mb = blockIdx.x*64;
  int lr = lane >> 3;
  int lc = (lane & 7) ^ lr;
  const u16* gA = vt  + (size_t)bh*DHEAD*SEQ + (size_t)(w*8 + lr)*SEQ + lc*8;
  const u16* gB = kpt + ((size_t)bh*MFEAT + mb + w*8 + lr)*SEQ + lc*8;
  f32x4 acc[2][2] = {};
  for(int k0=0;k0<SEQ;k0+=64){
    #pragma unroll
    for(int t=0;t<2;t++){
      GLOAD16(gA + (size_t)(t*32)*SEQ + k0, &As[(t*4+w)*512]);
      GLOAD16(gB + (size_t)(t*32)*SEQ + k0, &Bs[(t*4+w)*512]);
    }
    __syncthreads();
    #pragma unroll
    for(int ks=0;ks<2;ks++){
      bf16x8 af[2], bfr[2];
      int kc = ks*4 + hi;
      #pragma unroll
      for(int t=0;t<2;t++){
        int ar = wr*32 + t*16 + li;
        af[t] = *(const bf16x8*)&As[ar*64 + ((kc ^ (ar&7))<<3)];
        int bc = wc*32 + t*16 + li;
        bfr[t] = *(const bf16x8*)&Bs[bc*64 + ((kc ^ (bc&7))<<3)];
      }
      #pragma unroll
      for(int i2=0;i2<2;i2++)
        #pragma unroll
        for(int j2=0;j2<2;j2++)
          acc[i2][j2] = MFMA16(af[i2], bfr[j2], acc[i2][j2]);
    }
    __syncthreads();
  }
  #pragma unroll
  for(int i2=0;i2<2;i2++)
    #pragma unroll
    for(int j2=0;j2<2;j2++){
      int m = mb + wc*32 + j2*16 + li;
      #pragma unroll
      for(int r=0;r<4;r++){
        int dh = wr*32 + i2*16 + hi*4 + r;
        ctxt[((size_t)bh*DHEAD + dh)*MFEAT + m] = f2bf(acc[i2][j2][r]);
      }
    }
}

// ---------------- o[b][n][h*64+dh] = (qp @ ctx_t^T)/den, bf16 ----------------
__global__ __launch_bounds__(256)
void k_o(const u16* __restrict__ qp, const u16* __restrict__ ctxt,
         const float* __restrict__ den, u16* __restrict__ o){
  __shared__ u16 As[128*64];
  __shared__ u16 Bs[64*64];
  int tid = threadIdx.x, w = tid >> 6, lane = tid & 63;
  int wr = w >> 1, wc = w & 1;
  int hi = lane >> 4, li = lane & 15;
  int bh = blockIdx.y, nb = blockIdx.x*128;
  int b = bh >> 3, h = bh & 7;
  int lr = lane >> 3;
  int lc = (lane & 7) ^ lr;
  const u16* gA = qp   + ((size_t)bh*SEQ + nb + w*8 + lr)*MFEAT + lc*8;
  const u16* gB = ctxt + (size_t)bh*DHEAD*MFEAT + (size_t)(w*8 + lr)*MFEAT + lc*8;
  f32x4 acc[4][2] = {};
  for(int k0=0;k0<MFEAT;k0+=64){
    #pragma unroll
    for(int t=0;t<4;t++){
      GLOAD16(gA + (size_t)(t*32)*MFEAT + k0, &As[(t*4+w)*512]);
      if(t < 2) GLOAD16(gB + (size_t)(t*32)*MFEAT + k0, &Bs[(t*4+w)*512]);
    }
    __syncthreads();
    #pragma unroll
    for(int ks=0;ks<2;ks++){
      bf16x8 af[4], bfr[2];
      int kc = ks*4 + hi;
      #pragma unroll
      for(int t=0;t<4;t++){
        int ar = wr*64 + t*16 + li;
        af[t] = *(const bf16x8*)&As[ar*64 + ((kc ^ (ar&7))<<3)];
      }
      #pragma unroll
      for(int t=0;t<2;t++){
        int bc = wc*32 + t*16 + li;
        bfr[t] = *(const bf16x8*)&Bs[bc*64 + ((kc ^ (bc&7))<<3)];
      }
      #pragma unroll
      for(int i2=0;i2<4;i2++)
        #pragma unroll
        for(int j2=0;j2<2;j2++)
          acc[i2][j2] = MFMA16(af[i2], bfr[j2], acc[i2][j2]);
    }
    __syncthreads();
  }
  #pragma unroll
  for(int i2=0;i2<4;i2++){
    #pragma unroll
    for(int r=0;r<4;r++){
      int n = nb + wr*64 + i2*16 + hi*4 + r;
      float di = 1.0f/den[(size_t)bh*SEQ + n];
      #pragma unroll
      for(int j2=0;j2<2;j2++){
        int dh = wc*32 + j2*16 + li;
        o[((size_t)b*SEQ + n)*DMODEL + h*DHEAD + dh] = f2bf(acc[i2][j2][r]*di);
      }
    }
  }
}

__global__ void k_init(float* kmax){
  int i = threadIdx.x;
  if(i < BHN) kmax[i] = -INFINITY;
}

extern "C" void kernel_launch(void* const* d_in, const int* in_sizes, int n_in,
                              void* d_out, int out_size, void* d_ws, size_t ws_size,
                              hipStream_t stream){
  (void)in_sizes; (void)n_in; (void)out_size; (void)ws_size;
  const float* x    = (const float*)d_in[0];
  const float* proj = (const float*)d_in[1];
  const float* ln1g = (const float*)d_in[2];
  const float* ln1b = (const float*)d_in[3];
  const float* wq   = (const float*)d_in[4];
  const float* wk   = (const float*)d_in[5];
  const float* wv   = (const float*)d_in[6];
  const float* wo   = (const float*)d_in[7];
  const float* bo   = (const float*)d_in[8];
  const float* ln2g = (const float*)d_in[9];
  const float* ln2b = (const float*)d_in[10];
  const float* w1   = (const float*)d_in[11];
  const float* b1   = (const float*)d_in[12];
  const float* w2   = (const float*)d_in[13];
  const float* b2   = (const float*)d_in[14];
  float* xo = (float*)d_out;

  // workspace ~110 MB
  char* ws = (char*)d_ws;
  u16* bufH  = (u16*)ws;  ws += (size_t)TOK*DMODEL*2;       // 16.78 MB  h / o (bf16)
  u16* bufA  = (u16*)ws;  ws += (size_t)TOK*DMODEL*2;       // 16.78 MB  k / v_t / q / h2 (bf16)
  u16* featb = (u16*)ws;  ws += (size_t)BHN*SEQ*MFEAT*2;    // 67.11 MB  kp_t / qp / ffn1 (bf16)
  u16* ctxt  = (u16*)ws;  ws += (size_t)BHN*DHEAD*MFEAT*2;  //  2.10 MB
  u16* wT    = (u16*)ws;  ws += (size_t)3*1048576*2;        //  6.29 MB  per-layer bf16 W^T
  u16* pjb   = (u16*)ws;  ws += (size_t)LNUM*MFEAT*DHEAD*2; //  0.19 MB
  float* ksum= (float*)ws; ws += (size_t)BHN*MFEAT*4;       // 64 KB
  float* den = (float*)ws; ws += (size_t)BHN*SEQ*4;         // 512 KB
  float* kmax= (float*)ws; ws += 256;

  u16* wqT = wT;                 // [512][512]
  u16* wkT = wT +  262144;
  u16* wvT = wT +  524288;
  u16* woT = wT +  786432;
  u16* w1T = wT + 1048576;       // [2048][512]
  u16* w2T = wT + 2097152;       // [512][2048]

  k_addpe<<<(TOK*DMODEL)/256, 256, 0, stream>>>(x, xo);
  k_pcvt<<<(LNUM*MFEAT*DHEAD)/256, 256, 0, stream>>>(proj, pjb);

  for(int l=0; l<LNUM; l++){
    const u16* pj_l = pjb + (size_t)l*MFEAT*DHEAD;
    k_wcvt<<<dim3(8,8),  256, 0, stream>>>(wq + (size_t)l*262144,  wqT, DMODEL, DMODEL);
    k_wcvt<<<dim3(8,8),  256, 0, stream>>>(wk + (size_t)l*262144,  wkT, DMODEL, DMODEL);
    k_wcvt<<<dim3(8,8),  256, 0, stream>>>(wv + (size_t)l*262144,  wvT, DMODEL, DMODEL);
    k_wcvt<<<dim3(8,8),  256, 0, stream>>>(wo + (size_t)l*262144,  woT, DMODEL, DMODEL);
    k_wcvt<<<dim3(32,8), 256, 0, stream>>>(w1 + (size_t)l*1048576, w1T, DMODEL, DFF);
    k_wcvt<<<dim3(8,32), 256, 0, stream>>>(w2 + (size_t)l*1048576, w2T, DFF, DMODEL);

    k_init<<<1, 64, 0, stream>>>(kmax);
    k_ln<<<TOK, 256, 0, stream>>>(xo, ln1g + l*DMODEL, ln1b + l*DMODEL, bufH);
    // K path: k -> kmax -> kp_t -> ksum
    k_mm<1><<<dim3(4,128), 256, 0, stream>>>(bufH, wkT, nullptr, bufA, DMODEL, DMODEL);
    k_feat<0><<<(BHN*SEQ)/32, 256, 0, stream>>>(bufA, pj_l, nullptr, kmax, nullptr, nullptr);
    k_feat<1><<<(BHN*SEQ)/32, 256, 0, stream>>>(bufA, pj_l, featb, kmax, nullptr, nullptr);
    k_ksum<<<(BHN*MFEAT)/4, 256, 0, stream>>>(featb, ksum);
    // V path: v_t -> ctx_t
    k_mm<4><<<dim3(4,128), 256, 0, stream>>>(bufH, wvT, nullptr, bufA, DMODEL, DMODEL);
    k_ctx<<<dim3(4,BHN), 256, 0, stream>>>(bufA, featb, ctxt);
    // Q path: q -> qp + den -> o -> wo-GEMM (residual add)
    k_mm<1><<<dim3(4,128), 256, 0, stream>>>(bufH, wqT, nullptr, bufA, DMODEL, DMODEL);
    k_feat<2><<<(BHN*SEQ)/32, 256, 0, stream>>>(bufA, pj_l, featb, nullptr, ksum, den);
    k_o<<<dim3(SEQ/128,BHN), 256, 0, stream>>>(featb, ctxt, den, bufH);
    k_mm<2><<<dim3(4,128), 256, 0, stream>>>(bufH, woT, bo + l*DMODEL, xo, DMODEL, DMODEL);
    // FFN
    k_ln<<<TOK, 256, 0, stream>>>(xo, ln2g + l*DMODEL, ln2b + l*DMODEL, bufA);
    k_mm<3><<<dim3(16,128), 256, 0, stream>>>(bufA, w1T, b1 + l*DFF, featb, DFF, DMODEL);
    k_mm<2><<<dim3(4,128), 256, 0, stream>>>(featb, w2T, b2 + l*DMODEL, xo, DMODEL, DFF);
  }
}

// Round 9
// 2386.168 us; speedup vs baseline: 14.5029x; 1.0386x over previous
//
#include <hip/hip_runtime.h>
#include <math.h>

#define LNUM 6
#define HNUM 8
#define DMODEL 512
#define DHEAD 64
#define MFEAT 256
#define BATCH 8
#define SEQ 2048
#define TOK (BATCH*SEQ)
#define BHN (BATCH*HNUM)
#define DFF 2048
#define EPSF 1e-4f
#define LN_EPS 1e-5f
#define DNRM 0.35355339059327373f
#define SMF 0.0625f

typedef unsigned short u16;
typedef __attribute__((ext_vector_type(8))) short bf16x8;
typedef __attribute__((ext_vector_type(4))) float f32x4;
#define MFMA16(a,b,c) __builtin_amdgcn_mfma_f32_16x16x32_bf16(a,b,c,0,0,0)

// async global->LDS, 16B per lane; LDS dest = wave-uniform base + lane*16
#define GLOAD16(g,l) __builtin_amdgcn_global_load_lds( \
    (const __attribute__((address_space(1))) void*)(g), \
    (__attribute__((address_space(3))) void*)(l), 16, 0, 0)

__device__ __forceinline__ u16 f2bf(float f){
  unsigned int u = __float_as_uint(f);
  u = (u + 0x7fffu + ((u >> 16) & 1u)) >> 16;
  return (u16)u;
}
__device__ __forceinline__ float bf2f(u16 s){
  return __uint_as_float(((unsigned int)s) << 16);
}
__device__ __forceinline__ void atomicMaxF(float* addr, float val){
  if(val >= 0.f) atomicMax((int*)addr, __float_as_int(val));
  else           atomicMin((unsigned int*)addr, __float_as_uint(val));
}
// gelu tanh-approx: 0.5 z (1+tanh(c1 z + c2 z^3)) = z * sigmoid(2*(c1 z + c2 z^3))
__device__ __forceinline__ float fast_gelu(float z){
  float g2 = z*(1.5957691216f + 0.07135481628f*z*z);
  return z / (1.0f + __expf(-g2));
}

// ---------------- x = x + sinusoidal PE ----------------
__global__ void k_addpe(const float* __restrict__ x, float* __restrict__ xo){
  int idx = blockIdx.x*256 + threadIdx.x;
  int d = idx & (DMODEL-1);
  int n = (idx >> 9) & (SEQ-1);
  int j = d >> 1;
  float freq = expf((float)(2*j) * (-9.210340371976184f / (float)DMODEL));
  float ang = (float)n * freq;
  float pe = (d & 1) ? cosf(ang) : sinf(ang);
  xo[idx] = x[idx] + pe;
}

// ---------------- LayerNorm (512) -> bf16 ----------------
__global__ void k_ln(const float* __restrict__ x, const float* __restrict__ g,
                     const float* __restrict__ bv, u16* __restrict__ out){
  __shared__ float sred[8];
  int t = blockIdx.x, tid = threadIdx.x;
  const float2 v = ((const float2*)(x + (size_t)t*DMODEL))[tid];
  float s = v.x + v.y;
  #pragma unroll
  for(int o=32;o;o>>=1) s += __shfl_down(s,o);
  if((tid&63)==0) sred[tid>>6] = s;
  __syncthreads();
  if(tid==0) sred[4] = (sred[0]+sred[1]+sred[2]+sred[3]) * (1.0f/DMODEL);
  __syncthreads();
  float mu = sred[4];
  float dx = v.x - mu, dy = v.y - mu;
  float s2 = dx*dx + dy*dy;
  #pragma unroll
  for(int o=32;o;o>>=1) s2 += __shfl_down(s2,o);
  if((tid&63)==0) sred[tid>>6] = s2;
  __syncthreads();
  if(tid==0) sred[5] = rsqrtf((sred[0]+sred[1]+sred[2]+sred[3])*(1.0f/DMODEL) + LN_EPS);
  __syncthreads();
  float rs = sred[5];
  const float2 gg = ((const float2*)g)[tid];
  const float2 bb = ((const float2*)bv)[tid];
  ushort2 o2; o2.x = f2bf(dx*rs*gg.x + bb.x); o2.y = f2bf(dy*rs*gg.y + bb.y);
  ((ushort2*)(out + (size_t)t*DMODEL))[tid] = o2;
}

// ---------------- w[K][N] f32 -> wt[N][K] bf16 ----------------
__global__ void k_wcvt(const float* __restrict__ w, u16* __restrict__ wt, int K, int N){
  __shared__ float sm[64][65];
  int kt = blockIdx.y*64, nt = blockIdx.x*64;
  int t = threadIdx.x;
  int c = t & 63, r4 = t >> 6;
  #pragma unroll
  for(int i=0;i<16;i++){
    int kl = i*4 + r4;
    sm[kl][c] = w[(size_t)(kt+kl)*N + nt + c];
  }
  __syncthreads();
  #pragma unroll
  for(int i=0;i<16;i++){
    int nl = i*4 + r4;
    wt[(size_t)(nt+nl)*K + kt + c] = f2bf(sm[c][nl]);
  }
}

__global__ void k_pcvt(const float* __restrict__ p, u16* __restrict__ pb){
  int i = blockIdx.x*256 + threadIdx.x;
  pb[i] = f2bf(p[i]);
}

// ---------------- MFMA GEMM, BK=32, depth-2, counted vmcnt, 128-reg cap ----------------
// LDS[buf][r][c] (c = 8-u16 chunk 0..3) holds global chunk c ^ ((r>>1)&3).
// Staging source pre-swizzled (lane-constant chunk (l&3)^((l>>3)&3)); GLOAD dest linear.
// Read swizzle term is q-invariant -> single precomputed base + immediate offsets.
// EPI 1: split-head bf16 [bh][n][dh]   2: f32 C += acc+bias
// EPI 3: bf16 C = gelu(acc+bias)       4: v_t bf16 [bh][dh][n]
template<int EPI>
__global__ __launch_bounds__(256,4)
void k_mm(const u16* __restrict__ A, const u16* __restrict__ Bt,
          const float* __restrict__ bias, void* __restrict__ Cv,
          int Nc, int K){
  __shared__ u16 As[2][128*32];
  __shared__ u16 Bs[2][128*32];
  int tid = threadIdx.x;
  int w = tid >> 6, lane = tid & 63;
  int wr = w >> 1, wc = w & 1;
  int hi = lane >> 4, li = lane & 15;
  int row0 = blockIdx.y*128, col0 = blockIdx.x*128;
  int lr = lane >> 2;
  int cs = (lane & 3) ^ ((lane >> 3) & 3);
  const u16* gA = A  + (size_t)(row0 + w*16 + lr)*K + cs*8;
  const u16* gB = Bt + (size_t)(col0 + w*16 + lr)*K + cs*8;
  // swizzled LDS read base (u16 index); q-contribution is +q*512, wave +wr*2048/+wc*2048
  int rb = li*32 + ((hi ^ ((li>>1)&3))<<3);
  f32x4 acc[4][4] = {};

#define STAGE_MM(b,k0) { \
    GLOAD16(gA + (k0),                &As[b][(w*16)*32]);      \
    GLOAD16(gA + (size_t)64*K + (k0), &As[b][(64+w*16)*32]);   \
    GLOAD16(gB + (k0),                &Bs[b][(w*16)*32]);      \
    GLOAD16(gB + (size_t)64*K + (k0), &Bs[b][(64+w*16)*32]); }

  int nk = K >> 5;           // >= 16 for all our shapes
  STAGE_MM(0, 0)
  STAGE_MM(1, 32)
  for(int t=0; t<nk; ++t){
    __builtin_amdgcn_sched_barrier(0);
    if(t+1 < nk){ asm volatile("s_waitcnt vmcnt(4)"); }
    else        { asm volatile("s_waitcnt vmcnt(0)"); }
    __builtin_amdgcn_s_barrier();
    __builtin_amdgcn_sched_barrier(0);
    const u16* pa = &As[t&1][0];
    const u16* pb = &Bs[t&1][0];
    bf16x8 bfr[4];
    #pragma unroll
    for(int q=0;q<4;q++) bfr[q] = *(const bf16x8*)&pb[rb + wc*2048 + q*512];
    #pragma unroll
    for(int i2=0;i2<4;i2++){
      bf16x8 a = *(const bf16x8*)&pa[rb + wr*2048 + i2*512];
      #pragma unroll
      for(int j2=0;j2<4;j2++)
        acc[i2][j2] = MFMA16(a, bfr[j2], acc[i2][j2]);
    }
    __builtin_amdgcn_sched_barrier(0);
    __builtin_amdgcn_s_barrier();
    __builtin_amdgcn_sched_barrier(0);
    if(t+2 < nk){ STAGE_MM(t&1, (size_t)(t+2)*32) }
  }
#undef STAGE_MM

  #pragma unroll
  for(int i2=0;i2<4;i2++){
    #pragma unroll
    for(int j2=0;j2<4;j2++){
      int col = col0 + wc*64 + j2*16 + li;
      float bcol = (EPI==2 || EPI==3) ? bias[col] : 0.f;
      if constexpr (EPI==4){
        int nb = row0 + wr*64 + i2*16 + hi*4;
        int b = nb >> 11, n = nb & (SEQ-1);
        int h = col >> 6, dh = col & 63;
        ushort4 pk;
        pk.x = f2bf(acc[i2][j2][0]); pk.y = f2bf(acc[i2][j2][1]);
        pk.z = f2bf(acc[i2][j2][2]); pk.w = f2bf(acc[i2][j2][3]);
        *(ushort4*)((u16*)Cv + (((size_t)(b*HNUM+h)*DHEAD + dh)*SEQ + n)) = pk;
      } else {
        #pragma unroll
        for(int r=0;r<4;r++){
          int row = row0 + wr*64 + i2*16 + hi*4 + r;
          float v = acc[i2][j2][r];
          if constexpr (EPI==1){
            int b = row >> 11, n = row & (SEQ-1);
            int h = col >> 6, dh = col & 63;
            ((u16*)Cv)[((size_t)(b*HNUM+h)*SEQ + n)*DHEAD + dh] = f2bf(v);
          } else if constexpr (EPI==2){
            ((float*)Cv)[(size_t)row*Nc + col] += v + bcol;
          } else {
            ((u16*)Cv)[(size_t)row*Nc + col] = f2bf(fast_gelu(v + bcol));
          }
        }
      }
    }
  }
}

// ---------------- FAVOR+ features via MFMA; 32 rows x 256 feats per block ----------------
// PHASE 0: global max per bh (atomic).  PHASE 1: kp_t[bh][m][n] bf16 + ksum atomics.
// PHASE 2: qp[row][m] bf16 + den = qp.ksum.
template<int PHASE>
__global__ __launch_bounds__(256)
void k_feat(const u16* __restrict__ xg, const u16* __restrict__ pjb,
            u16* __restrict__ outp, float* __restrict__ kmax,
            float* __restrict__ ksum, float* __restrict__ den){
  __shared__ u16 pj[256*64];
  __shared__ u16 xs[32*64];
  __shared__ float dgs[32];
  __shared__ float wred[4][32];
  __shared__ float wden[4][32];
  __shared__ float ksl[256];
  int tid = threadIdx.x, w = tid >> 6, lane = tid & 63;
  int hi = lane >> 4, li = lane & 15;
  int r0 = blockIdx.x * 32;        // global feature row = bh*SEQ + n0
  int bh = r0 >> 11;
  #pragma unroll
  for(int i=0;i<8;i++){
    int idx = i*256 + tid;
    int m = idx >> 3, c = idx & 7;
    bf16x8 v = *(const bf16x8*)(pjb + m*64 + c*8);
    *(bf16x8*)&pj[m*64 + ((c ^ (m&7))<<3)] = v;
  }
  {
    int m = tid >> 3, c = tid & 7;
    bf16x8 v = *(const bf16x8*)(xg + (size_t)(r0+m)*64 + c*8);
    *(bf16x8*)&xs[m*64 + ((c ^ (m&7))<<3)] = v;
  }
  if constexpr (PHASE==2){ ksl[tid] = ksum[bh*MFEAT + tid]; }
  __syncthreads();
  if constexpr (PHASE!=0){
    if(tid < 32){
      float s = 0.f;
      #pragma unroll
      for(int d=0;d<64;d++){ float t = bf2f(xs[tid*64 + d]); s += t*t; }
      dgs[tid] = 0.5f*DNRM*DNRM*s;
    }
  }
  f32x4 acc[2][4] = {};
  #pragma unroll
  for(int ks=0;ks<2;ks++){
    bf16x8 af[2], bfr[4];
    int kc = ks*4 + hi;
    #pragma unroll
    for(int t=0;t<2;t++){
      int ar = t*16 + li;
      af[t] = *(const bf16x8*)&xs[ar*64 + ((kc ^ (ar&7))<<3)];
    }
    #pragma unroll
    for(int t=0;t<4;t++){
      int bc = w*64 + t*16 + li;
      bfr[t] = *(const bf16x8*)&pj[bc*64 + ((kc ^ (bc&7))<<3)];
    }
    #pragma unroll
    for(int i2=0;i2<2;i2++)
      #pragma unroll
      for(int j2=0;j2<4;j2++)
        acc[i2][j2] = MFMA16(af[i2], bfr[j2], acc[i2][j2]);
  }
  __syncthreads();
  if constexpr (PHASE==0){
    float mx = -1e30f;
    #pragma unroll
    for(int i2=0;i2<2;i2++)
      #pragma unroll
      for(int j2=0;j2<4;j2++)
        #pragma unroll
        for(int r=0;r<4;r++) mx = fmaxf(mx, acc[i2][j2][r]);
    #pragma unroll
    for(int o=32;o;o>>=1) mx = fmaxf(mx, __shfl_xor(mx,o));
    if(lane==0) wred[w][0] = mx;
    __syncthreads();
    if(tid==0){
      float m2 = fmaxf(fmaxf(wred[0][0],wred[1][0]), fmaxf(wred[2][0],wred[3][0]));
      atomicMaxF(&kmax[bh], m2*DNRM);
    }
  } else if constexpr (PHASE==1){
    float km = kmax[bh];
    float csum[4] = {0.f,0.f,0.f,0.f};
    #pragma unroll
    for(int i2=0;i2<2;i2++){
      #pragma unroll
      for(int j2=0;j2<4;j2++){
        int col = w*64 + j2*16 + li;
        ushort4 pk;
        float cpart = 0.f;
        #pragma unroll
        for(int r=0;r<4;r++){
          int rl = i2*16 + hi*4 + r;
          float u = acc[i2][j2][r]*DNRM;
          u16 eb = f2bf(SMF*(expf(u - dgs[rl] - km) + EPSF));
          ((u16*)&pk)[r] = eb;
          cpart += bf2f(eb);
        }
        *(ushort4*)(outp + ((size_t)(bh*MFEAT + col)*SEQ + (r0 & (SEQ-1)) + i2*16 + hi*4)) = pk;
        csum[j2] += cpart;
      }
    }
    #pragma unroll
    for(int j2=0;j2<4;j2++){
      float v = csum[j2];
      v += __shfl_xor(v,16); v += __shfl_xor(v,32);
      if(hi==0) atomicAdd(&ksum[bh*MFEAT + w*64 + j2*16 + li], v);
    }
  } else {
    #pragma unroll
    for(int i2=0;i2<2;i2++){
      #pragma unroll
      for(int r=0;r<4;r++){
        float v = fmaxf(fmaxf(acc[i2][0][r],acc[i2][1][r]), fmaxf(acc[i2][2][r],acc[i2][3][r]));
        v = fmaxf(v, __shfl_xor(v,1)); v = fmaxf(v, __shfl_xor(v,2));
        v = fmaxf(v, __shfl_xor(v,4)); v = fmaxf(v, __shfl_xor(v,8));
        if(li==0) wred[w][i2*16 + hi*4 + r] = v;
      }
    }
    __syncthreads();
    #pragma unroll
    for(int i2=0;i2<2;i2++){
      #pragma unroll
      for(int r=0;r<4;r++){
        int rl = i2*16 + hi*4 + r;
        float rm = fmaxf(fmaxf(wred[0][rl],wred[1][rl]), fmaxf(wred[2][rl],wred[3][rl]));
        float dsum = 0.f;
        #pragma unroll
        for(int j2=0;j2<4;j2++){
          int col = w*64 + j2*16 + li;
          float u = acc[i2][j2][r]*DNRM;
          u16 eb = f2bf(SMF*(expf(u - dgs[rl] - rm) + EPSF));
          outp[((size_t)r0 + rl)*MFEAT + col] = eb;
          dsum += bf2f(eb)*ksl[col];
        }
        dsum += __shfl_xor(dsum,1); dsum += __shfl_xor(dsum,2);
        dsum += __shfl_xor(dsum,4); dsum += __shfl_xor(dsum,8);
        if(li==0) wden[w][rl] = dsum;
      }
    }
    __syncthreads();
    if(tid < 32) den[(size_t)r0 + tid] = wden[0][tid]+wden[1][tid]+wden[2][tid]+wden[3][tid];
  }
}

// ---------------- ctx_t[bh][dh][m] = sum_n v_t[dh][n]*kp_t[m][n] ----------------
__global__ __launch_bounds__(256)
void k_ctx(const u16* __restrict__ vt, const u16* __restrict__ kpt,
           u16* __restrict__ ctxt){
  __shared__ u16 As[64*64];
  __shared__ u16 Bs[64*64];
  int tid = threadIdx.x, w = tid >> 6, lane = tid & 63;
  int wr = w >> 1, wc = w & 1;
  int hi = lane >> 4, li = lane & 15;
  int bh = blockIdx.y, mb = blockIdx.x*64;
  int lr = lane >> 3;
  int lc = (lane & 7) ^ lr;
  const u16* gA = vt  + (size_t)bh*DHEAD*SEQ + (size_t)(w*8 + lr)*SEQ + lc*8;
  const u16* gB = kpt + ((size_t)bh*MFEAT + mb + w*8 + lr)*SEQ + lc*8;
  f32x4 acc[2][2] = {};
  for(int k0=0;k0<SEQ;k0+=64){
    #pragma unroll
    for(int t=0;t<2;t++){
      GLOAD16(gA + (size_t)(t*32)*SEQ + k0, &As[(t*4+w)*512]);
      GLOAD16(gB + (size_t)(t*32)*SEQ + k0, &Bs[(t*4+w)*512]);
    }
    __syncthreads();
    #pragma unroll
    for(int ks=0;ks<2;ks++){
      bf16x8 af[2], bfr[2];
      int kc = ks*4 + hi;
      #pragma unroll
      for(int t=0;t<2;t++){
        int ar = wr*32 + t*16 + li;
        af[t] = *(const bf16x8*)&As[ar*64 + ((kc ^ (ar&7))<<3)];
        int bc = wc*32 + t*16 + li;
        bfr[t] = *(const bf16x8*)&Bs[bc*64 + ((kc ^ (bc&7))<<3)];
      }
      #pragma unroll
      for(int i2=0;i2<2;i2++)
        #pragma unroll
        for(int j2=0;j2<2;j2++)
          acc[i2][j2] = MFMA16(af[i2], bfr[j2], acc[i2][j2]);
    }
    __syncthreads();
  }
  #pragma unroll
  for(int i2=0;i2<2;i2++)
    #pragma unroll
    for(int j2=0;j2<2;j2++){
      int m = mb + wc*32 + j2*16 + li;
      #pragma unroll
      for(int r=0;r<4;r++){
        int dh = wr*32 + i2*16 + hi*4 + r;
        ctxt[((size_t)bh*DHEAD + dh)*MFEAT + m] = f2bf(acc[i2][j2][r]);
      }
    }
}

// ---------------- o[b][n][h*64+dh] = (qp @ ctx_t^T)/den, bf16 ----------------
__global__ __launch_bounds__(256)
void k_o(const u16* __restrict__ qp, const u16* __restrict__ ctxt,
         const float* __restrict__ den, u16* __restrict__ o){
  __shared__ u16 As[128*64];
  __shared__ u16 Bs[64*64];
  int tid = threadIdx.x, w = tid >> 6, lane = tid & 63;
  int wr = w >> 1, wc = w & 1;
  int hi = lane >> 4, li = lane & 15;
  int bh = blockIdx.y, nb = blockIdx.x*128;
  int b = bh >> 3, h = bh & 7;
  int lr = lane >> 3;
  int lc = (lane & 7) ^ lr;
  const u16* gA = qp   + ((size_t)bh*SEQ + nb + w*8 + lr)*MFEAT + lc*8;
  const u16* gB = ctxt + (size_t)bh*DHEAD*MFEAT + (size_t)(w*8 + lr)*MFEAT + lc*8;
  f32x4 acc[4][2] = {};
  for(int k0=0;k0<MFEAT;k0+=64){
    #pragma unroll
    for(int t=0;t<4;t++){
      GLOAD16(gA + (size_t)(t*32)*MFEAT + k0, &As[(t*4+w)*512]);
      if(t < 2) GLOAD16(gB + (size_t)(t*32)*MFEAT + k0, &Bs[(t*4+w)*512]);
    }
    __syncthreads();
    #pragma unroll
    for(int ks=0;ks<2;ks++){
      bf16x8 af[4], bfr[2];
      int kc = ks*4 + hi;
      #pragma unroll
      for(int t=0;t<4;t++){
        int ar = wr*64 + t*16 + li;
        af[t] = *(const bf16x8*)&As[ar*64 + ((kc ^ (ar&7))<<3)];
      }
      #pragma unroll
      for(int t=0;t<2;t++){
        int bc = wc*32 + t*16 + li;
        bfr[t] = *(const bf16x8*)&Bs[bc*64 + ((kc ^ (bc&7))<<3)];
      }
      #pragma unroll
      for(int i2=0;i2<4;i2++)
        #pragma unroll
        for(int j2=0;j2<2;j2++)
          acc[i2][j2] = MFMA16(af[i2], bfr[j2], acc[i2][j2]);
    }
    __syncthreads();
  }
  #pragma unroll
  for(int i2=0;i2<4;i2++){
    #pragma unroll
    for(int r=0;r<4;r++){
      int n = nb + wr*64 + i2*16 + hi*4 + r;
      float di = 1.0f/den[(size_t)bh*SEQ + n];
      #pragma unroll
      for(int j2=0;j2<2;j2++){
        int dh = wc*32 + j2*16 + li;
        o[((size_t)b*SEQ + n)*DMODEL + h*DHEAD + dh] = f2bf(acc[i2][j2][r]*di);
      }
    }
  }
}

__global__ void k_init(float* ksum, float* kmax){
  int i = blockIdx.x*256 + threadIdx.x;
  if(i < BHN*MFEAT) ksum[i] = 0.f;
  if(i < BHN) kmax[i] = -INFINITY;
}

extern "C" void kernel_launch(void* const* d_in, const int* in_sizes, int n_in,
                              void* d_out, int out_size, void* d_ws, size_t ws_size,
                              hipStream_t stream){
  (void)in_sizes; (void)n_in; (void)out_size; (void)ws_size;
  const float* x    = (const float*)d_in[0];
  const float* proj = (const float*)d_in[1];
  const float* ln1g = (const float*)d_in[2];
  const float* ln1b = (const float*)d_in[3];
  const float* wq   = (const float*)d_in[4];
  const float* wk   = (const float*)d_in[5];
  const float* wv   = (const float*)d_in[6];
  const float* wo   = (const float*)d_in[7];
  const float* bo   = (const float*)d_in[8];
  const float* ln2g = (const float*)d_in[9];
  const float* ln2b = (const float*)d_in[10];
  const float* w1   = (const float*)d_in[11];
  const float* b1   = (const float*)d_in[12];
  const float* w2   = (const float*)d_in[13];
  const float* b2   = (const float*)d_in[14];
  float* xo = (float*)d_out;

  // workspace ~110 MB
  char* ws = (char*)d_ws;
  u16* bufH  = (u16*)ws;  ws += (size_t)TOK*DMODEL*2;       // 16.78 MB  h / o (bf16)
  u16* bufA  = (u16*)ws;  ws += (size_t)TOK*DMODEL*2;       // 16.78 MB  k / v_t / q / h2 (bf16)
  u16* featb = (u16*)ws;  ws += (size_t)BHN*SEQ*MFEAT*2;    // 67.11 MB  kp_t / qp / ffn1 (bf16)
  u16* ctxt  = (u16*)ws;  ws += (size_t)BHN*DHEAD*MFEAT*2;  //  2.10 MB
  u16* wT    = (u16*)ws;  ws += (size_t)3*1048576*2;        //  6.29 MB  per-layer bf16 W^T
  u16* pjb   = (u16*)ws;  ws += (size_t)LNUM*MFEAT*DHEAD*2; //  0.19 MB
  float* ksum= (float*)ws; ws += (size_t)BHN*MFEAT*4;       // 64 KB
  float* den = (float*)ws; ws += (size_t)BHN*SEQ*4;         // 512 KB
  float* kmax= (float*)ws; ws += 256;

  u16* wqT = wT;                 // [512][512]
  u16* wkT = wT +  262144;
  u16* wvT = wT +  524288;
  u16* woT = wT +  786432;
  u16* w1T = wT + 1048576;       // [2048][512]
  u16* w2T = wT + 2097152;       // [512][2048]

  k_addpe<<<(TOK*DMODEL)/256, 256, 0, stream>>>(x, xo);
  k_pcvt<<<(LNUM*MFEAT*DHEAD)/256, 256, 0, stream>>>(proj, pjb);

  for(int l=0; l<LNUM; l++){
    const u16* pj_l = pjb + (size_t)l*MFEAT*DHEAD;
    k_wcvt<<<dim3(8,8),  256, 0, stream>>>(wq + (size_t)l*262144,  wqT, DMODEL, DMODEL);
    k_wcvt<<<dim3(8,8),  256, 0, stream>>>(wk + (size_t)l*262144,  wkT, DMODEL, DMODEL);
    k_wcvt<<<dim3(8,8),  256, 0, stream>>>(wv + (size_t)l*262144,  wvT, DMODEL, DMODEL);
    k_wcvt<<<dim3(8,8),  256, 0, stream>>>(wo + (size_t)l*262144,  woT, DMODEL, DMODEL);
    k_wcvt<<<dim3(32,8), 256, 0, stream>>>(w1 + (size_t)l*1048576, w1T, DMODEL, DFF);
    k_wcvt<<<dim3(8,32), 256, 0, stream>>>(w2 + (size_t)l*1048576, w2T, DFF, DMODEL);

    k_init<<<64, 256, 0, stream>>>(ksum, kmax);
    k_ln<<<TOK, 256, 0, stream>>>(xo, ln1g + l*DMODEL, ln1b + l*DMODEL, bufH);
    // K path: k -> kmax -> kp_t (+ksum atomics)
    k_mm<1><<<dim3(4,128), 256, 0, stream>>>(bufH, wkT, nullptr, bufA, DMODEL, DMODEL);
    k_feat<0><<<(BHN*SEQ)/32, 256, 0, stream>>>(bufA, pj_l, nullptr, kmax, nullptr, nullptr);
    k_feat<1><<<(BHN*SEQ)/32, 256, 0, stream>>>(bufA, pj_l, featb, kmax, ksum, nullptr);
    // V path: v_t -> ctx_t
    k_mm<4><<<dim3(4,128), 256, 0, stream>>>(bufH, wvT, nullptr, bufA, DMODEL, DMODEL);
    k_ctx<<<dim3(4,BHN), 256, 0, stream>>>(bufA, featb, ctxt);
    // Q path: q -> qp + den -> o -> wo-GEMM (residual add)
    k_mm<1><<<dim3(4,128), 256, 0, stream>>>(bufH, wqT, nullptr, bufA, DMODEL, DMODEL);
    k_feat<2><<<(BHN*SEQ)/32, 256, 0, stream>>>(bufA, pj_l, featb, nullptr, ksum, den);
    k_o<<<dim3(SEQ/128,BHN), 256, 0, stream>>>(featb, ctxt, den, bufH);
    k_mm<2><<<dim3(4,128), 256, 0, stream>>>(bufH, woT, bo + l*DMODEL, xo, DMODEL, DMODEL);
    // FFN
    k_ln<<<TOK, 256, 0, stream>>>(xo, ln2g + l*DMODEL, ln2b + l*DMODEL, bufA);
    k_mm<3><<<dim3(16,128), 256, 0, stream>>>(bufA, w1T, b1 + l*DFF, featb, DFF, DMODEL);
    k_mm<2><<<dim3(4,128), 256, 0, stream>>>(featb, w2T, b2 + l*DMODEL, xo, DMODEL, DFF);
  }
}

// Round 10
// 2370.847 us; speedup vs baseline: 14.5967x; 1.0065x over previous
//
#include <hip/hip_runtime.h>
#include <math.h>

#define LNUM 6
#define HNUM 8
#define DMODEL 512
#define DHEAD 64
#define MFEAT 256
#define BATCH 8
#define SEQ 2048
#define TOK (BATCH*SEQ)
#define BHN (BATCH*HNUM)
#define DFF 2048
#define EPSF 1e-4f
#define LN_EPS 1e-5f
#define DNRM 0.35355339059327373f
#define SMF 0.0625f

typedef unsigned short u16;
typedef __attribute__((ext_vector_type(8))) short bf16x8;
typedef __attribute__((ext_vector_type(4))) float f32x4;
#define MFMA16(a,b,c) __builtin_amdgcn_mfma_f32_16x16x32_bf16(a,b,c,0,0,0)

// async global->LDS, 16B per lane; LDS dest = wave-uniform base + lane*16
#define GLOAD16(g,l) __builtin_amdgcn_global_load_lds( \
    (const __attribute__((address_space(1))) void*)(g), \
    (__attribute__((address_space(3))) void*)(l), 16, 0, 0)

__device__ __forceinline__ u16 f2bf(float f){
  unsigned int u = __float_as_uint(f);
  u = (u + 0x7fffu + ((u >> 16) & 1u)) >> 16;
  return (u16)u;
}
__device__ __forceinline__ float bf2f(u16 s){
  return __uint_as_float(((unsigned int)s) << 16);
}
__device__ __forceinline__ void atomicMaxF(float* addr, float val){
  if(val >= 0.f) atomicMax((int*)addr, __float_as_int(val));
  else           atomicMin((unsigned int*)addr, __float_as_uint(val));
}
// gelu tanh-approx: z * sigmoid(2*(c1 z + c2 z^3))
__device__ __forceinline__ float fast_gelu(float z){
  float g2 = z*(1.5957691216f + 0.07135481628f*z*z);
  return z / (1.0f + __expf(-g2));
}

// ---------------- x = x + sinusoidal PE ----------------
__global__ void k_addpe(const float* __restrict__ x, float* __restrict__ xo){
  int idx = blockIdx.x*256 + threadIdx.x;
  int d = idx & (DMODEL-1);
  int n = (idx >> 9) & (SEQ-1);
  int j = d >> 1;
  float freq = expf((float)(2*j) * (-9.210340371976184f / (float)DMODEL));
  float ang = (float)n * freq;
  float pe = (d & 1) ? cosf(ang) : sinf(ang);
  xo[idx] = x[idx] + pe;
}

// ---------------- LayerNorm (512) -> bf16 ----------------
__global__ void k_ln(const float* __restrict__ x, const float* __restrict__ g,
                     const float* __restrict__ bv, u16* __restrict__ out){
  __shared__ float sred[8];
  int t = blockIdx.x, tid = threadIdx.x;
  const float2 v = ((const float2*)(x + (size_t)t*DMODEL))[tid];
  float s = v.x + v.y;
  #pragma unroll
  for(int o=32;o;o>>=1) s += __shfl_down(s,o);
  if((tid&63)==0) sred[tid>>6] = s;
  __syncthreads();
  if(tid==0) sred[4] = (sred[0]+sred[1]+sred[2]+sred[3]) * (1.0f/DMODEL);
  __syncthreads();
  float mu = sred[4];
  float dx = v.x - mu, dy = v.y - mu;
  float s2 = dx*dx + dy*dy;
  #pragma unroll
  for(int o=32;o;o>>=1) s2 += __shfl_down(s2,o);
  if((tid&63)==0) sred[tid>>6] = s2;
  __syncthreads();
  if(tid==0) sred[5] = rsqrtf((sred[0]+sred[1]+sred[2]+sred[3])*(1.0f/DMODEL) + LN_EPS);
  __syncthreads();
  float rs = sred[5];
  const float2 gg = ((const float2*)g)[tid];
  const float2 bb = ((const float2*)bv)[tid];
  ushort2 o2; o2.x = f2bf(dx*rs*gg.x + bb.x); o2.y = f2bf(dy*rs*gg.y + bb.y);
  ((ushort2*)(out + (size_t)t*DMODEL))[tid] = o2;
}

__global__ void k_pcvt(const float* __restrict__ p, u16* __restrict__ pb){
  int i = blockIdx.x*256 + threadIdx.x;
  pb[i] = f2bf(p[i]);
}

// ---------------- all weight transposes + ksum/kmax init in ONE dispatch ----------------
// blocks 0..255: wq/wk/wv/wo (64 each, 8x8)   256..511: w1 (32x8)   512..767: w2 (8x32)
// blocks 768..831: init ksum (16384) + kmax (64)
__global__ void k_wcvt_all(const float* __restrict__ wq, const float* __restrict__ wk,
                           const float* __restrict__ wv, const float* __restrict__ wo,
                           const float* __restrict__ w1, const float* __restrict__ w2,
                           u16* __restrict__ wqT, u16* __restrict__ wkT,
                           u16* __restrict__ wvT, u16* __restrict__ woT,
                           u16* __restrict__ w1T, u16* __restrict__ w2T,
                           float* __restrict__ ksum, float* __restrict__ kmax){
  int bid = blockIdx.x;
  if(bid >= 768){
    int i = (bid-768)*256 + threadIdx.x;
    ksum[i] = 0.f;
    if(i < BHN) kmax[i] = -INFINITY;
    return;
  }
  const float* src; u16* dst; int K, N, bx, by;
  if(bid < 256){
    int which = bid >> 6, sub = bid & 63;
    src = which==0 ? wq : which==1 ? wk : which==2 ? wv : wo;
    dst = which==0 ? wqT : which==1 ? wkT : which==2 ? wvT : woT;
    K = 512; N = 512; bx = sub & 7; by = sub >> 3;
  } else if(bid < 512){
    int sub = bid - 256; src = w1; dst = w1T; K = 512; N = 2048; bx = sub & 31; by = sub >> 5;
  } else {
    int sub = bid - 512; src = w2; dst = w2T; K = 2048; N = 512; bx = sub & 7; by = sub >> 3;
  }
  __shared__ float sm[64][65];
  int kt = by*64, nt = bx*64;
  int t = threadIdx.x, c = t & 63, r4 = t >> 6;
  #pragma unroll
  for(int i=0;i<16;i++){
    int kl = i*4 + r4;
    sm[kl][c] = src[(size_t)(kt+kl)*N + nt + c];
  }
  __syncthreads();
  #pragma unroll
  for(int i=0;i<16;i++){
    int nl = i*4 + r4;
    dst[(size_t)(nt+nl)*K + kt + c] = f2bf(sm[c][nl]);
  }
}

// ---------------- MFMA GEMM, BK=32, depth-2, counted vmcnt, 128-reg cap ----------------
// LDS[buf][r][c] holds global chunk c ^ ((r>>1)&3); staging source pre-swizzled.
// EPI 1: split-head bf16 [bh][n][dh]   2: f32 C += acc+bias
// EPI 3: bf16 C = gelu(acc+bias)       4: v_t bf16 [bh][dh][n]
template<int EPI>
__global__ __launch_bounds__(256,4)
void k_mm(const u16* __restrict__ A, const u16* __restrict__ Bt,
          const float* __restrict__ bias, void* __restrict__ Cv,
          int Nc, int K){
  __shared__ u16 As[2][128*32];
  __shared__ u16 Bs[2][128*32];
  int tid = threadIdx.x;
  int w = tid >> 6, lane = tid & 63;
  int wr = w >> 1, wc = w & 1;
  int hi = lane >> 4, li = lane & 15;
  int row0 = blockIdx.y*128, col0 = blockIdx.x*128;
  int lr = lane >> 2;
  int cs = (lane & 3) ^ ((lane >> 3) & 3);
  const u16* gA = A  + (size_t)(row0 + w*16 + lr)*K + cs*8;
  const u16* gB = Bt + (size_t)(col0 + w*16 + lr)*K + cs*8;
  int rb = li*32 + ((hi ^ ((li>>1)&3))<<3);
  f32x4 acc[4][4] = {};

#define STAGE_MM(b,k0) { \
    GLOAD16(gA + (k0),                &As[b][(w*16)*32]);      \
    GLOAD16(gA + (size_t)64*K + (k0), &As[b][(64+w*16)*32]);   \
    GLOAD16(gB + (k0),                &Bs[b][(w*16)*32]);      \
    GLOAD16(gB + (size_t)64*K + (k0), &Bs[b][(64+w*16)*32]); }

  int nk = K >> 5;
  STAGE_MM(0, 0)
  STAGE_MM(1, 32)
  for(int t=0; t<nk; ++t){
    __builtin_amdgcn_sched_barrier(0);
    if(t+1 < nk){ asm volatile("s_waitcnt vmcnt(4)"); }
    else        { asm volatile("s_waitcnt vmcnt(0)"); }
    __builtin_amdgcn_s_barrier();
    __builtin_amdgcn_sched_barrier(0);
    const u16* pa = &As[t&1][0];
    const u16* pb = &Bs[t&1][0];
    bf16x8 bfr[4];
    #pragma unroll
    for(int q=0;q<4;q++) bfr[q] = *(const bf16x8*)&pb[rb + wc*2048 + q*512];
    #pragma unroll
    for(int i2=0;i2<4;i2++){
      bf16x8 a = *(const bf16x8*)&pa[rb + wr*2048 + i2*512];
      #pragma unroll
      for(int j2=0;j2<4;j2++)
        acc[i2][j2] = MFMA16(a, bfr[j2], acc[i2][j2]);
    }
    __builtin_amdgcn_sched_barrier(0);
    __builtin_amdgcn_s_barrier();
    __builtin_amdgcn_sched_barrier(0);
    if(t+2 < nk){ STAGE_MM(t&1, (size_t)(t+2)*32) }
  }
#undef STAGE_MM

  #pragma unroll
  for(int i2=0;i2<4;i2++){
    #pragma unroll
    for(int j2=0;j2<4;j2++){
      int col = col0 + wc*64 + j2*16 + li;
      float bcol = (EPI==2 || EPI==3) ? bias[col] : 0.f;
      if constexpr (EPI==4){
        int nb = row0 + wr*64 + i2*16 + hi*4;
        int b = nb >> 11, n = nb & (SEQ-1);
        int h = col >> 6, dh = col & 63;
        ushort4 pk;
        pk.x = f2bf(acc[i2][j2][0]); pk.y = f2bf(acc[i2][j2][1]);
        pk.z = f2bf(acc[i2][j2][2]); pk.w = f2bf(acc[i2][j2][3]);
        *(ushort4*)((u16*)Cv + (((size_t)(b*HNUM+h)*DHEAD + dh)*SEQ + n)) = pk;
      } else {
        #pragma unroll
        for(int r=0;r<4;r++){
          int row = row0 + wr*64 + i2*16 + hi*4 + r;
          float v = acc[i2][j2][r];
          if constexpr (EPI==1){
            int b = row >> 11, n = row & (SEQ-1);
            int h = col >> 6, dh = col & 63;
            ((u16*)Cv)[((size_t)(b*HNUM+h)*SEQ + n)*DHEAD + dh] = f2bf(v);
          } else if constexpr (EPI==2){
            ((float*)Cv)[(size_t)row*Nc + col] += v + bcol;
          } else {
            ((u16*)Cv)[(size_t)row*Nc + col] = f2bf(fast_gelu(v + bcol));
          }
        }
      }
    }
  }
}

// ---------------- K-feature passes (PHASE 0: bh max; PHASE 1: kp_t + ksum) ----------------
template<int PHASE>
__global__ __launch_bounds__(256)
void k_feat(const u16* __restrict__ xg, const u16* __restrict__ pjb,
            u16* __restrict__ outp, float* __restrict__ kmax,
            float* __restrict__ ksum){
  __shared__ u16 pj[256*64];
  __shared__ u16 xs[32*64];
  __shared__ float dgs[32];
  __shared__ float wred[4][32];
  int tid = threadIdx.x, w = tid >> 6, lane = tid & 63;
  int hi = lane >> 4, li = lane & 15;
  int r0 = blockIdx.x * 32;
  int bh = r0 >> 11;
  #pragma unroll
  for(int i=0;i<8;i++){
    int idx = i*256 + tid;
    int m = idx >> 3, c = idx & 7;
    bf16x8 v = *(const bf16x8*)(pjb + m*64 + c*8);
    *(bf16x8*)&pj[m*64 + ((c ^ (m&7))<<3)] = v;
  }
  {
    int m = tid >> 3, c = tid & 7;
    bf16x8 v = *(const bf16x8*)(xg + (size_t)(r0+m)*64 + c*8);
    *(bf16x8*)&xs[m*64 + ((c ^ (m&7))<<3)] = v;
  }
  __syncthreads();
  if constexpr (PHASE==1){
    if(tid < 32){
      float s = 0.f;
      #pragma unroll
      for(int d=0;d<64;d++){ float t = bf2f(xs[tid*64 + d]); s += t*t; }
      dgs[tid] = 0.5f*DNRM*DNRM*s;
    }
  }
  f32x4 acc[2][4] = {};
  #pragma unroll
  for(int ks=0;ks<2;ks++){
    bf16x8 af[2], bfr[4];
    int kc = ks*4 + hi;
    #pragma unroll
    for(int t=0;t<2;t++){
      int ar = t*16 + li;
      af[t] = *(const bf16x8*)&xs[ar*64 + ((kc ^ (ar&7))<<3)];
    }
    #pragma unroll
    for(int t=0;t<4;t++){
      int bc = w*64 + t*16 + li;
      bfr[t] = *(const bf16x8*)&pj[bc*64 + ((kc ^ (bc&7))<<3)];
    }
    #pragma unroll
    for(int i2=0;i2<2;i2++)
      #pragma unroll
      for(int j2=0;j2<4;j2++)
        acc[i2][j2] = MFMA16(af[i2], bfr[j2], acc[i2][j2]);
  }
  __syncthreads();
  if constexpr (PHASE==0){
    float mx = -1e30f;
    #pragma unroll
    for(int i2=0;i2<2;i2++)
      #pragma unroll
      for(int j2=0;j2<4;j2++)
        #pragma unroll
        for(int r=0;r<4;r++) mx = fmaxf(mx, acc[i2][j2][r]);
    #pragma unroll
    for(int o=32;o;o>>=1) mx = fmaxf(mx, __shfl_xor(mx,o));
    if(lane==0) wred[w][0] = mx;
    __syncthreads();
    if(tid==0){
      float m2 = fmaxf(fmaxf(wred[0][0],wred[1][0]), fmaxf(wred[2][0],wred[3][0]));
      atomicMaxF(&kmax[bh], m2*DNRM);
    }
  } else {
    float km = kmax[bh];
    float csum[4] = {0.f,0.f,0.f,0.f};
    #pragma unroll
    for(int i2=0;i2<2;i2++){
      #pragma unroll
      for(int j2=0;j2<4;j2++){
        int col = w*64 + j2*16 + li;
        ushort4 pk;
        float cpart = 0.f;
        #pragma unroll
        for(int r=0;r<4;r++){
          int rl = i2*16 + hi*4 + r;
          float u = acc[i2][j2][r]*DNRM;
          u16 eb = f2bf(SMF*(expf(u - dgs[rl] - km) + EPSF));
          ((u16*)&pk)[r] = eb;
          cpart += bf2f(eb);
        }
        *(ushort4*)(outp + ((size_t)(bh*MFEAT + col)*SEQ + (r0 & (SEQ-1)) + i2*16 + hi*4)) = pk;
        csum[j2] += cpart;
      }
    }
    #pragma unroll
    for(int j2=0;j2<4;j2++){
      float v = csum[j2];
      v += __shfl_xor(v,16); v += __shfl_xor(v,32);
      if(hi==0) atomicAdd(&ksum[bh*MFEAT + w*64 + j2*16 + li], v);
    }
  }
}

// ---------------- fused Q-feature + PV: q -> qp (LDS) -> o = (qp@ctx^T)/den ----------------
__global__ __launch_bounds__(256)
void k_feato(const u16* __restrict__ xg, const u16* __restrict__ pjb,
             const u16* __restrict__ ctxt, const float* __restrict__ ksum,
             u16* __restrict__ o){
  __shared__ u16 smA[16384];   // pj (swz) -> ctx (swz) after u-MFMA
  __shared__ u16 smX[2048];    // q rows (swz)
  __shared__ u16 smQ[8192];    // qp (swz)
  __shared__ float dgs[32];
  __shared__ float wred[4][32];
  __shared__ float wden[4][32];
  __shared__ float ksl[256];
  __shared__ float denl[32];
  int tid = threadIdx.x, w = tid >> 6, lane = tid & 63;
  int hi = lane >> 4, li = lane & 15;
  int r0 = blockIdx.x * 32;
  int bh = r0 >> 11;
  int b = bh >> 3, h = bh & 7;
  #pragma unroll
  for(int i=0;i<8;i++){
    int idx = i*256 + tid;
    int m = idx >> 3, c = idx & 7;
    bf16x8 v = *(const bf16x8*)(pjb + m*64 + c*8);
    *(bf16x8*)&smA[m*64 + ((c ^ (m&7))<<3)] = v;
  }
  {
    int m = tid >> 3, c = tid & 7;
    bf16x8 v = *(const bf16x8*)(xg + (size_t)(r0+m)*64 + c*8);
    *(bf16x8*)&smX[m*64 + ((c ^ (m&7))<<3)] = v;
  }
  ksl[tid] = ksum[bh*MFEAT + tid];
  __syncthreads();
  if(tid < 32){
    float s = 0.f;
    #pragma unroll
    for(int d=0;d<64;d++){ float t = bf2f(smX[tid*64 + d]); s += t*t; }
    dgs[tid] = 0.5f*DNRM*DNRM*s;
  }
  f32x4 acc[2][4] = {};
  #pragma unroll
  for(int ks=0;ks<2;ks++){
    bf16x8 af[2], bfr[4];
    int kc = ks*4 + hi;
    #pragma unroll
    for(int t=0;t<2;t++){
      int ar = t*16 + li;
      af[t] = *(const bf16x8*)&smX[ar*64 + ((kc ^ (ar&7))<<3)];
    }
    #pragma unroll
    for(int t=0;t<4;t++){
      int bc = w*64 + t*16 + li;
      bfr[t] = *(const bf16x8*)&smA[bc*64 + ((kc ^ (bc&7))<<3)];
    }
    #pragma unroll
    for(int i2=0;i2<2;i2++)
      #pragma unroll
      for(int j2=0;j2<4;j2++)
        acc[i2][j2] = MFMA16(af[i2], bfr[j2], acc[i2][j2]);
  }
  __syncthreads();   // all pj reads done; dgs visible; smA reusable
  // async ctx_t[bh] (64x256 bf16) -> smA, swizzled source, linear dest
  {
    int Lc0 = w*64 + lane;
    int row0 = Lc0 >> 5, c0 = Lc0 & 31;
    const u16* gCl = ctxt + (size_t)bh*DHEAD*MFEAT + ((size_t)row0*32 + (c0 ^ (row0&7)))*8;
    #pragma unroll
    for(int i=0;i<8;i++)
      GLOAD16(gCl + i*2048, &smA[i*2048 + w*512]);
  }
  // per-row max over m
  #pragma unroll
  for(int i2=0;i2<2;i2++){
    #pragma unroll
    for(int r=0;r<4;r++){
      float v = fmaxf(fmaxf(acc[i2][0][r],acc[i2][1][r]), fmaxf(acc[i2][2][r],acc[i2][3][r]));
      v = fmaxf(v, __shfl_xor(v,1)); v = fmaxf(v, __shfl_xor(v,2));
      v = fmaxf(v, __shfl_xor(v,4)); v = fmaxf(v, __shfl_xor(v,8));
      if(li==0) wred[w][i2*16 + hi*4 + r] = v;
    }
  }
  __builtin_amdgcn_sched_barrier(0);
  asm volatile("s_waitcnt lgkmcnt(0)");
  __builtin_amdgcn_s_barrier();
  __builtin_amdgcn_sched_barrier(0);
  // qp = exp(u - diag - rowmax)*s + eps -> smQ ; den partial = qp . ksum
  #pragma unroll
  for(int i2=0;i2<2;i2++){
    #pragma unroll
    for(int r=0;r<4;r++){
      int rl = i2*16 + hi*4 + r;
      float rm = fmaxf(fmaxf(wred[0][rl],wred[1][rl]), fmaxf(wred[2][rl],wred[3][rl]));
      float dsum = 0.f;
      #pragma unroll
      for(int j2=0;j2<4;j2++){
        int col = w*64 + j2*16 + li;
        float u = acc[i2][j2][r]*DNRM;
        u16 eb = f2bf(SMF*(expf(u - dgs[rl] - rm) + EPSF));
        smQ[rl*256 + (((col>>3) ^ (rl&7))<<3) + (col&7)] = eb;
        dsum += bf2f(eb)*ksl[col];
      }
      dsum += __shfl_xor(dsum,1); dsum += __shfl_xor(dsum,2);
      dsum += __shfl_xor(dsum,4); dsum += __shfl_xor(dsum,8);
      if(li==0) wden[w][rl] = dsum;
    }
  }
  __builtin_amdgcn_sched_barrier(0);
  asm volatile("s_waitcnt vmcnt(0) lgkmcnt(0)");
  __builtin_amdgcn_s_barrier();
  __builtin_amdgcn_sched_barrier(0);
  if(tid < 32) denl[tid] = wden[0][tid]+wden[1][tid]+wden[2][tid]+wden[3][tid];
  // PV: wave w owns dh-tile w (16 dh) x 32 rows; K=256 over m
  f32x4 acc2[2] = {};
  #pragma unroll
  for(int s=0;s<8;s++){
    int kc = s*4 + hi;
    int bc = w*16 + li;
    bf16x8 bf = *(const bf16x8*)&smA[bc*256 + ((kc ^ (bc&7))<<3)];
    #pragma unroll
    for(int t=0;t<2;t++){
      int ar = t*16 + li;
      bf16x8 aa = *(const bf16x8*)&smQ[ar*256 + ((kc ^ (ar&7))<<3)];
      acc2[t] = MFMA16(aa, bf, acc2[t]);
    }
  }
  __syncthreads();   // denl visible
  int nbase = r0 & (SEQ-1);
  #pragma unroll
  for(int t=0;t<2;t++){
    #pragma unroll
    for(int r=0;r<4;r++){
      int nl = t*16 + hi*4 + r;
      float di = 1.0f/denl[nl];
      o[((size_t)b*SEQ + nbase + nl)*DMODEL + h*DHEAD + w*16 + li] = f2bf(acc2[t][r]*di);
    }
  }
}

// ---------------- ctx_t[bh][dh][m] = sum_n v_t[dh][n]*kp_t[m][n], depth-2 pipeline ----------------
__global__ __launch_bounds__(256)
void k_ctx(const u16* __restrict__ vt, const u16* __restrict__ kpt,
           u16* __restrict__ ctxt){
  __shared__ u16 As[2][64*64];
  __shared__ u16 Bs[2][64*64];
  int tid = threadIdx.x, w = tid >> 6, lane = tid & 63;
  int wr = w >> 1, wc = w & 1;
  int hi = lane >> 4, li = lane & 15;
  int bh = blockIdx.y, mb = blockIdx.x*64;
  int lr = lane >> 3;
  int lc = (lane & 7) ^ lr;
  const u16* gA = vt  + (size_t)bh*DHEAD*SEQ + (size_t)(w*8 + lr)*SEQ + lc*8;
  const u16* gB = kpt + ((size_t)bh*MFEAT + mb + w*8 + lr)*SEQ + lc*8;
  f32x4 acc[2][2] = {};
#define STAGE_CTX(b,k0) { \
    GLOAD16(gA + (k0),                 &As[b][(w*8)*64]);      \
    GLOAD16(gA + (size_t)32*SEQ + (k0),&As[b][(32+w*8)*64]);   \
    GLOAD16(gB + (k0),                 &Bs[b][(w*8)*64]);      \
    GLOAD16(gB + (size_t)32*SEQ + (k0),&Bs[b][(32+w*8)*64]); }
  int nk = SEQ/64;
  STAGE_CTX(0, 0)
  STAGE_CTX(1, 64)
  for(int t=0; t<nk; ++t){
    __builtin_amdgcn_sched_barrier(0);
    if(t+1 < nk){ asm volatile("s_waitcnt vmcnt(4)"); }
    else        { asm volatile("s_waitcnt vmcnt(0)"); }
    __builtin_amdgcn_s_barrier();
    __builtin_amdgcn_sched_barrier(0);
    const u16* pa = &As[t&1][0];
    const u16* pb = &Bs[t&1][0];
    #pragma unroll
    for(int ks=0;ks<2;ks++){
      bf16x8 af[2], bfr[2];
      int kc = ks*4 + hi;
      #pragma unroll
      for(int q=0;q<2;q++){
        int ar = wr*32 + q*16 + li;
        af[q] = *(const bf16x8*)&pa[ar*64 + ((kc ^ (ar&7))<<3)];
        int bc = wc*32 + q*16 + li;
        bfr[q] = *(const bf16x8*)&pb[bc*64 + ((kc ^ (bc&7))<<3)];
      }
      #pragma unroll
      for(int i2=0;i2<2;i2++)
        #pragma unroll
        for(int j2=0;j2<2;j2++)
          acc[i2][j2] = MFMA16(af[i2], bfr[j2], acc[i2][j2]);
    }
    __builtin_amdgcn_sched_barrier(0);
    __builtin_amdgcn_s_barrier();
    __builtin_amdgcn_sched_barrier(0);
    if(t+2 < nk){ STAGE_CTX(t&1, (size_t)(t+2)*64) }
  }
#undef STAGE_CTX
  #pragma unroll
  for(int i2=0;i2<2;i2++)
    #pragma unroll
    for(int j2=0;j2<2;j2++){
      int m = mb + wc*32 + j2*16 + li;
      #pragma unroll
      for(int r=0;r<4;r++){
        int dh = wr*32 + i2*16 + hi*4 + r;
        ctxt[((size_t)bh*DHEAD + dh)*MFEAT + m] = f2bf(acc[i2][j2][r]);
      }
    }
}

extern "C" void kernel_launch(void* const* d_in, const int* in_sizes, int n_in,
                              void* d_out, int out_size, void* d_ws, size_t ws_size,
                              hipStream_t stream){
  (void)in_sizes; (void)n_in; (void)out_size; (void)ws_size;
  const float* x    = (const float*)d_in[0];
  const float* proj = (const float*)d_in[1];
  const float* ln1g = (const float*)d_in[2];
  const float* ln1b = (const float*)d_in[3];
  const float* wq   = (const float*)d_in[4];
  const float* wk   = (const float*)d_in[5];
  const float* wv   = (const float*)d_in[6];
  const float* wo   = (const float*)d_in[7];
  const float* bo   = (const float*)d_in[8];
  const float* ln2g = (const float*)d_in[9];
  const float* ln2b = (const float*)d_in[10];
  const float* w1   = (const float*)d_in[11];
  const float* b1   = (const float*)d_in[12];
  const float* w2   = (const float*)d_in[13];
  const float* b2   = (const float*)d_in[14];
  float* xo = (float*)d_out;

  // workspace ~110 MB (layout unchanged from round 9)
  char* ws = (char*)d_ws;
  u16* bufH  = (u16*)ws;  ws += (size_t)TOK*DMODEL*2;
  u16* bufA  = (u16*)ws;  ws += (size_t)TOK*DMODEL*2;
  u16* featb = (u16*)ws;  ws += (size_t)BHN*SEQ*MFEAT*2;
  u16* ctxt  = (u16*)ws;  ws += (size_t)BHN*DHEAD*MFEAT*2;
  u16* wT    = (u16*)ws;  ws += (size_t)3*1048576*2;
  u16* pjb   = (u16*)ws;  ws += (size_t)LNUM*MFEAT*DHEAD*2;
  float* ksum= (float*)ws; ws += (size_t)BHN*MFEAT*4;
  float* den = (float*)ws; ws += (size_t)BHN*SEQ*4;  (void)den;
  float* kmax= (float*)ws; ws += 256;

  u16* wqT = wT;
  u16* wkT = wT +  262144;
  u16* wvT = wT +  524288;
  u16* woT = wT +  786432;
  u16* w1T = wT + 1048576;
  u16* w2T = wT + 2097152;

  k_addpe<<<(TOK*DMODEL)/256, 256, 0, stream>>>(x, xo);
  k_pcvt<<<(LNUM*MFEAT*DHEAD)/256, 256, 0, stream>>>(proj, pjb);

  for(int l=0; l<LNUM; l++){
    const u16* pj_l = pjb + (size_t)l*MFEAT*DHEAD;
    k_wcvt_all<<<832, 256, 0, stream>>>(wq + (size_t)l*262144, wk + (size_t)l*262144,
                                        wv + (size_t)l*262144, wo + (size_t)l*262144,
                                        w1 + (size_t)l*1048576, w2 + (size_t)l*1048576,
                                        wqT, wkT, wvT, woT, w1T, w2T, ksum, kmax);
    k_ln<<<TOK, 256, 0, stream>>>(xo, ln1g + l*DMODEL, ln1b + l*DMODEL, bufH);
    // K path: k -> kmax -> kp_t (+ksum atomics)
    k_mm<1><<<dim3(4,128), 256, 0, stream>>>(bufH, wkT, nullptr, bufA, DMODEL, DMODEL);
    k_feat<0><<<(BHN*SEQ)/32, 256, 0, stream>>>(bufA, pj_l, nullptr, kmax, nullptr);
    k_feat<1><<<(BHN*SEQ)/32, 256, 0, stream>>>(bufA, pj_l, featb, kmax, ksum);
    // V path: v_t -> ctx_t
    k_mm<4><<<dim3(4,128), 256, 0, stream>>>(bufH, wvT, nullptr, bufA, DMODEL, DMODEL);
    k_ctx<<<dim3(4,BHN), 256, 0, stream>>>(bufA, featb, ctxt);
    // Q path fused: q -> qp (LDS) -> o  -> wo-GEMM (residual add)
    k_mm<1><<<dim3(4,128), 256, 0, stream>>>(bufH, wqT, nullptr, bufA, DMODEL, DMODEL);
    k_feato<<<(BHN*SEQ)/32, 256, 0, stream>>>(bufA, pj_l, ctxt, ksum, bufH);
    k_mm<2><<<dim3(4,128), 256, 0, stream>>>(bufH, woT, bo + l*DMODEL, xo, DMODEL, DMODEL);
    // FFN
    k_ln<<<TOK, 256, 0, stream>>>(xo, ln2g + l*DMODEL, ln2b + l*DMODEL, bufA);
    k_mm<3><<<dim3(16,128), 256, 0, stream>>>(bufA, w1T, b1 + l*DFF, featb, DFF, DMODEL);
    k_mm<2><<<dim3(4,128), 256, 0, stream>>>(featb, w2T, b2 + l*DMODEL, xo, DMODEL, DFF);
  }
}

// Round 11
// 2338.858 us; speedup vs baseline: 14.7963x; 1.0137x over previous
//
#include <hip/hip_runtime.h>
#include <math.h>

#define LNUM 6
#define HNUM 8
#define DMODEL 512
#define DHEAD 64
#define MFEAT 256
#define BATCH 8
#define SEQ 2048
#define TOK (BATCH*SEQ)
#define BHN (BATCH*HNUM)
#define DFF 2048
#define EPSF 1e-4f
#define LN_EPS 1e-5f
#define DNRM 0.35355339059327373f
#define SMF 0.0625f

typedef unsigned short u16;
typedef __attribute__((ext_vector_type(8))) short bf16x8;
typedef __attribute__((ext_vector_type(4))) float f32x4;
#define MFMA16(a,b,c) __builtin_amdgcn_mfma_f32_16x16x32_bf16(a,b,c,0,0,0)

// async global->LDS, 16B per lane; LDS dest = wave-uniform base + lane*16
#define GLOAD16(g,l) __builtin_amdgcn_global_load_lds( \
    (const __attribute__((address_space(1))) void*)(g), \
    (__attribute__((address_space(3))) void*)(l), 16, 0, 0)

__device__ __forceinline__ u16 f2bf(float f){
  unsigned int u = __float_as_uint(f);
  u = (u + 0x7fffu + ((u >> 16) & 1u)) >> 16;
  return (u16)u;
}
__device__ __forceinline__ float bf2f(u16 s){
  return __uint_as_float(((unsigned int)s) << 16);
}
__device__ __forceinline__ void atomicMaxF(float* addr, float val){
  if(val >= 0.f) atomicMax((int*)addr, __float_as_int(val));
  else           atomicMin((unsigned int*)addr, __float_as_uint(val));
}
// gelu tanh-approx: z * sigmoid(2*(c1 z + c2 z^3))
__device__ __forceinline__ float fast_gelu(float z){
  float g2 = z*(1.5957691216f + 0.07135481628f*z*z);
  return z / (1.0f + __expf(-g2));
}

// ---------------- x = x + sinusoidal PE ----------------
__global__ void k_addpe(const float* __restrict__ x, float* __restrict__ xo){
  int idx = blockIdx.x*256 + threadIdx.x;
  int d = idx & (DMODEL-1);
  int n = (idx >> 9) & (SEQ-1);
  int j = d >> 1;
  float freq = expf((float)(2*j) * (-9.210340371976184f / (float)DMODEL));
  float ang = (float)n * freq;
  float pe = (d & 1) ? cosf(ang) : sinf(ang);
  xo[idx] = x[idx] + pe;
}

// ---------------- LayerNorm (512) -> bf16 ----------------
__global__ void k_ln(const float* __restrict__ x, const float* __restrict__ g,
                     const float* __restrict__ bv, u16* __restrict__ out){
  __shared__ float sred[8];
  int t = blockIdx.x, tid = threadIdx.x;
  const float2 v = ((const float2*)(x + (size_t)t*DMODEL))[tid];
  float s = v.x + v.y;
  #pragma unroll
  for(int o=32;o;o>>=1) s += __shfl_down(s,o);
  if((tid&63)==0) sred[tid>>6] = s;
  __syncthreads();
  if(tid==0) sred[4] = (sred[0]+sred[1]+sred[2]+sred[3]) * (1.0f/DMODEL);
  __syncthreads();
  float mu = sred[4];
  float dx = v.x - mu, dy = v.y - mu;
  float s2 = dx*dx + dy*dy;
  #pragma unroll
  for(int o=32;o;o>>=1) s2 += __shfl_down(s2,o);
  if((tid&63)==0) sred[tid>>6] = s2;
  __syncthreads();
  if(tid==0) sred[5] = rsqrtf((sred[0]+sred[1]+sred[2]+sred[3])*(1.0f/DMODEL) + LN_EPS);
  __syncthreads();
  float rs = sred[5];
  const float2 gg = ((const float2*)g)[tid];
  const float2 bb = ((const float2*)bv)[tid];
  ushort2 o2; o2.x = f2bf(dx*rs*gg.x + bb.x); o2.y = f2bf(dy*rs*gg.y + bb.y);
  ((ushort2*)(out + (size_t)t*DMODEL))[tid] = o2;
}

__global__ void k_pcvt(const float* __restrict__ p, u16* __restrict__ pb){
  int i = blockIdx.x*256 + threadIdx.x;
  pb[i] = f2bf(p[i]);
}

// ---------------- all weight transposes + ksum/kmax init in ONE dispatch ----------------
__global__ void k_wcvt_all(const float* __restrict__ wq, const float* __restrict__ wk,
                           const float* __restrict__ wv, const float* __restrict__ wo,
                           const float* __restrict__ w1, const float* __restrict__ w2,
                           u16* __restrict__ wqT, u16* __restrict__ wkT,
                           u16* __restrict__ wvT, u16* __restrict__ woT,
                           u16* __restrict__ w1T, u16* __restrict__ w2T,
                           float* __restrict__ ksum, float* __restrict__ kmax){
  int bid = blockIdx.x;
  if(bid >= 768){
    int i = (bid-768)*256 + threadIdx.x;
    ksum[i] = 0.f;
    if(i < BHN) kmax[i] = -INFINITY;
    return;
  }
  const float* src; u16* dst; int K, N, bx, by;
  if(bid < 256){
    int which = bid >> 6, sub = bid & 63;
    src = which==0 ? wq : which==1 ? wk : which==2 ? wv : wo;
    dst = which==0 ? wqT : which==1 ? wkT : which==2 ? wvT : woT;
    K = 512; N = 512; bx = sub & 7; by = sub >> 3;
  } else if(bid < 512){
    int sub = bid - 256; src = w1; dst = w1T; K = 512; N = 2048; bx = sub & 31; by = sub >> 5;
  } else {
    int sub = bid - 512; src = w2; dst = w2T; K = 2048; N = 512; bx = sub & 7; by = sub >> 3;
  }
  __shared__ float sm[64][65];
  int kt = by*64, nt = bx*64;
  int t = threadIdx.x, c = t & 63, r4 = t >> 6;
  #pragma unroll
  for(int i=0;i<16;i++){
    int kl = i*4 + r4;
    sm[kl][c] = src[(size_t)(kt+kl)*N + nt + c];
  }
  __syncthreads();
  #pragma unroll
  for(int i=0;i<16;i++){
    int nl = i*4 + r4;
    dst[(size_t)(nt+nl)*K + kt + c] = f2bf(sm[c][nl]);
  }
}

// ---------------- MFMA GEMM, BK=32, depth-2, counted vmcnt, 128-reg cap ----------------
template<int EPI>
__global__ __launch_bounds__(256,4)
void k_mm(const u16* __restrict__ A, const u16* __restrict__ Bt,
          const float* __restrict__ bias, void* __restrict__ Cv,
          int Nc, int K){
  __shared__ u16 As[2][128*32];
  __shared__ u16 Bs[2][128*32];
  int tid = threadIdx.x;
  int w = tid >> 6, lane = tid & 63;
  int wr = w >> 1, wc = w & 1;
  int hi = lane >> 4, li = lane & 15;
  int row0 = blockIdx.y*128, col0 = blockIdx.x*128;
  int lr = lane >> 2;
  int cs = (lane & 3) ^ ((lane >> 3) & 3);
  const u16* gA = A  + (size_t)(row0 + w*16 + lr)*K + cs*8;
  const u16* gB = Bt + (size_t)(col0 + w*16 + lr)*K + cs*8;
  int rb = li*32 + ((hi ^ ((li>>1)&3))<<3);
  f32x4 acc[4][4] = {};

#define STAGE_MM(b,k0) { \
    GLOAD16(gA + (k0),                &As[b][(w*16)*32]);      \
    GLOAD16(gA + (size_t)64*K + (k0), &As[b][(64+w*16)*32]);   \
    GLOAD16(gB + (k0),                &Bs[b][(w*16)*32]);      \
    GLOAD16(gB + (size_t)64*K + (k0), &Bs[b][(64+w*16)*32]); }

  int nk = K >> 5;
  STAGE_MM(0, 0)
  STAGE_MM(1, 32)
  for(int t=0; t<nk; ++t){
    __builtin_amdgcn_sched_barrier(0);
    if(t+1 < nk){ asm volatile("s_waitcnt vmcnt(4)"); }
    else        { asm volatile("s_waitcnt vmcnt(0)"); }
    __builtin_amdgcn_s_barrier();
    __builtin_amdgcn_sched_barrier(0);
    const u16* pa = &As[t&1][0];
    const u16* pb = &Bs[t&1][0];
    bf16x8 bfr[4];
    #pragma unroll
    for(int q=0;q<4;q++) bfr[q] = *(const bf16x8*)&pb[rb + wc*2048 + q*512];
    #pragma unroll
    for(int i2=0;i2<4;i2++){
      bf16x8 a = *(const bf16x8*)&pa[rb + wr*2048 + i2*512];
      #pragma unroll
      for(int j2=0;j2<4;j2++)
        acc[i2][j2] = MFMA16(a, bfr[j2], acc[i2][j2]);
    }
    __builtin_amdgcn_sched_barrier(0);
    __builtin_amdgcn_s_barrier();
    __builtin_amdgcn_sched_barrier(0);
    if(t+2 < nk){ STAGE_MM(t&1, (size_t)(t+2)*32) }
  }
#undef STAGE_MM

  #pragma unroll
  for(int i2=0;i2<4;i2++){
    #pragma unroll
    for(int j2=0;j2<4;j2++){
      int col = col0 + wc*64 + j2*16 + li;
      float bcol = (EPI==2 || EPI==3) ? bias[col] : 0.f;
      if constexpr (EPI==4){
        int nb = row0 + wr*64 + i2*16 + hi*4;
        int b = nb >> 11, n = nb & (SEQ-1);
        int h = col >> 6, dh = col & 63;
        ushort4 pk;
        pk.x = f2bf(acc[i2][j2][0]); pk.y = f2bf(acc[i2][j2][1]);
        pk.z = f2bf(acc[i2][j2][2]); pk.w = f2bf(acc[i2][j2][3]);
        *(ushort4*)((u16*)Cv + (((size_t)(b*HNUM+h)*DHEAD + dh)*SEQ + n)) = pk;
      } else {
        #pragma unroll
        for(int r=0;r<4;r++){
          int row = row0 + wr*64 + i2*16 + hi*4 + r;
          float v = acc[i2][j2][r];
          if constexpr (EPI==1){
            int b = row >> 11, n = row & (SEQ-1);
            int h = col >> 6, dh = col & 63;
            ((u16*)Cv)[((size_t)(b*HNUM+h)*SEQ + n)*DHEAD + dh] = f2bf(v);
          } else if constexpr (EPI==2){
            ((float*)Cv)[(size_t)row*Nc + col] += v + bcol;
          } else {
            ((u16*)Cv)[(size_t)row*Nc + col] = f2bf(fast_gelu(v + bcol));
          }
        }
      }
    }
  }
}

// ---------------- K max pass: 128 rows/block, streaming acc ----------------
__global__ __launch_bounds__(256)
void k_kmax(const u16* __restrict__ xg, const u16* __restrict__ pjb,
            float* __restrict__ kmax){
  __shared__ u16 pj[256*64];
  __shared__ u16 xs[128*64];
  __shared__ float wred[4];
  int tid = threadIdx.x, w = tid >> 6, lane = tid & 63;
  int hi = lane >> 4, li = lane & 15;
  int r0 = blockIdx.x * 128;
  int bh = r0 >> 11;
  #pragma unroll
  for(int i=0;i<8;i++){
    int idx = i*256 + tid;
    int m = idx >> 3, c = idx & 7;
    bf16x8 v = *(const bf16x8*)(pjb + m*64 + c*8);
    *(bf16x8*)&pj[m*64 + ((c ^ (m&7))<<3)] = v;
  }
  #pragma unroll
  for(int i=0;i<4;i++){
    int idx = i*256 + tid;
    int m = idx >> 3, c = idx & 7;
    bf16x8 v = *(const bf16x8*)(xg + (size_t)(r0+m)*64 + c*8);
    *(bf16x8*)&xs[m*64 + ((c ^ (m&7))<<3)] = v;
  }
  __syncthreads();
  bf16x8 bfr[2][4];
  #pragma unroll
  for(int ks=0;ks<2;ks++){
    int kc = ks*4 + hi;
    #pragma unroll
    for(int t=0;t<4;t++){
      int bc = w*64 + t*16 + li;
      bfr[ks][t] = *(const bf16x8*)&pj[bc*64 + ((kc ^ (bc&7))<<3)];
    }
  }
  float mx = -1e30f;
  #pragma unroll
  for(int i8=0;i8<8;i8++){
    f32x4 acc[4] = {};
    #pragma unroll
    for(int ks=0;ks<2;ks++){
      int kc = ks*4 + hi;
      int ar = i8*16 + li;
      bf16x8 af = *(const bf16x8*)&xs[ar*64 + ((kc ^ (ar&7))<<3)];
      #pragma unroll
      for(int j2=0;j2<4;j2++)
        acc[j2] = MFMA16(af, bfr[ks][j2], acc[j2]);
    }
    #pragma unroll
    for(int j2=0;j2<4;j2++)
      #pragma unroll
      for(int r=0;r<4;r++) mx = fmaxf(mx, acc[j2][r]);
  }
  #pragma unroll
  for(int o=32;o;o>>=1) mx = fmaxf(mx, __shfl_xor(mx,o));
  if(lane==0) wred[w] = mx;
  __syncthreads();
  if(tid==0){
    float m2 = fmaxf(fmaxf(wred[0],wred[1]), fmaxf(wred[2],wred[3]));
    atomicMaxF(&kmax[bh], m2*DNRM);
  }
}

// ---------------- K feature pass: 128 rows/block, kp_t + ksum, register diag ----------------
__global__ __launch_bounds__(256)
void k_kfeat(const u16* __restrict__ xg, const u16* __restrict__ pjb,
             u16* __restrict__ outp, const float* __restrict__ kmax,
             float* __restrict__ ksum){
  __shared__ u16 pj[256*64];
  __shared__ u16 xs[128*64];
  __shared__ float dgs[128];
  int tid = threadIdx.x, w = tid >> 6, lane = tid & 63;
  int hi = lane >> 4, li = lane & 15;
  int r0 = blockIdx.x * 128;
  int bh = r0 >> 11;
  int nbase = r0 & (SEQ-1);
  #pragma unroll
  for(int i=0;i<8;i++){
    int idx = i*256 + tid;
    int m = idx >> 3, c = idx & 7;
    bf16x8 v = *(const bf16x8*)(pjb + m*64 + c*8);
    *(bf16x8*)&pj[m*64 + ((c ^ (m&7))<<3)] = v;
  }
  #pragma unroll
  for(int i=0;i<4;i++){
    int idx = i*256 + tid;
    int m = idx >> 3, c = idx & 7;
    bf16x8 v = *(const bf16x8*)(xg + (size_t)(r0+m)*64 + c*8);
    *(bf16x8*)&xs[m*64 + ((c ^ (m&7))<<3)] = v;
    float s = 0.f;
    #pragma unroll
    for(int j=0;j<8;j++){ float t = bf2f((u16)v[j]); s += t*t; }
    s += __shfl_xor(s,1); s += __shfl_xor(s,2); s += __shfl_xor(s,4);
    if((tid&7)==0) dgs[m] = 0.5f*DNRM*DNRM*s;
  }
  __syncthreads();
  bf16x8 bfr[2][4];
  #pragma unroll
  for(int ks=0;ks<2;ks++){
    int kc = ks*4 + hi;
    #pragma unroll
    for(int t=0;t<4;t++){
      int bc = w*64 + t*16 + li;
      bfr[ks][t] = *(const bf16x8*)&pj[bc*64 + ((kc ^ (bc&7))<<3)];
    }
  }
  float km = kmax[bh];
  float csum[4] = {0.f,0.f,0.f,0.f};
  #pragma unroll
  for(int i8=0;i8<8;i8++){
    f32x4 acc[4] = {};
    #pragma unroll
    for(int ks=0;ks<2;ks++){
      int kc = ks*4 + hi;
      int ar = i8*16 + li;
      bf16x8 af = *(const bf16x8*)&xs[ar*64 + ((kc ^ (ar&7))<<3)];
      #pragma unroll
      for(int j2=0;j2<4;j2++)
        acc[j2] = MFMA16(af, bfr[ks][j2], acc[j2]);
    }
    #pragma unroll
    for(int j2=0;j2<4;j2++){
      int col = w*64 + j2*16 + li;
      ushort4 pk;
      float cpart = 0.f;
      #pragma unroll
      for(int r=0;r<4;r++){
        int rl = i8*16 + hi*4 + r;
        float u = acc[j2][r]*DNRM;
        u16 eb = f2bf(SMF*(expf(u - dgs[rl] - km) + EPSF));
        ((u16*)&pk)[r] = eb;
        cpart += bf2f(eb);
      }
      *(ushort4*)(outp + ((size_t)(bh*MFEAT + col)*SEQ + nbase + i8*16 + hi*4)) = pk;
      csum[j2] += cpart;
    }
  }
  #pragma unroll
  for(int j2=0;j2<4;j2++){
    float v = csum[j2];
    v += __shfl_xor(v,16); v += __shfl_xor(v,32);
    if(hi==0) atomicAdd(&ksum[bh*MFEAT + w*64 + j2*16 + li], v);
  }
}

// ---------------- fused Q-feature + PV: q -> qp (LDS) -> o = (qp@ctx^T)/den ----------------
__global__ __launch_bounds__(256)
void k_feato(const u16* __restrict__ xg, const u16* __restrict__ pjb,
             const u16* __restrict__ ctxt, const float* __restrict__ ksum,
             u16* __restrict__ o){
  __shared__ u16 smA[16384];   // pj (swz) -> ctx (swz) after u-MFMA
  __shared__ u16 smX[2048];    // q rows (swz)
  __shared__ u16 smQ[8192];    // qp (swz)
  __shared__ float dgs[32];
  __shared__ float wred[4][32];
  __shared__ float wden[4][32];
  __shared__ float ksl[256];
  __shared__ float denl[32];
  int tid = threadIdx.x, w = tid >> 6, lane = tid & 63;
  int hi = lane >> 4, li = lane & 15;
  int r0 = blockIdx.x * 32;
  int bh = r0 >> 11;
  int b = bh >> 3, h = bh & 7;
  #pragma unroll
  for(int i=0;i<8;i++){
    int idx = i*256 + tid;
    int m = idx >> 3, c = idx & 7;
    bf16x8 v = *(const bf16x8*)(pjb + m*64 + c*8);
    *(bf16x8*)&smA[m*64 + ((c ^ (m&7))<<3)] = v;
  }
  {
    int m = tid >> 3, c = tid & 7;
    bf16x8 v = *(const bf16x8*)(xg + (size_t)(r0+m)*64 + c*8);
    *(bf16x8*)&smX[m*64 + ((c ^ (m&7))<<3)] = v;
    float s = 0.f;
    #pragma unroll
    for(int j=0;j<8;j++){ float t = bf2f((u16)v[j]); s += t*t; }
    s += __shfl_xor(s,1); s += __shfl_xor(s,2); s += __shfl_xor(s,4);
    if((tid&7)==0) dgs[m] = 0.5f*DNRM*DNRM*s;
  }
  ksl[tid] = ksum[bh*MFEAT + tid];
  __syncthreads();
  f32x4 acc[2][4] = {};
  #pragma unroll
  for(int ks=0;ks<2;ks++){
    bf16x8 af[2], bfr[4];
    int kc = ks*4 + hi;
    #pragma unroll
    for(int t=0;t<2;t++){
      int ar = t*16 + li;
      af[t] = *(const bf16x8*)&smX[ar*64 + ((kc ^ (ar&7))<<3)];
    }
    #pragma unroll
    for(int t=0;t<4;t++){
      int bc = w*64 + t*16 + li;
      bfr[t] = *(const bf16x8*)&smA[bc*64 + ((kc ^ (bc&7))<<3)];
    }
    #pragma unroll
    for(int i2=0;i2<2;i2++)
      #pragma unroll
      for(int j2=0;j2<4;j2++)
        acc[i2][j2] = MFMA16(af[i2], bfr[j2], acc[i2][j2]);
  }
  __syncthreads();   // all pj reads done; smA reusable
  // async ctx_t[bh] (64x256 bf16) -> smA, swizzled source, linear dest
  {
    int Lc0 = w*64 + lane;
    int row0 = Lc0 >> 5, c0 = Lc0 & 31;
    const u16* gCl = ctxt + (size_t)bh*DHEAD*MFEAT + ((size_t)row0*32 + (c0 ^ (row0&7)))*8;
    #pragma unroll
    for(int i=0;i<8;i++)
      GLOAD16(gCl + i*2048, &smA[i*2048 + w*512]);
  }
  // per-row max over m
  #pragma unroll
  for(int i2=0;i2<2;i2++){
    #pragma unroll
    for(int r=0;r<4;r++){
      float v = fmaxf(fmaxf(acc[i2][0][r],acc[i2][1][r]), fmaxf(acc[i2][2][r],acc[i2][3][r]));
      v = fmaxf(v, __shfl_xor(v,1)); v = fmaxf(v, __shfl_xor(v,2));
      v = fmaxf(v, __shfl_xor(v,4)); v = fmaxf(v, __shfl_xor(v,8));
      if(li==0) wred[w][i2*16 + hi*4 + r] = v;
    }
  }
  __builtin_amdgcn_sched_barrier(0);
  asm volatile("s_waitcnt lgkmcnt(0)");
  __builtin_amdgcn_s_barrier();
  __builtin_amdgcn_sched_barrier(0);
  // qp = exp(u - diag - rowmax)*s + eps -> smQ ; den partial = qp . ksum
  #pragma unroll
  for(int i2=0;i2<2;i2++){
    #pragma unroll
    for(int r=0;r<4;r++){
      int rl = i2*16 + hi*4 + r;
      float rm = fmaxf(fmaxf(wred[0][rl],wred[1][rl]), fmaxf(wred[2][rl],wred[3][rl]));
      float dsum = 0.f;
      #pragma unroll
      for(int j2=0;j2<4;j2++){
        int col = w*64 + j2*16 + li;
        float u = acc[i2][j2][r]*DNRM;
        u16 eb = f2bf(SMF*(expf(u - dgs[rl] - rm) + EPSF));
        smQ[rl*256 + (((col>>3) ^ (rl&7))<<3) + (col&7)] = eb;
        dsum += bf2f(eb)*ksl[col];
      }
      dsum += __shfl_xor(dsum,1); dsum += __shfl_xor(dsum,2);
      dsum += __shfl_xor(dsum,4); dsum += __shfl_xor(dsum,8);
      if(li==0) wden[w][rl] = dsum;
    }
  }
  __builtin_amdgcn_sched_barrier(0);
  asm volatile("s_waitcnt vmcnt(0) lgkmcnt(0)");
  __builtin_amdgcn_s_barrier();
  __builtin_amdgcn_sched_barrier(0);
  if(tid < 32) denl[tid] = wden[0][tid]+wden[1][tid]+wden[2][tid]+wden[3][tid];
  // PV: wave w owns dh-tile w (16 dh) x 32 rows; K=256 over m
  f32x4 acc2[2] = {};
  #pragma unroll
  for(int s=0;s<8;s++){
    int kc = s*4 + hi;
    int bc = w*16 + li;
    bf16x8 bf = *(const bf16x8*)&smA[bc*256 + ((kc ^ (bc&7))<<3)];
    #pragma unroll
    for(int t=0;t<2;t++){
      int ar = t*16 + li;
      bf16x8 aa = *(const bf16x8*)&smQ[ar*256 + ((kc ^ (ar&7))<<3)];
      acc2[t] = MFMA16(aa, bf, acc2[t]);
    }
  }
  __syncthreads();   // denl visible
  int nbase = r0 & (SEQ-1);
  #pragma unroll
  for(int t=0;t<2;t++){
    #pragma unroll
    for(int r=0;r<4;r++){
      int nl = t*16 + hi*4 + r;
      float di = 1.0f/denl[nl];
      o[((size_t)b*SEQ + nbase + nl)*DMODEL + h*DHEAD + w*16 + li] = f2bf(acc2[t][r]*di);
    }
  }
}

// ---------------- ctx_t[bh][dh][m] = sum_n v_t[dh][n]*kp_t[m][n], depth-2 pipeline ----------------
__global__ __launch_bounds__(256)
void k_ctx(const u16* __restrict__ vt, const u16* __restrict__ kpt,
           u16* __restrict__ ctxt){
  __shared__ u16 As[2][64*64];
  __shared__ u16 Bs[2][64*64];
  int tid = threadIdx.x, w = tid >> 6, lane = tid & 63;
  int wr = w >> 1, wc = w & 1;
  int hi = lane >> 4, li = lane & 15;
  int bh = blockIdx.y, mb = blockIdx.x*64;
  int lr = lane >> 3;
  int lc = (lane & 7) ^ lr;
  const u16* gA = vt  + (size_t)bh*DHEAD*SEQ + (size_t)(w*8 + lr)*SEQ + lc*8;
  const u16* gB = kpt + ((size_t)bh*MFEAT + mb + w*8 + lr)*SEQ + lc*8;
  f32x4 acc[2][2] = {};
#define STAGE_CTX(b,k0) { \
    GLOAD16(gA + (k0),                 &As[b][(w*8)*64]);      \
    GLOAD16(gA + (size_t)32*SEQ + (k0),&As[b][(32+w*8)*64]);   \
    GLOAD16(gB + (k0),                 &Bs[b][(w*8)*64]);      \
    GLOAD16(gB + (size_t)32*SEQ + (k0),&Bs[b][(32+w*8)*64]); }
  int nk = SEQ/64;
  STAGE_CTX(0, 0)
  STAGE_CTX(1, 64)
  for(int t=0; t<nk; ++t){
    __builtin_amdgcn_sched_barrier(0);
    if(t+1 < nk){ asm volatile("s_waitcnt vmcnt(4)"); }
    else        { asm volatile("s_waitcnt vmcnt(0)"); }
    __builtin_amdgcn_s_barrier();
    __builtin_amdgcn_sched_barrier(0);
    const u16* pa = &As[t&1][0];
    const u16* pb = &Bs[t&1][0];
    #pragma unroll
    for(int ks=0;ks<2;ks++){
      bf16x8 af[2], bfr[2];
      int kc = ks*4 + hi;
      #pragma unroll
      for(int q=0;q<2;q++){
        int ar = wr*32 + q*16 + li;
        af[q] = *(const bf16x8*)&pa[ar*64 + ((kc ^ (ar&7))<<3)];
        int bc = wc*32 + q*16 + li;
        bfr[q] = *(const bf16x8*)&pb[bc*64 + ((kc ^ (bc&7))<<3)];
      }
      #pragma unroll
      for(int i2=0;i2<2;i2++)
        #pragma unroll
        for(int j2=0;j2<2;j2++)
          acc[i2][j2] = MFMA16(af[i2], bfr[j2], acc[i2][j2]);
    }
    __builtin_amdgcn_sched_barrier(0);
    __builtin_amdgcn_s_barrier();
    __builtin_amdgcn_sched_barrier(0);
    if(t+2 < nk){ STAGE_CTX(t&1, (size_t)(t+2)*64) }
  }
#undef STAGE_CTX
  #pragma unroll
  for(int i2=0;i2<2;i2++)
    #pragma unroll
    for(int j2=0;j2<2;j2++){
      int m = mb + wc*32 + j2*16 + li;
      #pragma unroll
      for(int r=0;r<4;r++){
        int dh = wr*32 + i2*16 + hi*4 + r;
        ctxt[((size_t)bh*DHEAD + dh)*MFEAT + m] = f2bf(acc[i2][j2][r]);
      }
    }
}

extern "C" void kernel_launch(void* const* d_in, const int* in_sizes, int n_in,
                              void* d_out, int out_size, void* d_ws, size_t ws_size,
                              hipStream_t stream){
  (void)in_sizes; (void)n_in; (void)out_size; (void)ws_size;
  const float* x    = (const float*)d_in[0];
  const float* proj = (const float*)d_in[1];
  const float* ln1g = (const float*)d_in[2];
  const float* ln1b = (const float*)d_in[3];
  const float* wq   = (const float*)d_in[4];
  const float* wk   = (const float*)d_in[5];
  const float* wv   = (const float*)d_in[6];
  const float* wo   = (const float*)d_in[7];
  const float* bo   = (const float*)d_in[8];
  const float* ln2g = (const float*)d_in[9];
  const float* ln2b = (const float*)d_in[10];
  const float* w1   = (const float*)d_in[11];
  const float* b1   = (const float*)d_in[12];
  const float* w2   = (const float*)d_in[13];
  const float* b2   = (const float*)d_in[14];
  float* xo = (float*)d_out;

  // workspace ~110 MB
  char* ws = (char*)d_ws;
  u16* bufH  = (u16*)ws;  ws += (size_t)TOK*DMODEL*2;
  u16* bufA  = (u16*)ws;  ws += (size_t)TOK*DMODEL*2;
  u16* featb = (u16*)ws;  ws += (size_t)BHN*SEQ*MFEAT*2;
  u16* ctxt  = (u16*)ws;  ws += (size_t)BHN*DHEAD*MFEAT*2;
  u16* wT    = (u16*)ws;  ws += (size_t)3*1048576*2;
  u16* pjb   = (u16*)ws;  ws += (size_t)LNUM*MFEAT*DHEAD*2;
  float* ksum= (float*)ws; ws += (size_t)BHN*MFEAT*4;
  float* kmax= (float*)ws; ws += 256;

  u16* wqT = wT;
  u16* wkT = wT +  262144;
  u16* wvT = wT +  524288;
  u16* woT = wT +  786432;
  u16* w1T = wT + 1048576;
  u16* w2T = wT + 2097152;

  k_addpe<<<(TOK*DMODEL)/256, 256, 0, stream>>>(x, xo);
  k_pcvt<<<(LNUM*MFEAT*DHEAD)/256, 256, 0, stream>>>(proj, pjb);

  for(int l=0; l<LNUM; l++){
    const u16* pj_l = pjb + (size_t)l*MFEAT*DHEAD;
    k_wcvt_all<<<832, 256, 0, stream>>>(wq + (size_t)l*262144, wk + (size_t)l*262144,
                                        wv + (size_t)l*262144, wo + (size_t)l*262144,
                                        w1 + (size_t)l*1048576, w2 + (size_t)l*1048576,
                                        wqT, wkT, wvT, woT, w1T, w2T, ksum, kmax);
    k_ln<<<TOK, 256, 0, stream>>>(xo, ln1g + l*DMODEL, ln1b + l*DMODEL, bufH);
    // K path: k -> kmax -> kp_t (+ksum atomics)
    k_mm<1><<<dim3(4,128), 256, 0, stream>>>(bufH, wkT, nullptr, bufA, DMODEL, DMODEL);
    k_kmax<<<(BHN*SEQ)/128, 256, 0, stream>>>(bufA, pj_l, kmax);
    k_kfeat<<<(BHN*SEQ)/128, 256, 0, stream>>>(bufA, pj_l, featb, kmax, ksum);
    // V path: v_t -> ctx_t
    k_mm<4><<<dim3(4,128), 256, 0, stream>>>(bufH, wvT, nullptr, bufA, DMODEL, DMODEL);
    k_ctx<<<dim3(4,BHN), 256, 0, stream>>>(bufA, featb, ctxt);
    // Q path fused: q -> qp (LDS) -> o  -> wo-GEMM (residual add)
    k_mm<1><<<dim3(4,128), 256, 0, stream>>>(bufH, wqT, nullptr, bufA, DMODEL, DMODEL);
    k_feato<<<(BHN*SEQ)/32, 256, 0, stream>>>(bufA, pj_l, ctxt, ksum, bufH);
    k_mm<2><<<dim3(4,128), 256, 0, stream>>>(bufH, woT, bo + l*DMODEL, xo, DMODEL, DMODEL);
    // FFN
    k_ln<<<TOK, 256, 0, stream>>>(xo, ln2g + l*DMODEL, ln2b + l*DMODEL, bufA);
    k_mm<3><<<dim3(16,128), 256, 0, stream>>>(bufA, w1T, b1 + l*DFF, featb, DFF, DMODEL);
    k_mm<2><<<dim3(4,128), 256, 0, stream>>>(featb, w2T, b2 + l*DMODEL, xo, DMODEL, DFF);
  }
}

// Round 12
// 2180.513 us; speedup vs baseline: 15.8708x; 1.0726x over previous
//
#include <hip/hip_runtime.h>
#include <math.h>

#define LNUM 6
#define HNUM 8
#define DMODEL 512
#define DHEAD 64
#define MFEAT 256
#define BATCH 8
#define SEQ 2048
#define TOK (BATCH*SEQ)
#define BHN (BATCH*HNUM)
#define DFF 2048
#define EPSF 1e-4f
#define LN_EPS 1e-5f
#define DNRM 0.35355339059327373f
#define SMF 0.0625f

typedef unsigned short u16;
typedef __attribute__((ext_vector_type(8))) short bf16x8;
typedef __attribute__((ext_vector_type(4))) float f32x4;
#define MFMA16(a,b,c) __builtin_amdgcn_mfma_f32_16x16x32_bf16(a,b,c,0,0,0)

// async global->LDS, 16B per lane; LDS dest = wave-uniform base + lane*16
#define GLOAD16(g,l) __builtin_amdgcn_global_load_lds( \
    (const __attribute__((address_space(1))) void*)(g), \
    (__attribute__((address_space(3))) void*)(l), 16, 0, 0)

__device__ __forceinline__ u16 f2bf(float f){
  unsigned int u = __float_as_uint(f);
  u = (u + 0x7fffu + ((u >> 16) & 1u)) >> 16;
  return (u16)u;
}
__device__ __forceinline__ float bf2f(u16 s){
  return __uint_as_float(((unsigned int)s) << 16);
}
__device__ __forceinline__ void atomicMaxF(float* addr, float val){
  if(val >= 0.f) atomicMax((int*)addr, __float_as_int(val));
  else           atomicMin((unsigned int*)addr, __float_as_uint(val));
}
// gelu tanh-approx: z * sigmoid(2*(c1 z + c2 z^3))
__device__ __forceinline__ float fast_gelu(float z){
  float g2 = z*(1.5957691216f + 0.07135481628f*z*z);
  return z / (1.0f + __expf(-g2));
}

// ---------------- x = x + sinusoidal PE ----------------
__global__ void k_addpe(const float* __restrict__ x, float* __restrict__ xo){
  int idx = blockIdx.x*256 + threadIdx.x;
  int d = idx & (DMODEL-1);
  int n = (idx >> 9) & (SEQ-1);
  int j = d >> 1;
  float freq = expf((float)(2*j) * (-9.210340371976184f / (float)DMODEL));
  float ang = (float)n * freq;
  float pe = (d & 1) ? cosf(ang) : sinf(ang);
  xo[idx] = x[idx] + pe;
}

// ---------------- LayerNorm (512) -> bf16 ----------------
__global__ void k_ln(const float* __restrict__ x, const float* __restrict__ g,
                     const float* __restrict__ bv, u16* __restrict__ out){
  __shared__ float sred[8];
  int t = blockIdx.x, tid = threadIdx.x;
  const float2 v = ((const float2*)(x + (size_t)t*DMODEL))[tid];
  float s = v.x + v.y;
  #pragma unroll
  for(int o=32;o;o>>=1) s += __shfl_down(s,o);
  if((tid&63)==0) sred[tid>>6] = s;
  __syncthreads();
  if(tid==0) sred[4] = (sred[0]+sred[1]+sred[2]+sred[3]) * (1.0f/DMODEL);
  __syncthreads();
  float mu = sred[4];
  float dx = v.x - mu, dy = v.y - mu;
  float s2 = dx*dx + dy*dy;
  #pragma unroll
  for(int o=32;o;o>>=1) s2 += __shfl_down(s2,o);
  if((tid&63)==0) sred[tid>>6] = s2;
  __syncthreads();
  if(tid==0) sred[5] = rsqrtf((sred[0]+sred[1]+sred[2]+sred[3])*(1.0f/DMODEL) + LN_EPS);
  __syncthreads();
  float rs = sred[5];
  const float2 gg = ((const float2*)g)[tid];
  const float2 bb = ((const float2*)bv)[tid];
  ushort2 o2; o2.x = f2bf(dx*rs*gg.x + bb.x); o2.y = f2bf(dy*rs*gg.y + bb.y);
  ((ushort2*)(out + (size_t)t*DMODEL))[tid] = o2;
}

__global__ void k_pcvt(const float* __restrict__ p, u16* __restrict__ pb){
  int i = blockIdx.x*256 + threadIdx.x;
  pb[i] = f2bf(p[i]);
}

// ---------------- all weight transposes + ksum/kmax init in ONE dispatch ----------------
__global__ void k_wcvt_all(const float* __restrict__ wq, const float* __restrict__ wk,
                           const float* __restrict__ wv, const float* __restrict__ wo,
                           const float* __restrict__ w1, const float* __restrict__ w2,
                           u16* __restrict__ wqT, u16* __restrict__ wkT,
                           u16* __restrict__ wvT, u16* __restrict__ woT,
                           u16* __restrict__ w1T, u16* __restrict__ w2T,
                           float* __restrict__ ksum, float* __restrict__ kmax){
  int bid = blockIdx.x;
  if(bid >= 768){
    int i = (bid-768)*256 + threadIdx.x;
    ksum[i] = 0.f;
    if(i < BHN) kmax[i] = -INFINITY;
    return;
  }
  const float* src; u16* dst; int K, N, bx, by;
  if(bid < 256){
    int which = bid >> 6, sub = bid & 63;
    src = which==0 ? wq : which==1 ? wk : which==2 ? wv : wo;
    dst = which==0 ? wqT : which==1 ? wkT : which==2 ? wvT : woT;
    K = 512; N = 512; bx = sub & 7; by = sub >> 3;
  } else if(bid < 512){
    int sub = bid - 256; src = w1; dst = w1T; K = 512; N = 2048; bx = sub & 31; by = sub >> 5;
  } else {
    int sub = bid - 512; src = w2; dst = w2T; K = 2048; N = 512; bx = sub & 7; by = sub >> 3;
  }
  __shared__ float sm[64][65];
  int kt = by*64, nt = bx*64;
  int t = threadIdx.x, c = t & 63, r4 = t >> 6;
  #pragma unroll
  for(int i=0;i<16;i++){
    int kl = i*4 + r4;
    sm[kl][c] = src[(size_t)(kt+kl)*N + nt + c];
  }
  __syncthreads();
  #pragma unroll
  for(int i=0;i<16;i++){
    int nl = i*4 + r4;
    dst[(size_t)(nt+nl)*K + kt + c] = f2bf(sm[c][nl]);
  }
}

// ---------------- MFMA GEMM, BK=32, depth-2, counted vmcnt, 128-reg cap ----------------
template<int EPI>
__global__ __launch_bounds__(256,4)
void k_mm(const u16* __restrict__ A, const u16* __restrict__ Bt,
          const float* __restrict__ bias, void* __restrict__ Cv,
          int Nc, int K){
  __shared__ u16 As[2][128*32];
  __shared__ u16 Bs[2][128*32];
  int tid = threadIdx.x;
  int w = tid >> 6, lane = tid & 63;
  int wr = w >> 1, wc = w & 1;
  int hi = lane >> 4, li = lane & 15;
  int row0 = blockIdx.y*128, col0 = blockIdx.x*128;
  int lr = lane >> 2;
  int cs = (lane & 3) ^ ((lane >> 3) & 3);
  const u16* gA = A  + (size_t)(row0 + w*16 + lr)*K + cs*8;
  const u16* gB = Bt + (size_t)(col0 + w*16 + lr)*K + cs*8;
  int rb = li*32 + ((hi ^ ((li>>1)&3))<<3);
  f32x4 acc[4][4] = {};

#define STAGE_MM(b,k0) { \
    GLOAD16(gA + (k0),                &As[b][(w*16)*32]);      \
    GLOAD16(gA + (size_t)64*K + (k0), &As[b][(64+w*16)*32]);   \
    GLOAD16(gB + (k0),                &Bs[b][(w*16)*32]);      \
    GLOAD16(gB + (size_t)64*K + (k0), &Bs[b][(64+w*16)*32]); }

  int nk = K >> 5;
  STAGE_MM(0, 0)
  STAGE_MM(1, 32)
  for(int t=0; t<nk; ++t){
    __builtin_amdgcn_sched_barrier(0);
    if(t+1 < nk){ asm volatile("s_waitcnt vmcnt(4)"); }
    else        { asm volatile("s_waitcnt vmcnt(0)"); }
    __builtin_amdgcn_s_barrier();
    __builtin_amdgcn_sched_barrier(0);
    const u16* pa = &As[t&1][0];
    const u16* pb = &Bs[t&1][0];
    bf16x8 bfr[4];
    #pragma unroll
    for(int q=0;q<4;q++) bfr[q] = *(const bf16x8*)&pb[rb + wc*2048 + q*512];
    #pragma unroll
    for(int i2=0;i2<4;i2++){
      bf16x8 a = *(const bf16x8*)&pa[rb + wr*2048 + i2*512];
      #pragma unroll
      for(int j2=0;j2<4;j2++)
        acc[i2][j2] = MFMA16(a, bfr[j2], acc[i2][j2]);
    }
    __builtin_amdgcn_sched_barrier(0);
    __builtin_amdgcn_s_barrier();
    __builtin_amdgcn_sched_barrier(0);
    if(t+2 < nk){ STAGE_MM(t&1, (size_t)(t+2)*32) }
  }
#undef STAGE_MM

  #pragma unroll
  for(int i2=0;i2<4;i2++){
    #pragma unroll
    for(int j2=0;j2<4;j2++){
      int col = col0 + wc*64 + j2*16 + li;
      float bcol = (EPI==2 || EPI==3) ? bias[col] : 0.f;
      if constexpr (EPI==4){
        int nb = row0 + wr*64 + i2*16 + hi*4;
        int b = nb >> 11, n = nb & (SEQ-1);
        int h = col >> 6, dh = col & 63;
        ushort4 pk;
        pk.x = f2bf(acc[i2][j2][0]); pk.y = f2bf(acc[i2][j2][1]);
        pk.z = f2bf(acc[i2][j2][2]); pk.w = f2bf(acc[i2][j2][3]);
        *(ushort4*)((u16*)Cv + (((size_t)(b*HNUM+h)*DHEAD + dh)*SEQ + n)) = pk;
      } else {
        #pragma unroll
        for(int r=0;r<4;r++){
          int row = row0 + wr*64 + i2*16 + hi*4 + r;
          float v = acc[i2][j2][r];
          if constexpr (EPI==1){
            int b = row >> 11, n = row & (SEQ-1);
            int h = col >> 6, dh = col & 63;
            ((u16*)Cv)[((size_t)(b*HNUM+h)*SEQ + n)*DHEAD + dh] = f2bf(v);
          } else if constexpr (EPI==2){
            ((float*)Cv)[(size_t)row*Nc + col] += v + bcol;
          } else {
            ((u16*)Cv)[(size_t)row*Nc + col] = f2bf(fast_gelu(v + bcol));
          }
        }
      }
    }
  }
}

// ---------------- K max pass: 128 rows/block, streaming acc ----------------
__global__ __launch_bounds__(256)
void k_kmax(const u16* __restrict__ xg, const u16* __restrict__ pjb,
            float* __restrict__ kmax){
  __shared__ u16 pj[256*64];
  __shared__ u16 xs[128*64];
  __shared__ float wred[4];
  int tid = threadIdx.x, w = tid >> 6, lane = tid & 63;
  int hi = lane >> 4, li = lane & 15;
  int r0 = blockIdx.x * 128;
  int bh = r0 >> 11;
  #pragma unroll
  for(int i=0;i<8;i++){
    int idx = i*256 + tid;
    int m = idx >> 3, c = idx & 7;
    bf16x8 v = *(const bf16x8*)(pjb + m*64 + c*8);
    *(bf16x8*)&pj[m*64 + ((c ^ (m&7))<<3)] = v;
  }
  #pragma unroll
  for(int i=0;i<4;i++){
    int idx = i*256 + tid;
    int m = idx >> 3, c = idx & 7;
    bf16x8 v = *(const bf16x8*)(xg + (size_t)(r0+m)*64 + c*8);
    *(bf16x8*)&xs[m*64 + ((c ^ (m&7))<<3)] = v;
  }
  __syncthreads();
  bf16x8 bfr[2][4];
  #pragma unroll
  for(int ks=0;ks<2;ks++){
    int kc = ks*4 + hi;
    #pragma unroll
    for(int t=0;t<4;t++){
      int bc = w*64 + t*16 + li;
      bfr[ks][t] = *(const bf16x8*)&pj[bc*64 + ((kc ^ (bc&7))<<3)];
    }
  }
  float mx = -1e30f;
  #pragma unroll
  for(int i8=0;i8<8;i8++){
    f32x4 acc[4] = {};
    #pragma unroll
    for(int ks=0;ks<2;ks++){
      int kc = ks*4 + hi;
      int ar = i8*16 + li;
      bf16x8 af = *(const bf16x8*)&xs[ar*64 + ((kc ^ (ar&7))<<3)];
      #pragma unroll
      for(int j2=0;j2<4;j2++)
        acc[j2] = MFMA16(af, bfr[ks][j2], acc[j2]);
    }
    #pragma unroll
    for(int j2=0;j2<4;j2++)
      #pragma unroll
      for(int r=0;r<4;r++) mx = fmaxf(mx, acc[j2][r]);
  }
  #pragma unroll
  for(int o=32;o;o>>=1) mx = fmaxf(mx, __shfl_xor(mx,o));
  if(lane==0) wred[w] = mx;
  __syncthreads();
  if(tid==0){
    float m2 = fmaxf(fmaxf(wred[0],wred[1]), fmaxf(wred[2],wred[3]));
    atomicMaxF(&kmax[bh], m2*DNRM);
  }
}

// ---------------- K feature pass: 128 rows/block, kp_t + ksum, register diag ----------------
__global__ __launch_bounds__(256)
void k_kfeat(const u16* __restrict__ xg, const u16* __restrict__ pjb,
             u16* __restrict__ outp, const float* __restrict__ kmax,
             float* __restrict__ ksum){
  __shared__ u16 pj[256*64];
  __shared__ u16 xs[128*64];
  __shared__ float dgs[128];
  int tid = threadIdx.x, w = tid >> 6, lane = tid & 63;
  int hi = lane >> 4, li = lane & 15;
  int r0 = blockIdx.x * 128;
  int bh = r0 >> 11;
  int nbase = r0 & (SEQ-1);
  #pragma unroll
  for(int i=0;i<8;i++){
    int idx = i*256 + tid;
    int m = idx >> 3, c = idx & 7;
    bf16x8 v = *(const bf16x8*)(pjb + m*64 + c*8);
    *(bf16x8*)&pj[m*64 + ((c ^ (m&7))<<3)] = v;
  }
  #pragma unroll
  for(int i=0;i<4;i++){
    int idx = i*256 + tid;
    int m = idx >> 3, c = idx & 7;
    bf16x8 v = *(const bf16x8*)(xg + (size_t)(r0+m)*64 + c*8);
    *(bf16x8*)&xs[m*64 + ((c ^ (m&7))<<3)] = v;
    float s = 0.f;
    #pragma unroll
    for(int j=0;j<8;j++){ float t = bf2f((u16)v[j]); s += t*t; }
    s += __shfl_xor(s,1); s += __shfl_xor(s,2); s += __shfl_xor(s,4);
    if((tid&7)==0) dgs[m] = 0.5f*DNRM*DNRM*s;
  }
  __syncthreads();
  bf16x8 bfr[2][4];
  #pragma unroll
  for(int ks=0;ks<2;ks++){
    int kc = ks*4 + hi;
    #pragma unroll
    for(int t=0;t<4;t++){
      int bc = w*64 + t*16 + li;
      bfr[ks][t] = *(const bf16x8*)&pj[bc*64 + ((kc ^ (bc&7))<<3)];
    }
  }
  float km = kmax[bh];
  float csum[4] = {0.f,0.f,0.f,0.f};
  #pragma unroll
  for(int i8=0;i8<8;i8++){
    f32x4 acc[4] = {};
    #pragma unroll
    for(int ks=0;ks<2;ks++){
      int kc = ks*4 + hi;
      int ar = i8*16 + li;
      bf16x8 af = *(const bf16x8*)&xs[ar*64 + ((kc ^ (ar&7))<<3)];
      #pragma unroll
      for(int j2=0;j2<4;j2++)
        acc[j2] = MFMA16(af, bfr[ks][j2], acc[j2]);
    }
    #pragma unroll
    for(int j2=0;j2<4;j2++){
      int col = w*64 + j2*16 + li;
      ushort4 pk;
      float cpart = 0.f;
      #pragma unroll
      for(int r=0;r<4;r++){
        int rl = i8*16 + hi*4 + r;
        float u = acc[j2][r]*DNRM;
        u16 eb = f2bf(SMF*(__expf(u - dgs[rl] - km) + EPSF));
        ((u16*)&pk)[r] = eb;
        cpart += bf2f(eb);
      }
      *(ushort4*)(outp + ((size_t)(bh*MFEAT + col)*SEQ + nbase + i8*16 + hi*4)) = pk;
      csum[j2] += cpart;
    }
  }
  #pragma unroll
  for(int j2=0;j2<4;j2++){
    float v = csum[j2];
    v += __shfl_xor(v,16); v += __shfl_xor(v,32);
    if(hi==0) atomicAdd(&ksum[bh*MFEAT + w*64 + j2*16 + li], v);
  }
}

// ---------------- fused Q-feature + PV: q -> qp (LDS) -> o = (qp@ctx^T)/den ----------------
__global__ __launch_bounds__(256)
void k_feato(const u16* __restrict__ xg, const u16* __restrict__ pjb,
             const u16* __restrict__ ctxt, const float* __restrict__ ksum,
             u16* __restrict__ o){
  __shared__ u16 smA[16384];   // pj (swz) -> ctx (swz) after u-MFMA
  __shared__ u16 smX[2048];    // q rows (swz)
  __shared__ u16 smQ[8448];    // qp, stride 264 (padded; per-row bank rotation)
  __shared__ float dgs[32];
  __shared__ float wred[4][32];
  __shared__ float wden[4][32];
  __shared__ float ksl[256];
  __shared__ float denl[32];
  int tid = threadIdx.x, w = tid >> 6, lane = tid & 63;
  int hi = lane >> 4, li = lane & 15;
  int r0 = blockIdx.x * 32;
  int bh = r0 >> 11;
  int b = bh >> 3, h = bh & 7;
  #pragma unroll
  for(int i=0;i<8;i++){
    int idx = i*256 + tid;
    int m = idx >> 3, c = idx & 7;
    bf16x8 v = *(const bf16x8*)(pjb + m*64 + c*8);
    *(bf16x8*)&smA[m*64 + ((c ^ (m&7))<<3)] = v;
  }
  {
    int m = tid >> 3, c = tid & 7;
    bf16x8 v = *(const bf16x8*)(xg + (size_t)(r0+m)*64 + c*8);
    *(bf16x8*)&smX[m*64 + ((c ^ (m&7))<<3)] = v;
    float s = 0.f;
    #pragma unroll
    for(int j=0;j<8;j++){ float t = bf2f((u16)v[j]); s += t*t; }
    s += __shfl_xor(s,1); s += __shfl_xor(s,2); s += __shfl_xor(s,4);
    if((tid&7)==0) dgs[m] = 0.5f*DNRM*DNRM*s;
  }
  ksl[tid] = ksum[bh*MFEAT + tid];
  __syncthreads();
  f32x4 acc[2][4] = {};
  #pragma unroll
  for(int ks=0;ks<2;ks++){
    bf16x8 af[2], bfr[4];
    int kc = ks*4 + hi;
    #pragma unroll
    for(int t=0;t<2;t++){
      int ar = t*16 + li;
      af[t] = *(const bf16x8*)&smX[ar*64 + ((kc ^ (ar&7))<<3)];
    }
    #pragma unroll
    for(int t=0;t<4;t++){
      int bc = w*64 + t*16 + li;
      bfr[t] = *(const bf16x8*)&smA[bc*64 + ((kc ^ (bc&7))<<3)];
    }
    #pragma unroll
    for(int i2=0;i2<2;i2++)
      #pragma unroll
      for(int j2=0;j2<4;j2++)
        acc[i2][j2] = MFMA16(af[i2], bfr[j2], acc[i2][j2]);
  }
  __syncthreads();   // all pj reads done; smA reusable
  // async ctx_t[bh] (64x256 bf16) -> smA, swizzled source, linear dest
  {
    int Lc0 = w*64 + lane;
    int row0 = Lc0 >> 5, c0 = Lc0 & 31;
    const u16* gCl = ctxt + (size_t)bh*DHEAD*MFEAT + ((size_t)row0*32 + (c0 ^ (row0&7)))*8;
    #pragma unroll
    for(int i=0;i<8;i++)
      GLOAD16(gCl + i*2048, &smA[i*2048 + w*512]);
  }
  // per-row max over m
  #pragma unroll
  for(int i2=0;i2<2;i2++){
    #pragma unroll
    for(int r=0;r<4;r++){
      float v = fmaxf(fmaxf(acc[i2][0][r],acc[i2][1][r]), fmaxf(acc[i2][2][r],acc[i2][3][r]));
      v = fmaxf(v, __shfl_xor(v,1)); v = fmaxf(v, __shfl_xor(v,2));
      v = fmaxf(v, __shfl_xor(v,4)); v = fmaxf(v, __shfl_xor(v,8));
      if(li==0) wred[w][i2*16 + hi*4 + r] = v;
    }
  }
  __builtin_amdgcn_sched_barrier(0);
  asm volatile("s_waitcnt lgkmcnt(0)");
  __builtin_amdgcn_s_barrier();
  __builtin_amdgcn_sched_barrier(0);
  // qp = exp(u - diag - rowmax)*s + eps -> smQ ; den partial = qp . ksum
  #pragma unroll
  for(int i2=0;i2<2;i2++){
    #pragma unroll
    for(int r=0;r<4;r++){
      int rl = i2*16 + hi*4 + r;
      float rm = fmaxf(fmaxf(wred[0][rl],wred[1][rl]), fmaxf(wred[2][rl],wred[3][rl]));
      float dsum = 0.f;
      #pragma unroll
      for(int j2=0;j2<4;j2++){
        int col = w*64 + j2*16 + li;
        float u = acc[i2][j2][r]*DNRM;
        u16 eb = f2bf(SMF*(__expf(u - dgs[rl] - rm) + EPSF));
        smQ[rl*264 + col] = eb;
        dsum += bf2f(eb)*ksl[col];
      }
      dsum += __shfl_xor(dsum,1); dsum += __shfl_xor(dsum,2);
      dsum += __shfl_xor(dsum,4); dsum += __shfl_xor(dsum,8);
      if(li==0) wden[w][rl] = dsum;
    }
  }
  __builtin_amdgcn_sched_barrier(0);
  asm volatile("s_waitcnt vmcnt(0) lgkmcnt(0)");
  __builtin_amdgcn_s_barrier();
  __builtin_amdgcn_sched_barrier(0);
  if(tid < 32) denl[tid] = wden[0][tid]+wden[1][tid]+wden[2][tid]+wden[3][tid];
  // PV: wave w owns dh-tile w (16 dh) x 32 rows; K=256 over m
  f32x4 acc2[2] = {};
  #pragma unroll
  for(int s=0;s<8;s++){
    int kc = s*4 + hi;
    int bc = w*16 + li;
    bf16x8 bf = *(const bf16x8*)&smA[bc*256 + ((kc ^ (bc&7))<<3)];
    #pragma unroll
    for(int t=0;t<2;t++){
      int ar = t*16 + li;
      bf16x8 aa = *(const bf16x8*)&smQ[ar*264 + kc*8];
      acc2[t] = MFMA16(aa, bf, acc2[t]);
    }
  }
  __syncthreads();   // denl visible
  int nbase = r0 & (SEQ-1);
  #pragma unroll
  for(int t=0;t<2;t++){
    #pragma unroll
    for(int r=0;r<4;r++){
      int nl = t*16 + hi*4 + r;
      float di = 1.0f/denl[nl];
      o[((size_t)b*SEQ + nbase + nl)*DMODEL + h*DHEAD + w*16 + li] = f2bf(acc2[t][r]*di);
    }
  }
}

// ---------------- ctx_t[bh][dh][m] = sum_n v_t[dh][n]*kp_t[m][n], depth-2 pipeline ----------------
__global__ __launch_bounds__(256)
void k_ctx(const u16* __restrict__ vt, const u16* __restrict__ kpt,
           u16* __restrict__ ctxt){
  __shared__ u16 As[2][64*64];
  __shared__ u16 Bs[2][64*64];
  int tid = threadIdx.x, w = tid >> 6, lane = tid & 63;
  int wr = w >> 1, wc = w & 1;
  int hi = lane >> 4, li = lane & 15;
  int bh = blockIdx.y, mb = blockIdx.x*64;
  int lr = lane >> 3;
  int lc = (lane & 7) ^ lr;
  const u16* gA = vt  + (size_t)bh*DHEAD*SEQ + (size_t)(w*8 + lr)*SEQ + lc*8;
  const u16* gB = kpt + ((size_t)bh*MFEAT + mb + w*8 + lr)*SEQ + lc*8;
  f32x4 acc[2][2] = {};
#define STAGE_CTX(b,k0) { \
    GLOAD16(gA + (k0),                 &As[b][(w*8)*64]);      \
    GLOAD16(gA + (size_t)32*SEQ + (k0),&As[b][(32+w*8)*64]);   \
    GLOAD16(gB + (k0),                 &Bs[b][(w*8)*64]);      \
    GLOAD16(gB + (size_t)32*SEQ + (k0),&Bs[b][(32+w*8)*64]); }
  int nk = SEQ/64;
  STAGE_CTX(0, 0)
  STAGE_CTX(1, 64)
  for(int t=0; t<nk; ++t){
    __builtin_amdgcn_sched_barrier(0);
    if(t+1 < nk){ asm volatile("s_waitcnt vmcnt(4)"); }
    else        { asm volatile("s_waitcnt vmcnt(0)"); }
    __builtin_amdgcn_s_barrier();
    __builtin_amdgcn_sched_barrier(0);
    const u16* pa = &As[t&1][0];
    const u16* pb = &Bs[t&1][0];
    #pragma unroll
    for(int ks=0;ks<2;ks++){
      bf16x8 af[2], bfr[2];
      int kc = ks*4 + hi;
      #pragma unroll
      for(int q=0;q<2;q++){
        int ar = wr*32 + q*16 + li;
        af[q] = *(const bf16x8*)&pa[ar*64 + ((kc ^ (ar&7))<<3)];
        int bc = wc*32 + q*16 + li;
        bfr[q] = *(const bf16x8*)&pb[bc*64 + ((kc ^ (bc&7))<<3)];
      }
      #pragma unroll
      for(int i2=0;i2<2;i2++)
        #pragma unroll
        for(int j2=0;j2<2;j2++)
          acc[i2][j2] = MFMA16(af[i2], bfr[j2], acc[i2][j2]);
    }
    __builtin_amdgcn_sched_barrier(0);
    __builtin_amdgcn_s_barrier();
    __builtin_amdgcn_sched_barrier(0);
    if(t+2 < nk){ STAGE_CTX(t&1, (size_t)(t+2)*64) }
  }
#undef STAGE_CTX
  #pragma unroll
  for(int i2=0;i2<2;i2++)
    #pragma unroll
    for(int j2=0;j2<2;j2++){
      int m = mb + wc*32 + j2*16 + li;
      #pragma unroll
      for(int r=0;r<4;r++){
        int dh = wr*32 + i2*16 + hi*4 + r;
        ctxt[((size_t)bh*DHEAD + dh)*MFEAT + m] = f2bf(acc[i2][j2][r]);
      }
    }
}

extern "C" void kernel_launch(void* const* d_in, const int* in_sizes, int n_in,
                              void* d_out, int out_size, void* d_ws, size_t ws_size,
                              hipStream_t stream){
  (void)in_sizes; (void)n_in; (void)out_size; (void)ws_size;
  const float* x    = (const float*)d_in[0];
  const float* proj = (const float*)d_in[1];
  const float* ln1g = (const float*)d_in[2];
  const float* ln1b = (const float*)d_in[3];
  const float* wq   = (const float*)d_in[4];
  const float* wk   = (const float*)d_in[5];
  const float* wv   = (const float*)d_in[6];
  const float* wo   = (const float*)d_in[7];
  const float* bo   = (const float*)d_in[8];
  const float* ln2g = (const float*)d_in[9];
  const float* ln2b = (const float*)d_in[10];
  const float* w1   = (const float*)d_in[11];
  const float* b1   = (const float*)d_in[12];
  const float* w2   = (const float*)d_in[13];
  const float* b2   = (const float*)d_in[14];
  float* xo = (float*)d_out;

  // workspace ~110 MB
  char* ws = (char*)d_ws;
  u16* bufH  = (u16*)ws;  ws += (size_t)TOK*DMODEL*2;
  u16* bufA  = (u16*)ws;  ws += (size_t)TOK*DMODEL*2;
  u16* featb = (u16*)ws;  ws += (size_t)BHN*SEQ*MFEAT*2;
  u16* ctxt  = (u16*)ws;  ws += (size_t)BHN*DHEAD*MFEAT*2;
  u16* wT    = (u16*)ws;  ws += (size_t)3*1048576*2;
  u16* pjb   = (u16*)ws;  ws += (size_t)LNUM*MFEAT*DHEAD*2;
  float* ksum= (float*)ws; ws += (size_t)BHN*MFEAT*4;
  float* kmax= (float*)ws; ws += 256;

  u16* wqT = wT;
  u16* wkT = wT +  262144;
  u16* wvT = wT +  524288;
  u16* woT = wT +  786432;
  u16* w1T = wT + 1048576;
  u16* w2T = wT + 2097152;

  k_addpe<<<(TOK*DMODEL)/256, 256, 0, stream>>>(x, xo);
  k_pcvt<<<(LNUM*MFEAT*DHEAD)/256, 256, 0, stream>>>(proj, pjb);

  for(int l=0; l<LNUM; l++){
    const u16* pj_l = pjb + (size_t)l*MFEAT*DHEAD;
    k_wcvt_all<<<832, 256, 0, stream>>>(wq + (size_t)l*262144, wk + (size_t)l*262144,
                                        wv + (size_t)l*262144, wo + (size_t)l*262144,
                                        w1 + (size_t)l*1048576, w2 + (size_t)l*1048576,
                                        wqT, wkT, wvT, woT, w1T, w2T, ksum, kmax);
    k_ln<<<TOK, 256, 0, stream>>>(xo, ln1g + l*DMODEL, ln1b + l*DMODEL, bufH);
    // K path: k -> kmax -> kp_t (+ksum atomics)
    k_mm<1><<<dim3(4,128), 256, 0, stream>>>(bufH, wkT, nullptr, bufA, DMODEL, DMODEL);
    k_kmax<<<(BHN*SEQ)/128, 256, 0, stream>>>(bufA, pj_l, kmax);
    k_kfeat<<<(BHN*SEQ)/128, 256, 0, stream>>>(bufA, pj_l, featb, kmax, ksum);
    // V path: v_t -> ctx_t
    k_mm<4><<<dim3(4,128), 256, 0, stream>>>(bufH, wvT, nullptr, bufA, DMODEL, DMODEL);
    k_ctx<<<dim3(4,BHN), 256, 0, stream>>>(bufA, featb, ctxt);
    // Q path fused: q -> qp (LDS) -> o  -> wo-GEMM (residual add)
    k_mm<1><<<dim3(4,128), 256, 0, stream>>>(bufH, wqT, nullptr, bufA, DMODEL, DMODEL);
    k_feato<<<(BHN*SEQ)/32, 256, 0, stream>>>(bufA, pj_l, ctxt, ksum, bufH);
    k_mm<2><<<dim3(4,128), 256, 0, stream>>>(bufH, woT, bo + l*DMODEL, xo, DMODEL, DMODEL);
    // FFN
    k_ln<<<TOK, 256, 0, stream>>>(xo, ln2g + l*DMODEL, ln2b + l*DMODEL, bufA);
    k_mm<3><<<dim3(16,128), 256, 0, stream>>>(bufA, w1T, b1 + l*DFF, featb, DFF, DMODEL);
    k_mm<2><<<dim3(4,128), 256, 0, stream>>>(featb, w2T, b2 + l*DMODEL, xo, DMODEL, DFF);
  }
}

// Round 13
// 2079.033 us; speedup vs baseline: 16.6454x; 1.0488x over previous
//
#include <hip/hip_runtime.h>
#include <math.h>

#define LNUM 6
#define HNUM 8
#define DMODEL 512
#define DHEAD 64
#define MFEAT 256
#define BATCH 8
#define SEQ 2048
#define TOK (BATCH*SEQ)
#define BHN (BATCH*HNUM)
#define DFF 2048
#define EPSF 1e-4f
#define LN_EPS 1e-5f
#define DNRM 0.35355339059327373f
#define SMF 0.0625f

typedef unsigned short u16;
typedef __attribute__((ext_vector_type(8))) short bf16x8;
typedef __attribute__((ext_vector_type(4))) float f32x4;
#define MFMA16(a,b,c) __builtin_amdgcn_mfma_f32_16x16x32_bf16(a,b,c,0,0,0)

// async global->LDS, 16B per lane; LDS dest = wave-uniform base + lane*16
#define GLOAD16(g,l) __builtin_amdgcn_global_load_lds( \
    (const __attribute__((address_space(1))) void*)(g), \
    (__attribute__((address_space(3))) void*)(l), 16, 0, 0)

__device__ __forceinline__ u16 f2bf(float f){
  unsigned int u = __float_as_uint(f);
  u = (u + 0x7fffu + ((u >> 16) & 1u)) >> 16;
  return (u16)u;
}
__device__ __forceinline__ float bf2f(u16 s){
  return __uint_as_float(((unsigned int)s) << 16);
}
__device__ __forceinline__ void atomicMaxF(float* addr, float val){
  if(val >= 0.f) atomicMax((int*)addr, __float_as_int(val));
  else           atomicMin((unsigned int*)addr, __float_as_uint(val));
}
// gelu tanh-approx: z * sigmoid(2*(c1 z + c2 z^3))
__device__ __forceinline__ float fast_gelu(float z){
  float g2 = z*(1.5957691216f + 0.07135481628f*z*z);
  return z / (1.0f + __expf(-g2));
}

// ---------------- x = x + sinusoidal PE ----------------
__global__ void k_addpe(const float* __restrict__ x, float* __restrict__ xo){
  int idx = blockIdx.x*256 + threadIdx.x;
  int d = idx & (DMODEL-1);
  int n = (idx >> 9) & (SEQ-1);
  int j = d >> 1;
  float freq = expf((float)(2*j) * (-9.210340371976184f / (float)DMODEL));
  float ang = (float)n * freq;
  float pe = (d & 1) ? cosf(ang) : sinf(ang);
  xo[idx] = x[idx] + pe;
}

// ---------------- LayerNorm (512) -> bf16 ----------------
__global__ void k_ln(const float* __restrict__ x, const float* __restrict__ g,
                     const float* __restrict__ bv, u16* __restrict__ out){
  __shared__ float sred[8];
  int t = blockIdx.x, tid = threadIdx.x;
  const float2 v = ((const float2*)(x + (size_t)t*DMODEL))[tid];
  float s = v.x + v.y;
  #pragma unroll
  for(int o=32;o;o>>=1) s += __shfl_down(s,o);
  if((tid&63)==0) sred[tid>>6] = s;
  __syncthreads();
  if(tid==0) sred[4] = (sred[0]+sred[1]+sred[2]+sred[3]) * (1.0f/DMODEL);
  __syncthreads();
  float mu = sred[4];
  float dx = v.x - mu, dy = v.y - mu;
  float s2 = dx*dx + dy*dy;
  #pragma unroll
  for(int o=32;o;o>>=1) s2 += __shfl_down(s2,o);
  if((tid&63)==0) sred[tid>>6] = s2;
  __syncthreads();
  if(tid==0) sred[5] = rsqrtf((sred[0]+sred[1]+sred[2]+sred[3])*(1.0f/DMODEL) + LN_EPS);
  __syncthreads();
  float rs = sred[5];
  const float2 gg = ((const float2*)g)[tid];
  const float2 bb = ((const float2*)bv)[tid];
  ushort2 o2; o2.x = f2bf(dx*rs*gg.x + bb.x); o2.y = f2bf(dy*rs*gg.y + bb.y);
  ((ushort2*)(out + (size_t)t*DMODEL))[tid] = o2;
}

__global__ void k_pcvt(const float* __restrict__ p, u16* __restrict__ pb){
  int i = blockIdx.x*256 + threadIdx.x;
  pb[i] = f2bf(p[i]);
}

// ---------------- all weight transposes + ksum/kmax init in ONE dispatch ----------------
__global__ void k_wcvt_all(const float* __restrict__ wq, const float* __restrict__ wk,
                           const float* __restrict__ wv, const float* __restrict__ wo,
                           const float* __restrict__ w1, const float* __restrict__ w2,
                           u16* __restrict__ wqT, u16* __restrict__ wkT,
                           u16* __restrict__ wvT, u16* __restrict__ woT,
                           u16* __restrict__ w1T, u16* __restrict__ w2T,
                           float* __restrict__ ksum, float* __restrict__ kmax){
  int bid = blockIdx.x;
  if(bid >= 768){
    int i = (bid-768)*256 + threadIdx.x;
    ksum[i] = 0.f;
    if(i < BHN) kmax[i] = -INFINITY;
    return;
  }
  const float* src; u16* dst; int K, N, bx, by;
  if(bid < 256){
    int which = bid >> 6, sub = bid & 63;
    src = which==0 ? wq : which==1 ? wk : which==2 ? wv : wo;
    dst = which==0 ? wqT : which==1 ? wkT : which==2 ? wvT : woT;
    K = 512; N = 512; bx = sub & 7; by = sub >> 3;
  } else if(bid < 512){
    int sub = bid - 256; src = w1; dst = w1T; K = 512; N = 2048; bx = sub & 31; by = sub >> 5;
  } else {
    int sub = bid - 512; src = w2; dst = w2T; K = 2048; N = 512; bx = sub & 7; by = sub >> 3;
  }
  __shared__ float sm[64][65];
  int kt = by*64, nt = bx*64;
  int t = threadIdx.x, c = t & 63, r4 = t >> 6;
  #pragma unroll
  for(int i=0;i<16;i++){
    int kl = i*4 + r4;
    sm[kl][c] = src[(size_t)(kt+kl)*N + nt + c];
  }
  __syncthreads();
  #pragma unroll
  for(int i=0;i<16;i++){
    int nl = i*4 + r4;
    dst[(size_t)(nt+nl)*K + kt + c] = f2bf(sm[c][nl]);
  }
}

// ---------------- MFMA GEMM, BK=32, depth-2, counted vmcnt, 128-reg cap ----------------
template<int EPI>
__global__ __launch_bounds__(256,4)
void k_mm(const u16* __restrict__ A, const u16* __restrict__ Bt,
          const float* __restrict__ bias, void* __restrict__ Cv,
          int Nc, int K){
  __shared__ u16 As[2][128*32];
  __shared__ u16 Bs[2][128*32];
  int tid = threadIdx.x;
  int w = tid >> 6, lane = tid & 63;
  int wr = w >> 1, wc = w & 1;
  int hi = lane >> 4, li = lane & 15;
  int row0 = blockIdx.y*128, col0 = blockIdx.x*128;
  int lr = lane >> 2;
  int cs = (lane & 3) ^ ((lane >> 3) & 3);
  const u16* gA = A  + (size_t)(row0 + w*16 + lr)*K + cs*8;
  const u16* gB = Bt + (size_t)(col0 + w*16 + lr)*K + cs*8;
  int rb = li*32 + ((hi ^ ((li>>1)&3))<<3);
  f32x4 acc[4][4] = {};

#define STAGE_MM(b,k0) { \
    GLOAD16(gA + (k0),                &As[b][(w*16)*32]);      \
    GLOAD16(gA + (size_t)64*K + (k0), &As[b][(64+w*16)*32]);   \
    GLOAD16(gB + (k0),                &Bs[b][(w*16)*32]);      \
    GLOAD16(gB + (size_t)64*K + (k0), &Bs[b][(64+w*16)*32]); }

  int nk = K >> 5;
  STAGE_MM(0, 0)
  STAGE_MM(1, 32)
  for(int t=0; t<nk; ++t){
    __builtin_amdgcn_sched_barrier(0);
    if(t+1 < nk){ asm volatile("s_waitcnt vmcnt(4)"); }
    else        { asm volatile("s_waitcnt vmcnt(0)"); }
    __builtin_amdgcn_s_barrier();
    __builtin_amdgcn_sched_barrier(0);
    const u16* pa = &As[t&1][0];
    const u16* pb = &Bs[t&1][0];
    bf16x8 bfr[4];
    #pragma unroll
    for(int q=0;q<4;q++) bfr[q] = *(const bf16x8*)&pb[rb + wc*2048 + q*512];
    #pragma unroll
    for(int i2=0;i2<4;i2++){
      bf16x8 a = *(const bf16x8*)&pa[rb + wr*2048 + i2*512];
      #pragma unroll
      for(int j2=0;j2<4;j2++)
        acc[i2][j2] = MFMA16(a, bfr[j2], acc[i2][j2]);
    }
    __builtin_amdgcn_sched_barrier(0);
    __builtin_amdgcn_s_barrier();
    __builtin_amdgcn_sched_barrier(0);
    if(t+2 < nk){ STAGE_MM(t&1, (size_t)(t+2)*32) }
  }
#undef STAGE_MM

  #pragma unroll
  for(int i2=0;i2<4;i2++){
    #pragma unroll
    for(int j2=0;j2<4;j2++){
      int col = col0 + wc*64 + j2*16 + li;
      float bcol = (EPI==2 || EPI==3) ? bias[col] : 0.f;
      if constexpr (EPI==4){
        int nb = row0 + wr*64 + i2*16 + hi*4;
        int b = nb >> 11, n = nb & (SEQ-1);
        int h = col >> 6, dh = col & 63;
        ushort4 pk;
        pk.x = f2bf(acc[i2][j2][0]); pk.y = f2bf(acc[i2][j2][1]);
        pk.z = f2bf(acc[i2][j2][2]); pk.w = f2bf(acc[i2][j2][3]);
        *(ushort4*)((u16*)Cv + (((size_t)(b*HNUM+h)*DHEAD + dh)*SEQ + n)) = pk;
      } else {
        #pragma unroll
        for(int r=0;r<4;r++){
          int row = row0 + wr*64 + i2*16 + hi*4 + r;
          float v = acc[i2][j2][r];
          if constexpr (EPI==1){
            int b = row >> 11, n = row & (SEQ-1);
            int h = col >> 6, dh = col & 63;
            ((u16*)Cv)[((size_t)(b*HNUM+h)*SEQ + n)*DHEAD + dh] = f2bf(v);
          } else if constexpr (EPI==2){
            ((float*)Cv)[(size_t)row*Nc + col] += v + bcol;
          } else {
            ((u16*)Cv)[(size_t)row*Nc + col] = f2bf(fast_gelu(v + bcol));
          }
        }
      }
    }
  }
}

// ---------------- K max pass: 128 rows/block, streaming acc ----------------
__global__ __launch_bounds__(256)
void k_kmax(const u16* __restrict__ xg, const u16* __restrict__ pjb,
            float* __restrict__ kmax){
  __shared__ u16 pj[256*64];
  __shared__ u16 xs[128*64];
  __shared__ float wred[4];
  int tid = threadIdx.x, w = tid >> 6, lane = tid & 63;
  int hi = lane >> 4, li = lane & 15;
  int r0 = blockIdx.x * 128;
  int bh = r0 >> 11;
  #pragma unroll
  for(int i=0;i<8;i++){
    int idx = i*256 + tid;
    int m = idx >> 3, c = idx & 7;
    bf16x8 v = *(const bf16x8*)(pjb + m*64 + c*8);
    *(bf16x8*)&pj[m*64 + ((c ^ (m&7))<<3)] = v;
  }
  #pragma unroll
  for(int i=0;i<4;i++){
    int idx = i*256 + tid;
    int m = idx >> 3, c = idx & 7;
    bf16x8 v = *(const bf16x8*)(xg + (size_t)(r0+m)*64 + c*8);
    *(bf16x8*)&xs[m*64 + ((c ^ (m&7))<<3)] = v;
  }
  __syncthreads();
  bf16x8 bfr[2][4];
  #pragma unroll
  for(int ks=0;ks<2;ks++){
    int kc = ks*4 + hi;
    #pragma unroll
    for(int t=0;t<4;t++){
      int bc = w*64 + t*16 + li;
      bfr[ks][t] = *(const bf16x8*)&pj[bc*64 + ((kc ^ (bc&7))<<3)];
    }
  }
  float mx = -1e30f;
  #pragma unroll
  for(int i8=0;i8<8;i8++){
    f32x4 acc[4] = {};
    #pragma unroll
    for(int ks=0;ks<2;ks++){
      int kc = ks*4 + hi;
      int ar = i8*16 + li;
      bf16x8 af = *(const bf16x8*)&xs[ar*64 + ((kc ^ (ar&7))<<3)];
      #pragma unroll
      for(int j2=0;j2<4;j2++)
        acc[j2] = MFMA16(af, bfr[ks][j2], acc[j2]);
    }
    #pragma unroll
    for(int j2=0;j2<4;j2++)
      #pragma unroll
      for(int r=0;r<4;r++) mx = fmaxf(mx, acc[j2][r]);
  }
  #pragma unroll
  for(int o=32;o;o>>=1) mx = fmaxf(mx, __shfl_xor(mx,o));
  if(lane==0) wred[w] = mx;
  __syncthreads();
  if(tid==0){
    float m2 = fmaxf(fmaxf(wred[0],wred[1]), fmaxf(wred[2],wred[3]));
    atomicMaxF(&kmax[bh], m2*DNRM);
  }
}

// ---------------- K feature pass: 128 rows/block, kp_t + ksum, register diag ----------------
__global__ __launch_bounds__(256)
void k_kfeat(const u16* __restrict__ xg, const u16* __restrict__ pjb,
             u16* __restrict__ outp, const float* __restrict__ kmax,
             float* __restrict__ ksum){
  __shared__ u16 pj[256*64];
  __shared__ u16 xs[128*64];
  __shared__ float dgs[128];
  int tid = threadIdx.x, w = tid >> 6, lane = tid & 63;
  int hi = lane >> 4, li = lane & 15;
  int r0 = blockIdx.x * 128;
  int bh = r0 >> 11;
  int nbase = r0 & (SEQ-1);
  #pragma unroll
  for(int i=0;i<8;i++){
    int idx = i*256 + tid;
    int m = idx >> 3, c = idx & 7;
    bf16x8 v = *(const bf16x8*)(pjb + m*64 + c*8);
    *(bf16x8*)&pj[m*64 + ((c ^ (m&7))<<3)] = v;
  }
  #pragma unroll
  for(int i=0;i<4;i++){
    int idx = i*256 + tid;
    int m = idx >> 3, c = idx & 7;
    bf16x8 v = *(const bf16x8*)(xg + (size_t)(r0+m)*64 + c*8);
    *(bf16x8*)&xs[m*64 + ((c ^ (m&7))<<3)] = v;
    float s = 0.f;
    #pragma unroll
    for(int j=0;j<8;j++){ float t = bf2f((u16)v[j]); s += t*t; }
    s += __shfl_xor(s,1); s += __shfl_xor(s,2); s += __shfl_xor(s,4);
    if((tid&7)==0) dgs[m] = 0.5f*DNRM*DNRM*s;
  }
  __syncthreads();
  bf16x8 bfr[2][4];
  #pragma unroll
  for(int ks=0;ks<2;ks++){
    int kc = ks*4 + hi;
    #pragma unroll
    for(int t=0;t<4;t++){
      int bc = w*64 + t*16 + li;
      bfr[ks][t] = *(const bf16x8*)&pj[bc*64 + ((kc ^ (bc&7))<<3)];
    }
  }
  float km = kmax[bh];
  float csum[4] = {0.f,0.f,0.f,0.f};
  #pragma unroll
  for(int i8=0;i8<8;i8++){
    f32x4 acc[4] = {};
    #pragma unroll
    for(int ks=0;ks<2;ks++){
      int kc = ks*4 + hi;
      int ar = i8*16 + li;
      bf16x8 af = *(const bf16x8*)&xs[ar*64 + ((kc ^ (ar&7))<<3)];
      #pragma unroll
      for(int j2=0;j2<4;j2++)
        acc[j2] = MFMA16(af, bfr[ks][j2], acc[j2]);
    }
    #pragma unroll
    for(int j2=0;j2<4;j2++){
      int col = w*64 + j2*16 + li;
      ushort4 pk;
      float cpart = 0.f;
      #pragma unroll
      for(int r=0;r<4;r++){
        int rl = i8*16 + hi*4 + r;
        float u = acc[j2][r]*DNRM;
        u16 eb = f2bf(SMF*(__expf(u - dgs[rl] - km) + EPSF));
        ((u16*)&pk)[r] = eb;
        cpart += bf2f(eb);
      }
      *(ushort4*)(outp + ((size_t)(bh*MFEAT + col)*SEQ + nbase + i8*16 + hi*4)) = pk;
      csum[j2] += cpart;
    }
  }
  #pragma unroll
  for(int j2=0;j2<4;j2++){
    float v = csum[j2];
    v += __shfl_xor(v,16); v += __shfl_xor(v,32);
    if(hi==0) atomicAdd(&ksum[bh*MFEAT + w*64 + j2*16 + li], v);
  }
}

// ---------------- fused Q-feature + PV, 512 threads / 64 rows per block ----------------
// waves: g = w>>2 row-group (32 rows), wq = w&3 col-quarter. PV: d4 = w>>1, g2 = w&1.
__global__ __launch_bounds__(512)
void k_feato(const u16* __restrict__ xg, const u16* __restrict__ pjb,
             const u16* __restrict__ ctxt, const float* __restrict__ ksum,
             u16* __restrict__ o){
  __shared__ u16 smA[16384];     // pj (swz) -> ctx (swz) after u-MFMA
  __shared__ u16 smX[4096];      // 64 q rows (swz)
  __shared__ u16 smQ[64*264];    // qp, stride 264
  __shared__ float dgs[64];
  __shared__ float wred[2][4][32];
  __shared__ float wden[2][4][32];
  __shared__ float ksl[256];
  __shared__ float denl[64];
  int tid = threadIdx.x, w = tid >> 6, lane = tid & 63;
  int hi = lane >> 4, li = lane & 15;
  int g = w >> 2, wq = w & 3;
  int r0 = blockIdx.x * 64;
  int bh = r0 >> 11;
  int b = bh >> 3, h = bh & 7;
  #pragma unroll
  for(int i=0;i<4;i++){
    int idx = i*512 + tid;
    int m = idx >> 3, c = idx & 7;
    bf16x8 v = *(const bf16x8*)(pjb + m*64 + c*8);
    *(bf16x8*)&smA[m*64 + ((c ^ (m&7))<<3)] = v;
  }
  {
    int m = tid >> 3, c = tid & 7;
    bf16x8 v = *(const bf16x8*)(xg + (size_t)(r0+m)*64 + c*8);
    *(bf16x8*)&smX[m*64 + ((c ^ (m&7))<<3)] = v;
    float s = 0.f;
    #pragma unroll
    for(int j=0;j<8;j++){ float t = bf2f((u16)v[j]); s += t*t; }
    s += __shfl_xor(s,1); s += __shfl_xor(s,2); s += __shfl_xor(s,4);
    if((tid&7)==0) dgs[m] = 0.5f*DNRM*DNRM*s;
  }
  if(tid < 256) ksl[tid] = ksum[bh*MFEAT + tid];
  __syncthreads();
  f32x4 acc[2][4] = {};
  #pragma unroll
  for(int ks=0;ks<2;ks++){
    bf16x8 af[2], bfr[4];
    int kc = ks*4 + hi;
    #pragma unroll
    for(int t=0;t<2;t++){
      int ar = g*32 + t*16 + li;
      af[t] = *(const bf16x8*)&smX[ar*64 + ((kc ^ (ar&7))<<3)];
    }
    #pragma unroll
    for(int t=0;t<4;t++){
      int bc = wq*64 + t*16 + li;
      bfr[t] = *(const bf16x8*)&smA[bc*64 + ((kc ^ (bc&7))<<3)];
    }
    #pragma unroll
    for(int i2=0;i2<2;i2++)
      #pragma unroll
      for(int j2=0;j2<4;j2++)
        acc[i2][j2] = MFMA16(af[i2], bfr[j2], acc[i2][j2]);
  }
  __syncthreads();   // all pj reads done; smA reusable
  // async ctx_t[bh] (64x256 bf16, 32KB) -> smA; lane-constant pre-swizzled source
  {
    int gch = (tid & 31) ^ ((tid >> 5) & 7);
    const u16* gCl = ctxt + (size_t)bh*DHEAD*MFEAT + (size_t)(tid>>5)*MFEAT + gch*8;
    #pragma unroll
    for(int i=0;i<4;i++)
      GLOAD16(gCl + (size_t)i*16*MFEAT, &smA[i*4096 + w*512]);
  }
  // per-row max over m (across the 4 col-quarter waves of this group)
  #pragma unroll
  for(int i2=0;i2<2;i2++){
    #pragma unroll
    for(int r=0;r<4;r++){
      float v = fmaxf(fmaxf(acc[i2][0][r],acc[i2][1][r]), fmaxf(acc[i2][2][r],acc[i2][3][r]));
      v = fmaxf(v, __shfl_xor(v,1)); v = fmaxf(v, __shfl_xor(v,2));
      v = fmaxf(v, __shfl_xor(v,4)); v = fmaxf(v, __shfl_xor(v,8));
      if(li==0) wred[g][wq][i2*16 + hi*4 + r] = v;
    }
  }
  __builtin_amdgcn_sched_barrier(0);
  asm volatile("s_waitcnt lgkmcnt(0)");
  __builtin_amdgcn_s_barrier();
  __builtin_amdgcn_sched_barrier(0);
  // qp = exp(u - diag - rowmax)*s + eps -> smQ ; den partial = qp . ksum
  #pragma unroll
  for(int i2=0;i2<2;i2++){
    #pragma unroll
    for(int r=0;r<4;r++){
      int rl = i2*16 + hi*4 + r;          // row within group (0..31)
      int row = g*32 + rl;                // row within block (0..63)
      float rm = fmaxf(fmaxf(wred[g][0][rl],wred[g][1][rl]),
                       fmaxf(wred[g][2][rl],wred[g][3][rl]));
      float dsum = 0.f;
      #pragma unroll
      for(int j2=0;j2<4;j2++){
        int col = wq*64 + j2*16 + li;
        float u = acc[i2][j2][r]*DNRM;
        u16 eb = f2bf(SMF*(__expf(u - dgs[row] - rm) + EPSF));
        smQ[row*264 + col] = eb;
        dsum += bf2f(eb)*ksl[col];
      }
      dsum += __shfl_xor(dsum,1); dsum += __shfl_xor(dsum,2);
      dsum += __shfl_xor(dsum,4); dsum += __shfl_xor(dsum,8);
      if(li==0) wden[g][wq][rl] = dsum;
    }
  }
  __builtin_amdgcn_sched_barrier(0);
  asm volatile("s_waitcnt vmcnt(0) lgkmcnt(0)");
  __builtin_amdgcn_s_barrier();
  __builtin_amdgcn_sched_barrier(0);
  if(tid < 64){
    int gg = tid >> 5, rr = tid & 31;
    denl[tid] = wden[gg][0][rr]+wden[gg][1][rr]+wden[gg][2][rr]+wden[gg][3][rr];
  }
  // PV: wave (d4 = w>>1, g2 = w&1) owns 16 dh x 32 rows; K=256 over m
  int d4 = w >> 1, g2 = w & 1;
  f32x4 acc2[2] = {};
  #pragma unroll
  for(int s=0;s<8;s++){
    int kc = s*4 + hi;
    int bc = d4*16 + li;
    bf16x8 bf = *(const bf16x8*)&smA[bc*256 + ((kc ^ (bc&7))<<3)];
    #pragma unroll
    for(int t=0;t<2;t++){
      int ar = g2*32 + t*16 + li;
      bf16x8 aa = *(const bf16x8*)&smQ[ar*264 + kc*8];
      acc2[t] = MFMA16(aa, bf, acc2[t]);
    }
  }
  __syncthreads();   // denl visible
  int nbase = r0 & (SEQ-1);
  #pragma unroll
  for(int t=0;t<2;t++){
    #pragma unroll
    for(int r=0;r<4;r++){
      int nl = g2*32 + t*16 + hi*4 + r;
      float di = 1.0f/denl[nl];
      o[((size_t)b*SEQ + nbase + nl)*DMODEL + h*DHEAD + d4*16 + li] = f2bf(acc2[t][r]*di);
    }
  }
}

// ---------------- ctx_t[bh][dh][m] = sum_n v_t[dh][n]*kp_t[m][n], depth-2 pipeline ----------------
__global__ __launch_bounds__(256)
void k_ctx(const u16* __restrict__ vt, const u16* __restrict__ kpt,
           u16* __restrict__ ctxt){
  __shared__ u16 As[2][64*64];
  __shared__ u16 Bs[2][64*64];
  int tid = threadIdx.x, w = tid >> 6, lane = tid & 63;
  int wr = w >> 1, wc = w & 1;
  int hi = lane >> 4, li = lane & 15;
  int bh = blockIdx.y, mb = blockIdx.x*64;
  int lr = lane >> 3;
  int lc = (lane & 7) ^ lr;
  const u16* gA = vt  + (size_t)bh*DHEAD*SEQ + (size_t)(w*8 + lr)*SEQ + lc*8;
  const u16* gB = kpt + ((size_t)bh*MFEAT + mb + w*8 + lr)*SEQ + lc*8;
  f32x4 acc[2][2] = {};
#define STAGE_CTX(b,k0) { \
    GLOAD16(gA + (k0),                 &As[b][(w*8)*64]);      \
    GLOAD16(gA + (size_t)32*SEQ + (k0),&As[b][(32+w*8)*64]);   \
    GLOAD16(gB + (k0),                 &Bs[b][(w*8)*64]);      \
    GLOAD16(gB + (size_t)32*SEQ + (k0),&Bs[b][(32+w*8)*64]); }
  int nk = SEQ/64;
  STAGE_CTX(0, 0)
  STAGE_CTX(1, 64)
  for(int t=0; t<nk; ++t){
    __builtin_amdgcn_sched_barrier(0);
    if(t+1 < nk){ asm volatile("s_waitcnt vmcnt(4)"); }
    else        { asm volatile("s_waitcnt vmcnt(0)"); }
    __builtin_amdgcn_s_barrier();
    __builtin_amdgcn_sched_barrier(0);
    const u16* pa = &As[t&1][0];
    const u16* pb = &Bs[t&1][0];
    #pragma unroll
    for(int ks=0;ks<2;ks++){
      bf16x8 af[2], bfr[2];
      int kc = ks*4 + hi;
      #pragma unroll
      for(int q=0;q<2;q++){
        int ar = wr*32 + q*16 + li;
        af[q] = *(const bf16x8*)&pa[ar*64 + ((kc ^ (ar&7))<<3)];
        int bc = wc*32 + q*16 + li;
        bfr[q] = *(const bf16x8*)&pb[bc*64 + ((kc ^ (bc&7))<<3)];
      }
      #pragma unroll
      for(int i2=0;i2<2;i2++)
        #pragma unroll
        for(int j2=0;j2<2;j2++)
          acc[i2][j2] = MFMA16(af[i2], bfr[j2], acc[i2][j2]);
    }
    __builtin_amdgcn_sched_barrier(0);
    __builtin_amdgcn_s_barrier();
    __builtin_amdgcn_sched_barrier(0);
    if(t+2 < nk){ STAGE_CTX(t&1, (size_t)(t+2)*64) }
  }
#undef STAGE_CTX
  #pragma unroll
  for(int i2=0;i2<2;i2++)
    #pragma unroll
    for(int j2=0;j2<2;j2++){
      int m = mb + wc*32 + j2*16 + li;
      #pragma unroll
      for(int r=0;r<4;r++){
        int dh = wr*32 + i2*16 + hi*4 + r;
        ctxt[((size_t)bh*DHEAD + dh)*MFEAT + m] = f2bf(acc[i2][j2][r]);
      }
    }
}

extern "C" void kernel_launch(void* const* d_in, const int* in_sizes, int n_in,
                              void* d_out, int out_size, void* d_ws, size_t ws_size,
                              hipStream_t stream){
  (void)in_sizes; (void)n_in; (void)out_size; (void)ws_size;
  const float* x    = (const float*)d_in[0];
  const float* proj = (const float*)d_in[1];
  const float* ln1g = (const float*)d_in[2];
  const float* ln1b = (const float*)d_in[3];
  const float* wq   = (const float*)d_in[4];
  const float* wk   = (const float*)d_in[5];
  const float* wv   = (const float*)d_in[6];
  const float* wo   = (const float*)d_in[7];
  const float* bo   = (const float*)d_in[8];
  const float* ln2g = (const float*)d_in[9];
  const float* ln2b = (const float*)d_in[10];
  const float* w1   = (const float*)d_in[11];
  const float* b1   = (const float*)d_in[12];
  const float* w2   = (const float*)d_in[13];
  const float* b2   = (const float*)d_in[14];
  float* xo = (float*)d_out;

  // workspace ~110 MB
  char* ws = (char*)d_ws;
  u16* bufH  = (u16*)ws;  ws += (size_t)TOK*DMODEL*2;
  u16* bufA  = (u16*)ws;  ws += (size_t)TOK*DMODEL*2;
  u16* featb = (u16*)ws;  ws += (size_t)BHN*SEQ*MFEAT*2;
  u16* ctxt  = (u16*)ws;  ws += (size_t)BHN*DHEAD*MFEAT*2;
  u16* wT    = (u16*)ws;  ws += (size_t)3*1048576*2;
  u16* pjb   = (u16*)ws;  ws += (size_t)LNUM*MFEAT*DHEAD*2;
  float* ksum= (float*)ws; ws += (size_t)BHN*MFEAT*4;
  float* kmax= (float*)ws; ws += 256;

  u16* wqT = wT;
  u16* wkT = wT +  262144;
  u16* wvT = wT +  524288;
  u16* woT = wT +  786432;
  u16* w1T = wT + 1048576;
  u16* w2T = wT + 2097152;

  k_addpe<<<(TOK*DMODEL)/256, 256, 0, stream>>>(x, xo);
  k_pcvt<<<(LNUM*MFEAT*DHEAD)/256, 256, 0, stream>>>(proj, pjb);

  for(int l=0; l<LNUM; l++){
    const u16* pj_l = pjb + (size_t)l*MFEAT*DHEAD;
    k_wcvt_all<<<832, 256, 0, stream>>>(wq + (size_t)l*262144, wk + (size_t)l*262144,
                                        wv + (size_t)l*262144, wo + (size_t)l*262144,
                                        w1 + (size_t)l*1048576, w2 + (size_t)l*1048576,
                                        wqT, wkT, wvT, woT, w1T, w2T, ksum, kmax);
    k_ln<<<TOK, 256, 0, stream>>>(xo, ln1g + l*DMODEL, ln1b + l*DMODEL, bufH);
    // K path: k -> kmax -> kp_t (+ksum atomics)
    k_mm<1><<<dim3(4,128), 256, 0, stream>>>(bufH, wkT, nullptr, bufA, DMODEL, DMODEL);
    k_kmax<<<(BHN*SEQ)/128, 256, 0, stream>>>(bufA, pj_l, kmax);
    k_kfeat<<<(BHN*SEQ)/128, 256, 0, stream>>>(bufA, pj_l, featb, kmax, ksum);
    // V path: v_t -> ctx_t
    k_mm<4><<<dim3(4,128), 256, 0, stream>>>(bufH, wvT, nullptr, bufA, DMODEL, DMODEL);
    k_ctx<<<dim3(4,BHN), 256, 0, stream>>>(bufA, featb, ctxt);
    // Q path fused: q -> qp (LDS) -> o  -> wo-GEMM (residual add)
    k_mm<1><<<dim3(4,128), 256, 0, stream>>>(bufH, wqT, nullptr, bufA, DMODEL, DMODEL);
    k_feato<<<(BHN*SEQ)/64, 512, 0, stream>>>(bufA, pj_l, ctxt, ksum, bufH);
    k_mm<2><<<dim3(4,128), 256, 0, stream>>>(bufH, woT, bo + l*DMODEL, xo, DMODEL, DMODEL);
    // FFN
    k_ln<<<TOK, 256, 0, stream>>>(xo, ln2g + l*DMODEL, ln2b + l*DMODEL, bufA);
    k_mm<3><<<dim3(16,128), 256, 0, stream>>>(bufA, w1T, b1 + l*DFF, featb, DFF, DMODEL);
    k_mm<2><<<dim3(4,128), 256, 0, stream>>>(featb, w2T, b2 + l*DMODEL, xo, DMODEL, DFF);
  }
}

// Round 14
// 2042.935 us; speedup vs baseline: 16.9396x; 1.0177x over previous
//
#include <hip/hip_runtime.h>
#include <math.h>

#define LNUM 6
#define HNUM 8
#define DMODEL 512
#define DHEAD 64
#define MFEAT 256
#define BATCH 8
#define SEQ 2048
#define TOK (BATCH*SEQ)
#define BHN (BATCH*HNUM)
#define DFF 2048
#define EPSF 1e-4f
#define LN_EPS 1e-5f
#define DNRM 0.35355339059327373f
#define SMF 0.0625f

typedef unsigned short u16;
typedef __attribute__((ext_vector_type(8))) short bf16x8;
typedef __attribute__((ext_vector_type(4))) float f32x4;
#define MFMA16(a,b,c) __builtin_amdgcn_mfma_f32_16x16x32_bf16(a,b,c,0,0,0)

// async global->LDS, 16B per lane; LDS dest = wave-uniform base + lane*16
#define GLOAD16(g,l) __builtin_amdgcn_global_load_lds( \
    (const __attribute__((address_space(1))) void*)(g), \
    (__attribute__((address_space(3))) void*)(l), 16, 0, 0)

__device__ __forceinline__ u16 f2bf(float f){
  unsigned int u = __float_as_uint(f);
  u = (u + 0x7fffu + ((u >> 16) & 1u)) >> 16;
  return (u16)u;
}
__device__ __forceinline__ float bf2f(u16 s){
  return __uint_as_float(((unsigned int)s) << 16);
}
__device__ __forceinline__ void atomicMaxF(float* addr, float val){
  if(val >= 0.f) atomicMax((int*)addr, __float_as_int(val));
  else           atomicMin((unsigned int*)addr, __float_as_uint(val));
}
// gelu tanh-approx: z * sigmoid(2*(c1 z + c2 z^3))
__device__ __forceinline__ float fast_gelu(float z){
  float g2 = z*(1.5957691216f + 0.07135481628f*z*z);
  return z / (1.0f + __expf(-g2));
}

// ---------------- x = x + sinusoidal PE ----------------
__global__ void k_addpe(const float* __restrict__ x, float* __restrict__ xo){
  int idx = blockIdx.x*256 + threadIdx.x;
  int d = idx & (DMODEL-1);
  int n = (idx >> 9) & (SEQ-1);
  int j = d >> 1;
  float freq = expf((float)(2*j) * (-9.210340371976184f / (float)DMODEL));
  float ang = (float)n * freq;
  float pe = (d & 1) ? cosf(ang) : sinf(ang);
  xo[idx] = x[idx] + pe;
}

// ---------------- LayerNorm (512) -> bf16 ----------------
__global__ void k_ln(const float* __restrict__ x, const float* __restrict__ g,
                     const float* __restrict__ bv, u16* __restrict__ out){
  __shared__ float sred[8];
  int t = blockIdx.x, tid = threadIdx.x;
  const float2 v = ((const float2*)(x + (size_t)t*DMODEL))[tid];
  float s = v.x + v.y;
  #pragma unroll
  for(int o=32;o;o>>=1) s += __shfl_down(s,o);
  if((tid&63)==0) sred[tid>>6] = s;
  __syncthreads();
  if(tid==0) sred[4] = (sred[0]+sred[1]+sred[2]+sred[3]) * (1.0f/DMODEL);
  __syncthreads();
  float mu = sred[4];
  float dx = v.x - mu, dy = v.y - mu;
  float s2 = dx*dx + dy*dy;
  #pragma unroll
  for(int o=32;o;o>>=1) s2 += __shfl_down(s2,o);
  if((tid&63)==0) sred[tid>>6] = s2;
  __syncthreads();
  if(tid==0) sred[5] = rsqrtf((sred[0]+sred[1]+sred[2]+sred[3])*(1.0f/DMODEL) + LN_EPS);
  __syncthreads();
  float rs = sred[5];
  const float2 gg = ((const float2*)g)[tid];
  const float2 bb = ((const float2*)bv)[tid];
  ushort2 o2; o2.x = f2bf(dx*rs*gg.x + bb.x); o2.y = f2bf(dy*rs*gg.y + bb.y);
  ((ushort2*)(out + (size_t)t*DMODEL))[tid] = o2;
}

__global__ void k_pcvt(const float* __restrict__ p, u16* __restrict__ pb){
  int i = blockIdx.x*256 + threadIdx.x;
  pb[i] = f2bf(p[i]);
}

// ---------------- all weight transposes + ksum/kmax init in ONE dispatch ----------------
__global__ void k_wcvt_all(const float* __restrict__ wq, const float* __restrict__ wk,
                           const float* __restrict__ wv, const float* __restrict__ wo,
                           const float* __restrict__ w1, const float* __restrict__ w2,
                           u16* __restrict__ wqT, u16* __restrict__ wkT,
                           u16* __restrict__ wvT, u16* __restrict__ woT,
                           u16* __restrict__ w1T, u16* __restrict__ w2T,
                           float* __restrict__ ksum, float* __restrict__ kmax){
  int bid = blockIdx.x;
  if(bid >= 768){
    int i = (bid-768)*256 + threadIdx.x;
    ksum[i] = 0.f;
    if(i < BHN) kmax[i] = -INFINITY;
    return;
  }
  const float* src; u16* dst; int K, N, bx, by;
  if(bid < 256){
    int which = bid >> 6, sub = bid & 63;
    src = which==0 ? wq : which==1 ? wk : which==2 ? wv : wo;
    dst = which==0 ? wqT : which==1 ? wkT : which==2 ? wvT : woT;
    K = 512; N = 512; bx = sub & 7; by = sub >> 3;
  } else if(bid < 512){
    int sub = bid - 256; src = w1; dst = w1T; K = 512; N = 2048; bx = sub & 31; by = sub >> 5;
  } else {
    int sub = bid - 512; src = w2; dst = w2T; K = 2048; N = 512; bx = sub & 7; by = sub >> 3;
  }
  __shared__ float sm[64][65];
  int kt = by*64, nt = bx*64;
  int t = threadIdx.x, c = t & 63, r4 = t >> 6;
  #pragma unroll
  for(int i=0;i<16;i++){
    int kl = i*4 + r4;
    sm[kl][c] = src[(size_t)(kt+kl)*N + nt + c];
  }
  __syncthreads();
  #pragma unroll
  for(int i=0;i<16;i++){
    int nl = i*4 + r4;
    dst[(size_t)(nt+nl)*K + kt + c] = f2bf(sm[c][nl]);
  }
}

// ---------------- MFMA GEMM, 256x128 tile, BK=64, 3-buffer phase-split pipeline ----------------
// 8 waves: wr = w>>1 (M quarter, 64 rows), wc = w&1 (N half, 64 cols); per-wave 64x64.
// LDS[buf] rows of 64 u16, chunk c holds global chunk c^(row&7); pre-swizzled source.
// Loads 2 tiles ahead; steady-state vmcnt(6); 2 MFMA phases per K-tile with setprio.
// EPI 1: split-head bf16 [bh][n][dh]   2: f32 C += acc+bias
// EPI 3: bf16 C = gelu(acc+bias)       4: v_t bf16 [bh][dh][n]
template<int EPI>
__global__ __launch_bounds__(512)
void k_mm8(const u16* __restrict__ A, const u16* __restrict__ Bt,
           const float* __restrict__ bias, void* __restrict__ Cv,
           int Nc, int K){
  __shared__ u16 Ab[3][256*64];   // 96 KB
  __shared__ u16 Bb[3][128*64];   // 48 KB
  int tid = threadIdx.x;
  int w = tid >> 6, lane = tid & 63;
  int wr = w >> 1, wc = w & 1;
  int hi = lane >> 4, li = lane & 15;
  int row0 = blockIdx.y*256, col0 = blockIdx.x*128;
  int lr = lane >> 3;
  int lc = (lane & 7) ^ lr;
  const u16* gA = A  + (size_t)(row0 + w*8 + lr)*K + lc*8;
  const u16* gB = Bt + (size_t)(col0 + w*8 + lr)*K + lc*8;
  f32x4 acc[4][4] = {};

#define STG8(buf,k0) { \
    GLOAD16(gA + (k0),                  &Ab[buf][w*512]);          \
    GLOAD16(gA + (size_t)64*K  + (k0),  &Ab[buf][4096  + w*512]);  \
    GLOAD16(gA + (size_t)128*K + (k0),  &Ab[buf][8192  + w*512]);  \
    GLOAD16(gA + (size_t)192*K + (k0),  &Ab[buf][12288 + w*512]);  \
    GLOAD16(gB + (k0),                  &Bb[buf][w*512]);          \
    GLOAD16(gB + (size_t)64*K  + (k0),  &Bb[buf][4096  + w*512]); }

  int nk = K >> 6;            // >= 8 for all our shapes
  STG8(0, 0)
  STG8(1, 64)
  for(int t=0; t<nk; ++t){
    int buf = t % 3;
    int nbuf = (t+2) % 3;
    size_t nk0 = (size_t)(t+2)*64;
    __builtin_amdgcn_sched_barrier(0);
    if(t+1 < nk){ asm volatile("s_waitcnt vmcnt(6)"); }
    else        { asm volatile("s_waitcnt vmcnt(0)"); }
    __builtin_amdgcn_s_barrier();
    __builtin_amdgcn_sched_barrier(0);
    const u16* pa = &Ab[buf][0];
    const u16* pb = &Bb[buf][0];
    // phase A: all B frags + A frags 0,1
    bf16x8 bfr[2][4], af[2][2];
    #pragma unroll
    for(int kk=0;kk<2;kk++){
      int kc = kk*4 + hi;
      #pragma unroll
      for(int j=0;j<4;j++){
        int bc = wc*64 + j*16 + li;
        bfr[kk][j] = *(const bf16x8*)&pb[bc*64 + ((kc ^ (bc&7))<<3)];
      }
      #pragma unroll
      for(int q=0;q<2;q++){
        int ar = wr*64 + q*16 + li;
        af[kk][q] = *(const bf16x8*)&pa[ar*64 + ((kc ^ (ar&7))<<3)];
      }
    }
    if(t+2 < nk){
      GLOAD16(gA + nk0,                  &Ab[nbuf][w*512]);
      GLOAD16(gA + (size_t)64*K  + nk0,  &Ab[nbuf][4096  + w*512]);
      GLOAD16(gA + (size_t)128*K + nk0,  &Ab[nbuf][8192  + w*512]);
    }
    __builtin_amdgcn_s_setprio(1);
    #pragma unroll
    for(int kk=0;kk<2;kk++)
      #pragma unroll
      for(int q=0;q<2;q++)
        #pragma unroll
        for(int j=0;j<4;j++)
          acc[q][j] = MFMA16(af[kk][q], bfr[kk][j], acc[q][j]);
    __builtin_amdgcn_s_setprio(0);
    __builtin_amdgcn_s_barrier();   // pacing
    // phase B: A frags 2,3 (B frags reused from registers)
    bf16x8 af2[2][2];
    #pragma unroll
    for(int kk=0;kk<2;kk++){
      int kc = kk*4 + hi;
      #pragma unroll
      for(int q=0;q<2;q++){
        int ar = wr*64 + (q+2)*16 + li;
        af2[kk][q] = *(const bf16x8*)&pa[ar*64 + ((kc ^ (ar&7))<<3)];
      }
    }
    if(t+2 < nk){
      GLOAD16(gA + (size_t)192*K + nk0,  &Ab[nbuf][12288 + w*512]);
      GLOAD16(gB + nk0,                  &Bb[nbuf][w*512]);
      GLOAD16(gB + (size_t)64*K  + nk0,  &Bb[nbuf][4096  + w*512]);
    }
    __builtin_amdgcn_s_setprio(1);
    #pragma unroll
    for(int kk=0;kk<2;kk++)
      #pragma unroll
      for(int q=0;q<2;q++)
        #pragma unroll
        for(int j=0;j<4;j++)
          acc[q+2][j] = MFMA16(af2[kk][q], bfr[kk][j], acc[q+2][j]);
    __builtin_amdgcn_s_setprio(0);
    __builtin_amdgcn_s_barrier();   // end of iter
  }
#undef STG8

  #pragma unroll
  for(int i2=0;i2<4;i2++){
    #pragma unroll
    for(int j2=0;j2<4;j2++){
      int col = col0 + wc*64 + j2*16 + li;
      float bcol = (EPI==2 || EPI==3) ? bias[col] : 0.f;
      if constexpr (EPI==4){
        int nb = row0 + wr*64 + i2*16 + hi*4;
        int b = nb >> 11, n = nb & (SEQ-1);
        int h = col >> 6, dh = col & 63;
        ushort4 pk;
        pk.x = f2bf(acc[i2][j2][0]); pk.y = f2bf(acc[i2][j2][1]);
        pk.z = f2bf(acc[i2][j2][2]); pk.w = f2bf(acc[i2][j2][3]);
        *(ushort4*)((u16*)Cv + (((size_t)(b*HNUM+h)*DHEAD + dh)*SEQ + n)) = pk;
      } else {
        #pragma unroll
        for(int r=0;r<4;r++){
          int row = row0 + wr*64 + i2*16 + hi*4 + r;
          float v = acc[i2][j2][r];
          if constexpr (EPI==1){
            int b = row >> 11, n = row & (SEQ-1);
            int h = col >> 6, dh = col & 63;
            ((u16*)Cv)[((size_t)(b*HNUM+h)*SEQ + n)*DHEAD + dh] = f2bf(v);
          } else if constexpr (EPI==2){
            ((float*)Cv)[(size_t)row*Nc + col] += v + bcol;
          } else {
            ((u16*)Cv)[(size_t)row*Nc + col] = f2bf(fast_gelu(v + bcol));
          }
        }
      }
    }
  }
}

// ---------------- K max pass: 128 rows/block, streaming acc ----------------
__global__ __launch_bounds__(256)
void k_kmax(const u16* __restrict__ xg, const u16* __restrict__ pjb,
            float* __restrict__ kmax){
  __shared__ u16 pj[256*64];
  __shared__ u16 xs[128*64];
  __shared__ float wred[4];
  int tid = threadIdx.x, w = tid >> 6, lane = tid & 63;
  int hi = lane >> 4, li = lane & 15;
  int r0 = blockIdx.x * 128;
  int bh = r0 >> 11;
  #pragma unroll
  for(int i=0;i<8;i++){
    int idx = i*256 + tid;
    int m = idx >> 3, c = idx & 7;
    bf16x8 v = *(const bf16x8*)(pjb + m*64 + c*8);
    *(bf16x8*)&pj[m*64 + ((c ^ (m&7))<<3)] = v;
  }
  #pragma unroll
  for(int i=0;i<4;i++){
    int idx = i*256 + tid;
    int m = idx >> 3, c = idx & 7;
    bf16x8 v = *(const bf16x8*)(xg + (size_t)(r0+m)*64 + c*8);
    *(bf16x8*)&xs[m*64 + ((c ^ (m&7))<<3)] = v;
  }
  __syncthreads();
  bf16x8 bfr[2][4];
  #pragma unroll
  for(int ks=0;ks<2;ks++){
    int kc = ks*4 + hi;
    #pragma unroll
    for(int t=0;t<4;t++){
      int bc = w*64 + t*16 + li;
      bfr[ks][t] = *(const bf16x8*)&pj[bc*64 + ((kc ^ (bc&7))<<3)];
    }
  }
  float mx = -1e30f;
  #pragma unroll
  for(int i8=0;i8<8;i8++){
    f32x4 acc[4] = {};
    #pragma unroll
    for(int ks=0;ks<2;ks++){
      int kc = ks*4 + hi;
      int ar = i8*16 + li;
      bf16x8 af = *(const bf16x8*)&xs[ar*64 + ((kc ^ (ar&7))<<3)];
      #pragma unroll
      for(int j2=0;j2<4;j2++)
        acc[j2] = MFMA16(af, bfr[ks][j2], acc[j2]);
    }
    #pragma unroll
    for(int j2=0;j2<4;j2++)
      #pragma unroll
      for(int r=0;r<4;r++) mx = fmaxf(mx, acc[j2][r]);
  }
  #pragma unroll
  for(int o=32;o;o>>=1) mx = fmaxf(mx, __shfl_xor(mx,o));
  if(lane==0) wred[w] = mx;
  __syncthreads();
  if(tid==0){
    float m2 = fmaxf(fmaxf(wred[0],wred[1]), fmaxf(wred[2],wred[3]));
    atomicMaxF(&kmax[bh], m2*DNRM);
  }
}

// ---------------- K feature pass: 128 rows/block, kp_t + ksum, register diag ----------------
__global__ __launch_bounds__(256)
void k_kfeat(const u16* __restrict__ xg, const u16* __restrict__ pjb,
             u16* __restrict__ outp, const float* __restrict__ kmax,
             float* __restrict__ ksum){
  __shared__ u16 pj[256*64];
  __shared__ u16 xs[128*64];
  __shared__ float dgs[128];
  int tid = threadIdx.x, w = tid >> 6, lane = tid & 63;
  int hi = lane >> 4, li = lane & 15;
  int r0 = blockIdx.x * 128;
  int bh = r0 >> 11;
  int nbase = r0 & (SEQ-1);
  #pragma unroll
  for(int i=0;i<8;i++){
    int idx = i*256 + tid;
    int m = idx >> 3, c = idx & 7;
    bf16x8 v = *(const bf16x8*)(pjb + m*64 + c*8);
    *(bf16x8*)&pj[m*64 + ((c ^ (m&7))<<3)] = v;
  }
  #pragma unroll
  for(int i=0;i<4;i++){
    int idx = i*256 + tid;
    int m = idx >> 3, c = idx & 7;
    bf16x8 v = *(const bf16x8*)(xg + (size_t)(r0+m)*64 + c*8);
    *(bf16x8*)&xs[m*64 + ((c ^ (m&7))<<3)] = v;
    float s = 0.f;
    #pragma unroll
    for(int j=0;j<8;j++){ float t = bf2f((u16)v[j]); s += t*t; }
    s += __shfl_xor(s,1); s += __shfl_xor(s,2); s += __shfl_xor(s,4);
    if((tid&7)==0) dgs[m] = 0.5f*DNRM*DNRM*s;
  }
  __syncthreads();
  bf16x8 bfr[2][4];
  #pragma unroll
  for(int ks=0;ks<2;ks++){
    int kc = ks*4 + hi;
    #pragma unroll
    for(int t=0;t<4;t++){
      int bc = w*64 + t*16 + li;
      bfr[ks][t] = *(const bf16x8*)&pj[bc*64 + ((kc ^ (bc&7))<<3)];
    }
  }
  float km = kmax[bh];
  float csum[4] = {0.f,0.f,0.f,0.f};
  #pragma unroll
  for(int i8=0;i8<8;i8++){
    f32x4 acc[4] = {};
    #pragma unroll
    for(int ks=0;ks<2;ks++){
      int kc = ks*4 + hi;
      int ar = i8*16 + li;
      bf16x8 af = *(const bf16x8*)&xs[ar*64 + ((kc ^ (ar&7))<<3)];
      #pragma unroll
      for(int j2=0;j2<4;j2++)
        acc[j2] = MFMA16(af, bfr[ks][j2], acc[j2]);
    }
    #pragma unroll
    for(int j2=0;j2<4;j2++){
      int col = w*64 + j2*16 + li;
      ushort4 pk;
      float cpart = 0.f;
      #pragma unroll
      for(int r=0;r<4;r++){
        int rl = i8*16 + hi*4 + r;
        float u = acc[j2][r]*DNRM;
        u16 eb = f2bf(SMF*(__expf(u - dgs[rl] - km) + EPSF));
        ((u16*)&pk)[r] = eb;
        cpart += bf2f(eb);
      }
      *(ushort4*)(outp + ((size_t)(bh*MFEAT + col)*SEQ + nbase + i8*16 + hi*4)) = pk;
      csum[j2] += cpart;
    }
  }
  #pragma unroll
  for(int j2=0;j2<4;j2++){
    float v = csum[j2];
    v += __shfl_xor(v,16); v += __shfl_xor(v,32);
    if(hi==0) atomicAdd(&ksum[bh*MFEAT + w*64 + j2*16 + li], v);
  }
}

// ---------------- fused Q-feature + PV, 512 threads / 64 rows per block ----------------
__global__ __launch_bounds__(512)
void k_feato(const u16* __restrict__ xg, const u16* __restrict__ pjb,
             const u16* __restrict__ ctxt, const float* __restrict__ ksum,
             u16* __restrict__ o){
  __shared__ u16 smA[16384];
  __shared__ u16 smX[4096];
  __shared__ u16 smQ[64*264];
  __shared__ float dgs[64];
  __shared__ float wred[2][4][32];
  __shared__ float wden[2][4][32];
  __shared__ float ksl[256];
  __shared__ float denl[64];
  int tid = threadIdx.x, w = tid >> 6, lane = tid & 63;
  int hi = lane >> 4, li = lane & 15;
  int g = w >> 2, wq = w & 3;
  int r0 = blockIdx.x * 64;
  int bh = r0 >> 11;
  int b = bh >> 3, h = bh & 7;
  #pragma unroll
  for(int i=0;i<4;i++){
    int idx = i*512 + tid;
    int m = idx >> 3, c = idx & 7;
    bf16x8 v = *(const bf16x8*)(pjb + m*64 + c*8);
    *(bf16x8*)&smA[m*64 + ((c ^ (m&7))<<3)] = v;
  }
  {
    int m = tid >> 3, c = tid & 7;
    bf16x8 v = *(const bf16x8*)(xg + (size_t)(r0+m)*64 + c*8);
    *(bf16x8*)&smX[m*64 + ((c ^ (m&7))<<3)] = v;
    float s = 0.f;
    #pragma unroll
    for(int j=0;j<8;j++){ float t = bf2f((u16)v[j]); s += t*t; }
    s += __shfl_xor(s,1); s += __shfl_xor(s,2); s += __shfl_xor(s,4);
    if((tid&7)==0) dgs[m] = 0.5f*DNRM*DNRM*s;
  }
  if(tid < 256) ksl[tid] = ksum[bh*MFEAT + tid];
  __syncthreads();
  f32x4 acc[2][4] = {};
  #pragma unroll
  for(int ks=0;ks<2;ks++){
    bf16x8 af[2], bfr[4];
    int kc = ks*4 + hi;
    #pragma unroll
    for(int t=0;t<2;t++){
      int ar = g*32 + t*16 + li;
      af[t] = *(const bf16x8*)&smX[ar*64 + ((kc ^ (ar&7))<<3)];
    }
    #pragma unroll
    for(int t=0;t<4;t++){
      int bc = wq*64 + t*16 + li;
      bfr[t] = *(const bf16x8*)&smA[bc*64 + ((kc ^ (bc&7))<<3)];
    }
    #pragma unroll
    for(int i2=0;i2<2;i2++)
      #pragma unroll
      for(int j2=0;j2<4;j2++)
        acc[i2][j2] = MFMA16(af[i2], bfr[j2], acc[i2][j2]);
  }
  __syncthreads();
  {
    int gch = (tid & 31) ^ ((tid >> 5) & 7);
    const u16* gCl = ctxt + (size_t)bh*DHEAD*MFEAT + (size_t)(tid>>5)*MFEAT + gch*8;
    #pragma unroll
    for(int i=0;i<4;i++)
      GLOAD16(gCl + (size_t)i*16*MFEAT, &smA[i*4096 + w*512]);
  }
  #pragma unroll
  for(int i2=0;i2<2;i2++){
    #pragma unroll
    for(int r=0;r<4;r++){
      float v = fmaxf(fmaxf(acc[i2][0][r],acc[i2][1][r]), fmaxf(acc[i2][2][r],acc[i2][3][r]));
      v = fmaxf(v, __shfl_xor(v,1)); v = fmaxf(v, __shfl_xor(v,2));
      v = fmaxf(v, __shfl_xor(v,4)); v = fmaxf(v, __shfl_xor(v,8));
      if(li==0) wred[g][wq][i2*16 + hi*4 + r] = v;
    }
  }
  __builtin_amdgcn_sched_barrier(0);
  asm volatile("s_waitcnt lgkmcnt(0)");
  __builtin_amdgcn_s_barrier();
  __builtin_amdgcn_sched_barrier(0);
  #pragma unroll
  for(int i2=0;i2<2;i2++){
    #pragma unroll
    for(int r=0;r<4;r++){
      int rl = i2*16 + hi*4 + r;
      int row = g*32 + rl;
      float rm = fmaxf(fmaxf(wred[g][0][rl],wred[g][1][rl]),
                       fmaxf(wred[g][2][rl],wred[g][3][rl]));
      float dsum = 0.f;
      #pragma unroll
      for(int j2=0;j2<4;j2++){
        int col = wq*64 + j2*16 + li;
        float u = acc[i2][j2][r]*DNRM;
        u16 eb = f2bf(SMF*(__expf(u - dgs[row] - rm) + EPSF));
        smQ[row*264 + col] = eb;
        dsum += bf2f(eb)*ksl[col];
      }
      dsum += __shfl_xor(dsum,1); dsum += __shfl_xor(dsum,2);
      dsum += __shfl_xor(dsum,4); dsum += __shfl_xor(dsum,8);
      if(li==0) wden[g][wq][rl] = dsum;
    }
  }
  __builtin_amdgcn_sched_barrier(0);
  asm volatile("s_waitcnt vmcnt(0) lgkmcnt(0)");
  __builtin_amdgcn_s_barrier();
  __builtin_amdgcn_sched_barrier(0);
  if(tid < 64){
    int gg = tid >> 5, rr = tid & 31;
    denl[tid] = wden[gg][0][rr]+wden[gg][1][rr]+wden[gg][2][rr]+wden[gg][3][rr];
  }
  int d4 = w >> 1, g2 = w & 1;
  f32x4 acc2[2] = {};
  #pragma unroll
  for(int s=0;s<8;s++){
    int kc = s*4 + hi;
    int bc = d4*16 + li;
    bf16x8 bf = *(const bf16x8*)&smA[bc*256 + ((kc ^ (bc&7))<<3)];
    #pragma unroll
    for(int t=0;t<2;t++){
      int ar = g2*32 + t*16 + li;
      bf16x8 aa = *(const bf16x8*)&smQ[ar*264 + kc*8];
      acc2[t] = MFMA16(aa, bf, acc2[t]);
    }
  }
  __syncthreads();
  int nbase = r0 & (SEQ-1);
  #pragma unroll
  for(int t=0;t<2;t++){
    #pragma unroll
    for(int r=0;r<4;r++){
      int nl = g2*32 + t*16 + hi*4 + r;
      float di = 1.0f/denl[nl];
      o[((size_t)b*SEQ + nbase + nl)*DMODEL + h*DHEAD + d4*16 + li] = f2bf(acc2[t][r]*di);
    }
  }
}

// ---------------- ctx_t[bh][dh][m] = sum_n v_t[dh][n]*kp_t[m][n], depth-2 pipeline ----------------
__global__ __launch_bounds__(256)
void k_ctx(const u16* __restrict__ vt, const u16* __restrict__ kpt,
           u16* __restrict__ ctxt){
  __shared__ u16 As[2][64*64];
  __shared__ u16 Bs[2][64*64];
  int tid = threadIdx.x, w = tid >> 6, lane = tid & 63;
  int wr = w >> 1, wc = w & 1;
  int hi = lane >> 4, li = lane & 15;
  int bh = blockIdx.y, mb = blockIdx.x*64;
  int lr = lane >> 3;
  int lc = (lane & 7) ^ lr;
  const u16* gA = vt  + (size_t)bh*DHEAD*SEQ + (size_t)(w*8 + lr)*SEQ + lc*8;
  const u16* gB = kpt + ((size_t)bh*MFEAT + mb + w*8 + lr)*SEQ + lc*8;
  f32x4 acc[2][2] = {};
#define STAGE_CTX(b,k0) { \
    GLOAD16(gA + (k0),                 &As[b][(w*8)*64]);      \
    GLOAD16(gA + (size_t)32*SEQ + (k0),&As[b][(32+w*8)*64]);   \
    GLOAD16(gB + (k0),                 &Bs[b][(w*8)*64]);      \
    GLOAD16(gB + (size_t)32*SEQ + (k0),&Bs[b][(32+w*8)*64]); }
  int nk = SEQ/64;
  STAGE_CTX(0, 0)
  STAGE_CTX(1, 64)
  for(int t=0; t<nk; ++t){
    __builtin_amdgcn_sched_barrier(0);
    if(t+1 < nk){ asm volatile("s_waitcnt vmcnt(4)"); }
    else        { asm volatile("s_waitcnt vmcnt(0)"); }
    __builtin_amdgcn_s_barrier();
    __builtin_amdgcn_sched_barrier(0);
    const u16* pa = &As[t&1][0];
    const u16* pb = &Bs[t&1][0];
    #pragma unroll
    for(int ks=0;ks<2;ks++){
      bf16x8 af[2], bfr[2];
      int kc = ks*4 + hi;
      #pragma unroll
      for(int q=0;q<2;q++){
        int ar = wr*32 + q*16 + li;
        af[q] = *(const bf16x8*)&pa[ar*64 + ((kc ^ (ar&7))<<3)];
        int bc = wc*32 + q*16 + li;
        bfr[q] = *(const bf16x8*)&pb[bc*64 + ((kc ^ (bc&7))<<3)];
      }
      #pragma unroll
      for(int i2=0;i2<2;i2++)
        #pragma unroll
        for(int j2=0;j2<2;j2++)
          acc[i2][j2] = MFMA16(af[i2], bfr[j2], acc[i2][j2]);
    }
    __builtin_amdgcn_sched_barrier(0);
    __builtin_amdgcn_s_barrier();
    __builtin_amdgcn_sched_barrier(0);
    if(t+2 < nk){ STAGE_CTX(t&1, (size_t)(t+2)*64) }
  }
#undef STAGE_CTX
  #pragma unroll
  for(int i2=0;i2<2;i2++)
    #pragma unroll
    for(int j2=0;j2<2;j2++){
      int m = mb + wc*32 + j2*16 + li;
      #pragma unroll
      for(int r=0;r<4;r++){
        int dh = wr*32 + i2*16 + hi*4 + r;
        ctxt[((size_t)bh*DHEAD + dh)*MFEAT + m] = f2bf(acc[i2][j2][r]);
      }
    }
}

extern "C" void kernel_launch(void* const* d_in, const int* in_sizes, int n_in,
                              void* d_out, int out_size, void* d_ws, size_t ws_size,
                              hipStream_t stream){
  (void)in_sizes; (void)n_in; (void)out_size; (void)ws_size;
  const float* x    = (const float*)d_in[0];
  const float* proj = (const float*)d_in[1];
  const float* ln1g = (const float*)d_in[2];
  const float* ln1b = (const float*)d_in[3];
  const float* wq   = (const float*)d_in[4];
  const float* wk   = (const float*)d_in[5];
  const float* wv   = (const float*)d_in[6];
  const float* wo   = (const float*)d_in[7];
  const float* bo   = (const float*)d_in[8];
  const float* ln2g = (const float*)d_in[9];
  const float* ln2b = (const float*)d_in[10];
  const float* w1   = (const float*)d_in[11];
  const float* b1   = (const float*)d_in[12];
  const float* w2   = (const float*)d_in[13];
  const float* b2   = (const float*)d_in[14];
  float* xo = (float*)d_out;

  // workspace ~110 MB
  char* ws = (char*)d_ws;
  u16* bufH  = (u16*)ws;  ws += (size_t)TOK*DMODEL*2;
  u16* bufA  = (u16*)ws;  ws += (size_t)TOK*DMODEL*2;
  u16* featb = (u16*)ws;  ws += (size_t)BHN*SEQ*MFEAT*2;
  u16* ctxt  = (u16*)ws;  ws += (size_t)BHN*DHEAD*MFEAT*2;
  u16* wT    = (u16*)ws;  ws += (size_t)3*1048576*2;
  u16* pjb   = (u16*)ws;  ws += (size_t)LNUM*MFEAT*DHEAD*2;
  float* ksum= (float*)ws; ws += (size_t)BHN*MFEAT*4;
  float* kmax= (float*)ws; ws += 256;

  u16* wqT = wT;
  u16* wkT = wT +  262144;
  u16* wvT = wT +  524288;
  u16* woT = wT +  786432;
  u16* w1T = wT + 1048576;
  u16* w2T = wT + 2097152;

  k_addpe<<<(TOK*DMODEL)/256, 256, 0, stream>>>(x, xo);
  k_pcvt<<<(LNUM*MFEAT*DHEAD)/256, 256, 0, stream>>>(proj, pjb);

  for(int l=0; l<LNUM; l++){
    const u16* pj_l = pjb + (size_t)l*MFEAT*DHEAD;
    k_wcvt_all<<<832, 256, 0, stream>>>(wq + (size_t)l*262144, wk + (size_t)l*262144,
                                        wv + (size_t)l*262144, wo + (size_t)l*262144,
                                        w1 + (size_t)l*1048576, w2 + (size_t)l*1048576,
                                        wqT, wkT, wvT, woT, w1T, w2T, ksum, kmax);
    k_ln<<<TOK, 256, 0, stream>>>(xo, ln1g + l*DMODEL, ln1b + l*DMODEL, bufH);
    // K path: k -> kmax -> kp_t (+ksum atomics)
    k_mm8<1><<<dim3(4,64), 512, 0, stream>>>(bufH, wkT, nullptr, bufA, DMODEL, DMODEL);
    k_kmax<<<(BHN*SEQ)/128, 256, 0, stream>>>(bufA, pj_l, kmax);
    k_kfeat<<<(BHN*SEQ)/128, 256, 0, stream>>>(bufA, pj_l, featb, kmax, ksum);
    // V path: v_t -> ctx_t
    k_mm8<4><<<dim3(4,64), 512, 0, stream>>>(bufH, wvT, nullptr, bufA, DMODEL, DMODEL);
    k_ctx<<<dim3(4,BHN), 256, 0, stream>>>(bufA, featb, ctxt);
    // Q path fused: q -> qp (LDS) -> o  -> wo-GEMM (residual add)
    k_mm8<1><<<dim3(4,64), 512, 0, stream>>>(bufH, wqT, nullptr, bufA, DMODEL, DMODEL);
    k_feato<<<(BHN*SEQ)/64, 512, 0, stream>>>(bufA, pj_l, ctxt, ksum, bufH);
    k_mm8<2><<<dim3(4,64), 512, 0, stream>>>(bufH, woT, bo + l*DMODEL, xo, DMODEL, DMODEL);
    // FFN
    k_ln<<<TOK, 256, 0, stream>>>(xo, ln2g + l*DMODEL, ln2b + l*DMODEL, bufA);
    k_mm8<3><<<dim3(16,64), 512, 0, stream>>>(bufA, w1T, b1 + l*DFF, featb, DFF, DMODEL);
    k_mm8<2><<<dim3(4,64), 512, 0, stream>>>(featb, w2T, b2 + l*DMODEL, xo, DMODEL, DFF);
  }
}